// Round 1
// baseline (647.757 us; speedup 1.0000x reference)
//
#include <hip/hip_runtime.h>
#include <hip/hip_bf16.h>
#include <math.h>

#define N_NODES 100000
#define N_HE    50000
#define N_INC   600000
#define D_IN    256
#define D_H     128
#define N_CLASSES 40

typedef __attribute__((ext_vector_type(8))) short short8;
typedef __attribute__((ext_vector_type(4))) float f32x4;

__device__ __forceinline__ float sigmoidf_(float x) {
    return 1.0f / (1.0f + expf(-x));
}

__device__ __forceinline__ short bfbits(float f) {
    __hip_bfloat16 h = __float2bfloat16(f);
    return *reinterpret_cast<short*>(&h);
}

__device__ __forceinline__ float bf_lo(unsigned u) { return __uint_as_float(u << 16); }
__device__ __forceinline__ float bf_hi(unsigned u) { return __uint_as_float(u & 0xffff0000u); }
__device__ __forceinline__ unsigned bfpack(float a, float b) {
    return (unsigned)(unsigned short)bfbits(a) | ((unsigned)(unsigned short)bfbits(b) << 16);
}

// ---------------------------------------------------------------------------
// MFMA GEMM: C(M x 128) = act( [A1|A2] @ W + bias ), bf16 inputs, fp32 acc.
// Block = 256 thr (4 waves 2x2), BM=128, BN=128, wave tile 64x64.
// Epilogue: stage C in LDS (reuse sW, stride 136 -> 2-way only), then
// cooperative full-line uint4 stores (no write-allocate fetch).
// ---------------------------------------------------------------------------
template<int K, int K1, bool AF32>
__global__ __launch_bounds__(256) void gemm_mfma(
    const void* __restrict__ A1v,
    const __hip_bfloat16* __restrict__ A2,
    const __hip_bfloat16* __restrict__ Wt,   // 128 x K bf16, transposed
    const float* __restrict__ bias,
    __hip_bfloat16* __restrict__ C,          // M x 128 bf16
    int M, int act)
{
    constexpr int KP = 136;
    __shared__ __hip_bfloat16 sW[128 * KP];  // 34816 B; reused for C staging

    const int tid = threadIdx.x;
    const int wave = tid >> 6, lane = tid & 63;
    const int quad = lane >> 4, nn = lane & 15;
    const int wr = wave >> 1, wc = wave & 1;
    const int row_base = blockIdx.x * 128 + wr * 64;
    const int col_base = wc * 64;

    f32x4 acc[4][4] = {};

    for (int h = 0; h < K / 128; ++h) {
        for (int c = tid; c < 128 * 16; c += 256) {
            const int n = c >> 4;
            const int ko = (c & 15) * 8;
            *(uint4*)&sW[n * KP + ko] = *(const uint4*)&Wt[(size_t)n * K + h * 128 + ko];
        }
        __syncthreads();

#pragma unroll
        for (int ks = 0; ks < 4; ++ks) {
            const int kl = ks * 32 + quad * 8;
            const int kq = h * 128 + kl;
            short8 a[4];
#pragma unroll
            for (int rt = 0; rt < 4; ++rt) {
                int r = row_base + rt * 16 + nn;
                if (r >= M) r = M - 1;
                if constexpr (AF32) {
                    const float* ap = (const float*)A1v + (size_t)r * K + kq;
                    const float4 p = *(const float4*)ap;
                    const float4 q = *(const float4*)(ap + 4);
                    short8 t;
                    t[0] = bfbits(p.x); t[1] = bfbits(p.y);
                    t[2] = bfbits(p.z); t[3] = bfbits(p.w);
                    t[4] = bfbits(q.x); t[5] = bfbits(q.y);
                    t[6] = bfbits(q.z); t[7] = bfbits(q.w);
                    a[rt] = t;
                } else {
                    const __hip_bfloat16* base;
                    if (K1 == K || kq < K1)
                        base = (const __hip_bfloat16*)A1v + (size_t)r * K1 + kq;
                    else
                        base = A2 + (size_t)r * (K - K1) + (kq - K1);
                    a[rt] = *(const short8*)base;
                }
            }
#pragma unroll
            for (int ct = 0; ct < 4; ++ct) {
                const short8 b = *(const short8*)&sW[(col_base + ct * 16 + nn) * KP + kl];
#pragma unroll
                for (int rt = 0; rt < 4; ++rt)
                    acc[rt][ct] = __builtin_amdgcn_mfma_f32_16x16x32_bf16(
                        a[rt], b, acc[rt][ct], 0, 0, 0);
            }
        }
        __syncthreads();   // also protects sW reuse below on last iteration
    }

    float bs[4];
#pragma unroll
    for (int ct = 0; ct < 4; ++ct) bs[ct] = bias[col_base + ct * 16 + nn];

    // ---- stage C tile into LDS (bf16, stride KP=136) ----
    unsigned short* sC = (unsigned short*)sW;
#pragma unroll
    for (int rt = 0; rt < 4; ++rt) {
#pragma unroll
        for (int i = 0; i < 4; ++i) {
            const int R = wr * 64 + rt * 16 + quad * 4 + i;
#pragma unroll
            for (int ct = 0; ct < 4; ++ct) {
                float v = acc[rt][ct][i] + bs[ct];
                if (act) v = sigmoidf_(v);
                sC[R * KP + col_base + ct * 16 + nn] = (unsigned short)bfbits(v);
            }
        }
    }
    __syncthreads();

    // ---- cooperative coalesced store: thread t -> row t/2, half t&1 ----
    // each half-row = 64 bf16 = 128 B = 8 uint4
    {
        const int row = tid >> 1, half = tid & 1;
        const int gr = blockIdx.x * 128 + row;
        if (gr < M) {
            const unsigned short* srcp = sC + row * KP + half * 64;
            uint4* dstp = (uint4*)(C + (size_t)gr * 128 + half * 64);
#pragma unroll
            for (int j = 0; j < 8; ++j) dstp[j] = *(const uint4*)(srcp + j * 8);
        }
    }
}

// ---------------------------------------------------------------------------
// MFMA output GEMM: out(M x 40) = X(M x 128 bf16) @ W + b, fp32 out.
// Epilogue staged via LDS (stride 44 fp32) -> coalesced float4 stores.
// ---------------------------------------------------------------------------
__global__ __launch_bounds__(256) void out_gemm_mfma(
    const __hip_bfloat16* __restrict__ X,
    const __hip_bfloat16* __restrict__ Wt,   // 48 x 128 bf16 (n-major, padded)
    const float* __restrict__ b, float* __restrict__ out, int M)
{
    constexpr int KP = 136;
    __shared__ __hip_bfloat16 sW[48 * KP];
    __shared__ float sB[48];
    __shared__ float sO[64 * 44];            // 11264 B

    const int tid = threadIdx.x;
    for (int c = tid; c < 48 * 16; c += 256) {
        const int n = c >> 4, ko = (c & 15) * 8;
        *(uint4*)&sW[n * KP + ko] = *(const uint4*)&Wt[n * 128 + ko];
    }
    if (tid < 48) sB[tid] = (tid < 40) ? b[tid] : 0.0f;
    __syncthreads();

    const int wave = tid >> 6, lane = tid & 63;
    const int quad = lane >> 4, nn = lane & 15;
    const int row0 = blockIdx.x * 64 + wave * 16;

    f32x4 acc[3] = {};
#pragma unroll
    for (int ks = 0; ks < 4; ++ks) {
        int r = row0 + nn;
        if (r >= M) r = M - 1;
        const short8 a = *(const short8*)(X + (size_t)r * 128 + ks * 32 + quad * 8);
#pragma unroll
        for (int ct = 0; ct < 3; ++ct) {
            const short8 bf = *(const short8*)&sW[(ct * 16 + nn) * KP + ks * 32 + quad * 8];
            acc[ct] = __builtin_amdgcn_mfma_f32_16x16x32_bf16(a, bf, acc[ct], 0, 0, 0);
        }
    }

    // stage into LDS
#pragma unroll
    for (int ct = 0; ct < 3; ++ct) {
        const int c = ct * 16 + nn;
        if (c < 40) {
#pragma unroll
            for (int i = 0; i < 4; ++i) {
                const int rl = wave * 16 + quad * 4 + i;
                sO[rl * 44 + c] = acc[ct][i] + sB[c];
            }
        }
    }
    __syncthreads();

    // cooperative store: 64 rows x 10 float4
    for (int c = tid; c < 640; c += 256) {
        const int row = c / 10, ch = c % 10;
        const int gr = blockIdx.x * 64 + row;
        if (gr < M)
            *(float4*)(out + (size_t)gr * 40 + ch * 4) =
                *(const float4*)(sO + row * 44 + ch * 4);
    }
}

// ---------------------------------------------------------------------------
// Weight prep: fp32 -> bf16 transposed Wt[n][k] for enc/m0/m1/out.
// ---------------------------------------------------------------------------
__global__ __launch_bounds__(256) void wprep_kernel(
    const float* __restrict__ We, const float* __restrict__ Wm0,
    const float* __restrict__ Wm1, const float* __restrict__ Wout,
    __hip_bfloat16* __restrict__ Wt_enc, __hip_bfloat16* __restrict__ Wt_m0,
    __hip_bfloat16* __restrict__ Wt_m1, __hip_bfloat16* __restrict__ Wt_out)
{
    const int i = blockIdx.x * 256 + threadIdx.x;  // 0..137215
    if (i < 32768) {
        const int n = i >> 8, k = i & 255;
        Wt_enc[n * 256 + k] = __float2bfloat16(We[k * 128 + n]);
    } else if (i < 65536) {
        int j = i - 32768; const int l = j >> 14; j &= 16383;
        const int n = j >> 7, k = j & 127;
        Wt_m0[l * 16384 + n * 128 + k] = __float2bfloat16(Wm0[l * 16384 + k * 128 + n]);
    } else if (i < 131072) {
        int j = i - 65536; const int l = j >> 15; j &= 32767;
        const int n = j >> 8, k = j & 255;
        Wt_m1[l * 32768 + n * 256 + k] = __float2bfloat16(Wm1[l * 32768 + k * 128 + n]);
    } else {
        const int j = i - 131072;
        const int n = j >> 7, k = j & 127;
        Wt_out[n * 128 + k] = (n < 40) ? __float2bfloat16(Wout[k * 40 + n])
                                       : __float2bfloat16(0.0f);
    }
}

// ---------------------------------------------------------------------------
// CSR build (atomic-free fill: hist captures per-edge rank)
// ---------------------------------------------------------------------------
__global__ __launch_bounds__(256) void zero_int_kernel(int* __restrict__ p, int n)
{
    const int i = blockIdx.x * 256 + threadIdx.x;
    if (i < n) p[i] = 0;
}

__global__ __launch_bounds__(256) void hist_kernel(
    const int* __restrict__ he_idx, const int* __restrict__ node_idx,
    int* __restrict__ he_cnt, int* __restrict__ node_cnt,
    int* __restrict__ he_rank, int* __restrict__ node_rank, int n)
{
    const int i = blockIdx.x * 256 + threadIdx.x;
    if (i < n) {
        he_rank[i] = atomicAdd(&he_cnt[he_idx[i]], 1);
        node_rank[i] = atomicAdd(&node_cnt[node_idx[i]], 1);
    }
}

__global__ __launch_bounds__(256) void scan1_kernel(
    int* __restrict__ data, int* __restrict__ bsums, int n)
{
    __shared__ int s[256];
    const int t = threadIdx.x;
    const int base = blockIdx.x * 1024 + t * 4;
    int4 v = make_int4(0, 0, 0, 0);
    if (base < n) v = *(const int4*)(data + base);
    s[t] = v.x + v.y + v.z + v.w;
    __syncthreads();
    for (int d = 1; d < 256; d <<= 1) {
        const int u = (t >= d) ? s[t - d] : 0;
        __syncthreads();
        s[t] += u;
        __syncthreads();
    }
    if (t == 255) bsums[blockIdx.x] = s[255];
    int e = t ? s[t - 1] : 0;
    if (base < n) {
        int4 o;
        o.x = e; e += v.x; o.y = e; e += v.y; o.z = e; e += v.z; o.w = e;
        *(int4*)(data + base) = o;
    }
}

__global__ __launch_bounds__(256) void scan2_kernel(int* __restrict__ bsums, int nb)
{
    __shared__ int s[256];
    const int t = threadIdx.x;
    const int v = (t < nb) ? bsums[t] : 0;
    s[t] = v;
    __syncthreads();
    for (int d = 1; d < 256; d <<= 1) {
        const int u = (t >= d) ? s[t - d] : 0;
        __syncthreads();
        s[t] += u;
        __syncthreads();
    }
    if (t < nb) bsums[t] = s[t] - v;
}

__global__ __launch_bounds__(256) void scan3_kernel(
    int* __restrict__ data, const int* __restrict__ bsums, int n)
{
    const int base = blockIdx.x * 1024 + threadIdx.x * 4;
    if (base >= n) return;
    const int adj = bsums[blockIdx.x] - ((base >= N_HE) ? N_INC : 0);
    int4 v = *(int4*)(data + base);
    v.x += adj; v.y += adj; v.z += adj; v.w += adj;
    *(int4*)(data + base) = v;
}

// fill packed edges at off[dest]+rank[e] — NO atomics
__global__ __launch_bounds__(256) void fill_kernel(
    const int* __restrict__ node_idx, const int* __restrict__ he_idx,
    const float* __restrict__ vals,
    const int* __restrict__ he_off, const int* __restrict__ node_off,
    const int* __restrict__ he_rank, const int* __restrict__ node_rank,
    int2* __restrict__ he_edge, int2* __restrict__ node_edge, int n)
{
    const int e = blockIdx.x * 256 + threadIdx.x;
    if (e >= n) return;
    const int hn = he_idx[e], nd = node_idx[e];
    const int vb = __float_as_int(vals[e]);
    he_edge[he_off[hn] + he_rank[e]] = make_int2(nd, vb);
    node_edge[node_off[nd] + node_rank[e]] = make_int2(hn, vb);
}

// ---------------------------------------------------------------------------
// Fused he-gather (4 edges/wave-iter, 16B/lane): agg = sum val*m0[src];
// writes m0_he AND x1_next = sigmoid(x1_cur + agg). Offsets EXCLUSIVE.
// Lane layout: g = lane>>4 selects edge slot (0..3); l16 = lane&15 covers
// bf16 columns l16*8 .. l16*8+7 (one uint4 = 16 B per lane per edge).
// Reduction across the 4 edge slots: shfl_xor 16 then 32.
// ---------------------------------------------------------------------------
__global__ __launch_bounds__(256) void gather_he_kernel(
    const __hip_bfloat16* __restrict__ msrc,
    const __hip_bfloat16* __restrict__ x1cur,
    __hip_bfloat16* __restrict__ m0_he,
    __hip_bfloat16* __restrict__ x1next,
    const int* __restrict__ off, const int2* __restrict__ edges, int n_seg)
{
    const int wave = threadIdx.x >> 6;
    const int lane = threadIdx.x & 63;
    const int row = blockIdx.x * 4 + wave;
    if (row >= n_seg) return;
    const int start = off[row];
    const int end = (row + 1 < n_seg) ? off[row + 1] : N_INC;
    const int g = lane >> 4;
    const int l16 = lane & 15;
    float a0 = 0.f, a1 = 0.f, a2 = 0.f, a3 = 0.f;
    float a4 = 0.f, a5 = 0.f, a6 = 0.f, a7 = 0.f;
    const unsigned short* s16 = (const unsigned short*)msrc;
    for (int e = start; e < end; e += 4) {
        const int ee = e + g;
        const int2 ed = (ee < end) ? edges[ee] : make_int2(0, 0);
        const float v = __int_as_float(ed.y);        // 0 for padding slots
        const uint4 u = *(const uint4*)(s16 + (size_t)ed.x * 128 + l16 * 8);
        a0 += bf_lo(u.x) * v; a1 += bf_hi(u.x) * v;
        a2 += bf_lo(u.y) * v; a3 += bf_hi(u.y) * v;
        a4 += bf_lo(u.z) * v; a5 += bf_hi(u.z) * v;
        a6 += bf_lo(u.w) * v; a7 += bf_hi(u.w) * v;
    }
    a0 += __shfl_xor(a0, 16); a1 += __shfl_xor(a1, 16);
    a2 += __shfl_xor(a2, 16); a3 += __shfl_xor(a3, 16);
    a4 += __shfl_xor(a4, 16); a5 += __shfl_xor(a5, 16);
    a6 += __shfl_xor(a6, 16); a7 += __shfl_xor(a7, 16);
    a0 += __shfl_xor(a0, 32); a1 += __shfl_xor(a1, 32);
    a2 += __shfl_xor(a2, 32); a3 += __shfl_xor(a3, 32);
    a4 += __shfl_xor(a4, 32); a5 += __shfl_xor(a5, 32);
    a6 += __shfl_xor(a6, 32); a7 += __shfl_xor(a7, 32);
    if (g == 0) {
        const size_t o = (size_t)row * 128 + l16 * 8;
        uint4 mg;
        mg.x = bfpack(a0, a1); mg.y = bfpack(a2, a3);
        mg.z = bfpack(a4, a5); mg.w = bfpack(a6, a7);
        *(uint4*)((unsigned short*)m0_he + o) = mg;
        const uint4 xu = *(const uint4*)((const unsigned short*)x1cur + o);
        uint4 r;
        r.x = bfpack(sigmoidf_(bf_lo(xu.x) + a0), sigmoidf_(bf_hi(xu.x) + a1));
        r.y = bfpack(sigmoidf_(bf_lo(xu.y) + a2), sigmoidf_(bf_hi(xu.y) + a3));
        r.z = bfpack(sigmoidf_(bf_lo(xu.z) + a4), sigmoidf_(bf_hi(xu.z) + a5));
        r.w = bfpack(sigmoidf_(bf_lo(xu.w) + a6), sigmoidf_(bf_hi(xu.w) + a7));
        *(uint4*)((unsigned short*)x1next + o) = r;
    }
}

// ---------------------------------------------------------------------------
// Fused node-gather (4 edges/wave-iter, 16B/lane): x0 = sigmoid(x0 + agg).
// ---------------------------------------------------------------------------
__global__ __launch_bounds__(256) void gather_node_kernel(
    const __hip_bfloat16* __restrict__ msrc,
    __hip_bfloat16* __restrict__ x0,
    const int* __restrict__ off, const int2* __restrict__ edges, int n_seg)
{
    const int wave = threadIdx.x >> 6;
    const int lane = threadIdx.x & 63;
    const int row = blockIdx.x * 4 + wave;
    if (row >= n_seg) return;
    const int start = off[row];
    const int end = (row + 1 < n_seg) ? off[row + 1] : N_INC;
    const int g = lane >> 4;
    const int l16 = lane & 15;
    float a0 = 0.f, a1 = 0.f, a2 = 0.f, a3 = 0.f;
    float a4 = 0.f, a5 = 0.f, a6 = 0.f, a7 = 0.f;
    const unsigned short* s16 = (const unsigned short*)msrc;
    for (int e = start; e < end; e += 4) {
        const int ee = e + g;
        const int2 ed = (ee < end) ? edges[ee] : make_int2(0, 0);
        const float v = __int_as_float(ed.y);
        const uint4 u = *(const uint4*)(s16 + (size_t)ed.x * 128 + l16 * 8);
        a0 += bf_lo(u.x) * v; a1 += bf_hi(u.x) * v;
        a2 += bf_lo(u.y) * v; a3 += bf_hi(u.y) * v;
        a4 += bf_lo(u.z) * v; a5 += bf_hi(u.z) * v;
        a6 += bf_lo(u.w) * v; a7 += bf_hi(u.w) * v;
    }
    a0 += __shfl_xor(a0, 16); a1 += __shfl_xor(a1, 16);
    a2 += __shfl_xor(a2, 16); a3 += __shfl_xor(a3, 16);
    a4 += __shfl_xor(a4, 16); a5 += __shfl_xor(a5, 16);
    a6 += __shfl_xor(a6, 16); a7 += __shfl_xor(a7, 16);
    a0 += __shfl_xor(a0, 32); a1 += __shfl_xor(a1, 32);
    a2 += __shfl_xor(a2, 32); a3 += __shfl_xor(a3, 32);
    a4 += __shfl_xor(a4, 32); a5 += __shfl_xor(a5, 32);
    a6 += __shfl_xor(a6, 32); a7 += __shfl_xor(a7, 32);
    if (g == 0) {
        const size_t o = (size_t)row * 128 + l16 * 8;
        uint4* px = (uint4*)((unsigned short*)x0 + o);
        const uint4 xu = *px;
        uint4 r;
        r.x = bfpack(sigmoidf_(bf_lo(xu.x) + a0), sigmoidf_(bf_hi(xu.x) + a1));
        r.y = bfpack(sigmoidf_(bf_lo(xu.y) + a2), sigmoidf_(bf_hi(xu.y) + a3));
        r.z = bfpack(sigmoidf_(bf_lo(xu.z) + a4), sigmoidf_(bf_hi(xu.z) + a5));
        r.w = bfpack(sigmoidf_(bf_lo(xu.w) + a6), sigmoidf_(bf_hi(xu.w) + a7));
        *px = r;
    }
}

// ---------------------------------------------------------------------------
extern "C" void kernel_launch(void* const* d_in, const int* in_sizes, int n_in,
                              void* d_out, int out_size, void* d_ws, size_t ws_size,
                              hipStream_t stream)
{
    const float* x0_in   = (const float*)d_in[0];
    const float* x1_in   = (const float*)d_in[1];
    const int*   node_idx = (const int*)d_in[2];
    const int*   he_idx   = (const int*)d_in[3];
    const float* inc_vals = (const float*)d_in[4];
    const float* W_enc   = (const float*)d_in[5];
    const float* b_enc   = (const float*)d_in[6];
    const float* W_msg0  = (const float*)d_in[7];
    const float* b_msg0  = (const float*)d_in[8];
    const float* W_msg1  = (const float*)d_in[9];
    const float* b_msg1  = (const float*)d_in[10];
    const float* W_out   = (const float*)d_in[11];
    const float* b_out   = (const float*)d_in[12];
    float* out = (float*)d_out;

    __hip_bfloat16* x0h    = (__hip_bfloat16*)d_ws;         // 12,800,000
    __hip_bfloat16* x1a    = x0h + 12800000;                //  6,400,000
    __hip_bfloat16* x1b    = x1a + 6400000;                 //  6,400,000
    __hip_bfloat16* mbuf   = x1b + 6400000;                 // 12,800,000
    __hip_bfloat16* m0_he  = mbuf + 12800000;               //  6,400,000
    __hip_bfloat16* Wt_enc = m0_he + 6400000;               // 32768
    __hip_bfloat16* Wt_m0  = Wt_enc + 32768;                // 32768
    __hip_bfloat16* Wt_m1  = Wt_m0 + 32768;                 // 65536
    __hip_bfloat16* Wt_out = Wt_m1 + 65536;                 // 6144
    int*  he_off    = (int*)(Wt_out + 6144);
    int*  node_off  = he_off + N_HE;
    int*  bsums     = node_off + N_NODES;                   // 256
    int*  he_rank   = bsums + 256;                          // 600k
    int*  node_rank = he_rank + N_INC;                      // 600k
    int2* he_edge   = (int2*)(node_rank + N_INC);
    int2* node_edge = he_edge + N_INC;

    // ---- CSR build ----
    zero_int_kernel<<<(N_HE + N_NODES + 255) / 256, 256, 0, stream>>>(
        he_off, N_HE + N_NODES);
    hist_kernel<<<(N_INC + 255) / 256, 256, 0, stream>>>(
        he_idx, node_idx, he_off, node_off, he_rank, node_rank, N_INC);
    const int scan_n = N_HE + N_NODES;
    const int scan_blocks = (scan_n + 1023) / 1024;          // 147
    scan1_kernel<<<scan_blocks, 256, 0, stream>>>(he_off, bsums, scan_n);
    scan2_kernel<<<1, 256, 0, stream>>>(bsums, scan_blocks);
    scan3_kernel<<<scan_blocks, 256, 0, stream>>>(he_off, bsums, scan_n);
    fill_kernel<<<(N_INC + 255) / 256, 256, 0, stream>>>(
        node_idx, he_idx, inc_vals, he_off, node_off, he_rank, node_rank,
        he_edge, node_edge, N_INC);

    // ---- weight prep ----
    wprep_kernel<<<536, 256, 0, stream>>>(W_enc, W_msg0, W_msg1, W_out,
                                          Wt_enc, Wt_m0, Wt_m1, Wt_out);

    // ---- encode ----
    gemm_mfma<256, 256, true><<<(N_NODES + 127) / 128, 256, 0, stream>>>(
        x0_in, nullptr, Wt_enc, b_enc, x0h, N_NODES, 0);
    gemm_mfma<256, 256, true><<<(N_HE + 127) / 128, 256, 0, stream>>>(
        x1_in, nullptr, Wt_enc, b_enc, x1a, N_HE, 0);

    __hip_bfloat16* x1cur = x1a;
    __hip_bfloat16* x1nxt = x1b;
    for (int l = 0; l < 2; ++l) {
        gemm_mfma<128, 128, false><<<(N_NODES + 127) / 128, 256, 0, stream>>>(
            x0h, nullptr, Wt_m0 + (size_t)l * 16384,
            b_msg0 + (size_t)l * 128, mbuf, N_NODES, 1);
        gather_he_kernel<<<(N_HE + 3) / 4, 256, 0, stream>>>(
            mbuf, x1cur, m0_he, x1nxt, he_off, he_edge, N_HE);
        gemm_mfma<256, 128, false><<<(N_HE + 127) / 128, 256, 0, stream>>>(
            x1cur, m0_he, Wt_m1 + (size_t)l * 32768,
            b_msg1 + (size_t)l * 128, mbuf, N_HE, 1);
        gather_node_kernel<<<(N_NODES + 3) / 4, 256, 0, stream>>>(
            mbuf, x0h, node_off, node_edge, N_NODES);
        __hip_bfloat16* t = x1cur; x1cur = x1nxt; x1nxt = t;
    }

    out_gemm_mfma<<<(N_NODES + 63) / 64, 256, 0, stream>>>(
        x0h, Wt_out, b_out, out, N_NODES);
}

// Round 2
// 642.287 us; speedup vs baseline: 1.0085x; 1.0085x over previous
//
#include <hip/hip_runtime.h>
#include <hip/hip_bf16.h>
#include <math.h>

#define N_NODES 100000
#define N_HE    50000
#define N_INC   600000
#define D_IN    256
#define D_H     128
#define N_CLASSES 40

typedef __attribute__((ext_vector_type(8))) short short8;
typedef __attribute__((ext_vector_type(4))) float f32x4;

__device__ __forceinline__ float sigmoidf_(float x) {
    return 1.0f / (1.0f + expf(-x));
}

__device__ __forceinline__ short bfbits(float f) {
    __hip_bfloat16 h = __float2bfloat16(f);
    return *reinterpret_cast<short*>(&h);
}

__device__ __forceinline__ float bf_lo(unsigned u) { return __uint_as_float(u << 16); }
__device__ __forceinline__ float bf_hi(unsigned u) { return __uint_as_float(u & 0xffff0000u); }
__device__ __forceinline__ unsigned bfpack(float a, float b) {
    return (unsigned)(unsigned short)bfbits(a) | ((unsigned)(unsigned short)bfbits(b) << 16);
}

// async global->LDS, 16 B per lane; LDS dest is wave-uniform base + lane*16
__device__ __forceinline__ void gload_lds16(const void* g, void* l) {
    __builtin_amdgcn_global_load_lds(
        (const __attribute__((address_space(1))) unsigned int*)g,
        (__attribute__((address_space(3))) unsigned int*)l, 16, 0, 0);
}

// ---------------------------------------------------------------------------
// fp32 -> bf16 streaming convert (8 elems/thread/iter, grid-stride)
// ---------------------------------------------------------------------------
__global__ __launch_bounds__(256) void cvt_kernel(
    const float* __restrict__ in, unsigned short* __restrict__ out, int n8)
{
    const int stride = gridDim.x * 256;
    for (int i = blockIdx.x * 256 + threadIdx.x; i < n8; i += stride) {
        const float4 p = *(const float4*)(in + (size_t)i * 8);
        const float4 q = *(const float4*)(in + (size_t)i * 8 + 4);
        uint4 r;
        r.x = bfpack(p.x, p.y); r.y = bfpack(p.z, p.w);
        r.z = bfpack(q.x, q.y); r.w = bfpack(q.z, q.w);
        *(uint4*)(out + (size_t)i * 8) = r;
    }
}

// ---------------------------------------------------------------------------
// Staged MFMA GEMM: C(M x 128) = act( A @ W + bias ), bf16, fp32 acc.
// A tile (128 rows x 128 k) and B tile (128 n x 128 k) staged in LDS via
// global_load_lds (linear dest, XOR-swizzled source chunk ^= row&7; read
// applies the same XOR -> 2-way bank conflicts only).
// Block = 256 thr (4 waves 2x2), wave tile 64x64.  LDS 64 KB -> 2 blk/CU.
// KT = number of 128-wide K tiles. SPLIT: tile h sources (h ? A2 : A1),
// each with 128-elem rows; !SPLIT: A1 rows of KT*128 elems, tile offset.
// ---------------------------------------------------------------------------
template<int KT, bool SPLIT>
__global__ __launch_bounds__(256) void gemm_st(
    const __hip_bfloat16* __restrict__ A1,
    const __hip_bfloat16* __restrict__ A2,
    const __hip_bfloat16* __restrict__ Wt,   // 128 x (KT*128) bf16, n-major
    const float* __restrict__ bias,
    __hip_bfloat16* __restrict__ C,          // M x 128 bf16
    int M, int act)
{
    __shared__ uint4 smemv[4096];            // 65536 B
    char* const sA = (char*)smemv;           // 32768 B: [128 rows][16 x 16B]
    char* const sB = (char*)smemv + 32768;   // 32768 B: [128 n   ][16 x 16B]

    const int tid = threadIdx.x;
    const int wave = tid >> 6, lane = tid & 63;
    const int quad = lane >> 4, nn = lane & 15;
    const int wr = wave >> 1, wc = wave & 1;
    const int row_base = blockIdx.x * 128;
    const int col_base = wc * 64;

    f32x4 acc[4][4] = {};

    for (int h = 0; h < KT; ++h) {
        // ---- stage A: 2048 slots of 16 B; 8 calls/wave, 1 KB contiguous each
        const char* Asrc = (const char*)(SPLIT ? (h ? A2 : A1) : A1);
        const size_t astride = SPLIT ? 256 : (size_t)KT * 256;   // row bytes
        const size_t aoff = SPLIT ? 0 : (size_t)h * 256;
#pragma unroll
        for (int j = 0; j < 8; ++j) {
            const int sb = j * 4 + wave;          // slot-block 0..31
            const int s = sb * 64 + lane;         // slot 0..2047
            const int row = s >> 4, c = s & 15;
            int grow = row_base + row; if (grow >= M) grow = M - 1;
            gload_lds16(Asrc + (size_t)grow * astride + aoff + ((c ^ (row & 7)) * 16),
                        sA + sb * 1024);
        }
        // ---- stage B
#pragma unroll
        for (int j = 0; j < 8; ++j) {
            const int sb = j * 4 + wave;
            const int s = sb * 64 + lane;
            const int n = s >> 4, c = s & 15;
            gload_lds16((const char*)Wt + (size_t)n * (KT * 256) + (size_t)h * 256
                            + ((c ^ (n & 7)) * 16),
                        sB + sb * 1024);
        }
        __syncthreads();   // compiler drains vmcnt before barrier

#pragma unroll
        for (int ks = 0; ks < 4; ++ks) {
            short8 a[4], b[4];
#pragma unroll
            for (int rt = 0; rt < 4; ++rt) {
                const int row = wr * 64 + rt * 16 + nn;
                a[rt] = *(const short8*)(sA + row * 256 + (((ks * 4 + quad) ^ (row & 7)) * 16));
            }
#pragma unroll
            for (int ct = 0; ct < 4; ++ct) {
                const int n = col_base + ct * 16 + nn;
                b[ct] = *(const short8*)(sB + n * 256 + (((ks * 4 + quad) ^ (n & 7)) * 16));
            }
#pragma unroll
            for (int ct = 0; ct < 4; ++ct)
#pragma unroll
                for (int rt = 0; rt < 4; ++rt)
                    acc[rt][ct] = __builtin_amdgcn_mfma_f32_16x16x32_bf16(
                        a[rt], b[ct], acc[rt][ct], 0, 0, 0);
        }
        __syncthreads();   // protects sA/sB overwrite (and sC reuse below)
    }

    float bs[4];
#pragma unroll
    for (int ct = 0; ct < 4; ++ct) bs[ct] = bias[col_base + ct * 16 + nn];

    // ---- stage C tile into LDS (bf16, stride 136 -> 2-way only) ----
    constexpr int KP = 136;
    unsigned short* sC = (unsigned short*)smemv;
#pragma unroll
    for (int rt = 0; rt < 4; ++rt) {
#pragma unroll
        for (int i = 0; i < 4; ++i) {
            const int R = wr * 64 + rt * 16 + quad * 4 + i;
#pragma unroll
            for (int ct = 0; ct < 4; ++ct) {
                float v = acc[rt][ct][i] + bs[ct];
                if (act) v = sigmoidf_(v);
                sC[R * KP + col_base + ct * 16 + nn] = (unsigned short)bfbits(v);
            }
        }
    }
    __syncthreads();

    // ---- cooperative coalesced store: thread t -> row t/2, half t&1 ----
    {
        const int row = tid >> 1, half = tid & 1;
        const int gr = row_base + row;
        if (gr < M) {
            const unsigned short* srcp = sC + row * KP + half * 64;
            uint4* dstp = (uint4*)(C + (size_t)gr * 128 + half * 64);
#pragma unroll
            for (int j = 0; j < 8; ++j) dstp[j] = *(const uint4*)(srcp + j * 8);
        }
    }
}

// ---------------------------------------------------------------------------
// MFMA output GEMM: out(M x 40) = X(M x 128 bf16) @ W + b, fp32 out.
// X tile (64 rows) staged via global_load_lds with the same XOR swizzle.
// ---------------------------------------------------------------------------
__global__ __launch_bounds__(256) void out_gemm_mfma(
    const __hip_bfloat16* __restrict__ X,
    const __hip_bfloat16* __restrict__ Wt,   // 48 x 128 bf16 (n-major, padded)
    const float* __restrict__ b, float* __restrict__ out, int M)
{
    constexpr int KP = 136;
    __shared__ uint4 sXv[1024];              // 16384 B: [64 rows][16 x 16B]
    __shared__ __hip_bfloat16 sW[48 * KP];
    __shared__ float sB[48];
    __shared__ float sO[64 * 44];            // 11264 B

    char* const sX = (char*)sXv;
    const int tid = threadIdx.x;
    const int wave = tid >> 6, lane = tid & 63;

    // stage X: 1024 slots, 4 calls/wave
#pragma unroll
    for (int j = 0; j < 4; ++j) {
        const int sb = j * 4 + wave;          // 0..15
        const int s = sb * 64 + lane;         // 0..1023
        const int row = s >> 4, c = s & 15;
        int grow = blockIdx.x * 64 + row; if (grow >= M) grow = M - 1;
        gload_lds16((const char*)X + (size_t)grow * 256 + ((c ^ (row & 7)) * 16),
                    sX + sb * 1024);
    }
    for (int c = tid; c < 48 * 16; c += 256) {
        const int n = c >> 4, ko = (c & 15) * 8;
        *(uint4*)&sW[n * KP + ko] = *(const uint4*)&Wt[n * 128 + ko];
    }
    if (tid < 48) sB[tid] = (tid < 40) ? b[tid] : 0.0f;
    __syncthreads();

    const int quad = lane >> 4, nn = lane & 15;

    f32x4 acc[3] = {};
#pragma unroll
    for (int ks = 0; ks < 4; ++ks) {
        const int rowl = wave * 16 + nn;
        const short8 a = *(const short8*)(sX + rowl * 256 + (((ks * 4 + quad) ^ (rowl & 7)) * 16));
#pragma unroll
        for (int ct = 0; ct < 3; ++ct) {
            const short8 bf = *(const short8*)&sW[(ct * 16 + nn) * KP + ks * 32 + quad * 8];
            acc[ct] = __builtin_amdgcn_mfma_f32_16x16x32_bf16(a, bf, acc[ct], 0, 0, 0);
        }
    }

    // stage into LDS
#pragma unroll
    for (int ct = 0; ct < 3; ++ct) {
        const int c = ct * 16 + nn;
        if (c < 40) {
#pragma unroll
            for (int i = 0; i < 4; ++i) {
                const int rl = wave * 16 + quad * 4 + i;
                sO[rl * 44 + c] = acc[ct][i] + sB[c];
            }
        }
    }
    __syncthreads();

    // cooperative store: 64 rows x 10 float4
    for (int c = tid; c < 640; c += 256) {
        const int row = c / 10, ch = c % 10;
        const int gr = blockIdx.x * 64 + row;
        if (gr < M)
            *(float4*)(out + (size_t)gr * 40 + ch * 4) =
                *(const float4*)(sO + row * 44 + ch * 4);
    }
}

// ---------------------------------------------------------------------------
// Weight prep: fp32 -> bf16 transposed Wt[n][k] for enc/m0/m1/out.
// ---------------------------------------------------------------------------
__global__ __launch_bounds__(256) void wprep_kernel(
    const float* __restrict__ We, const float* __restrict__ Wm0,
    const float* __restrict__ Wm1, const float* __restrict__ Wout,
    __hip_bfloat16* __restrict__ Wt_enc, __hip_bfloat16* __restrict__ Wt_m0,
    __hip_bfloat16* __restrict__ Wt_m1, __hip_bfloat16* __restrict__ Wt_out)
{
    const int i = blockIdx.x * 256 + threadIdx.x;  // 0..137215
    if (i < 32768) {
        const int n = i >> 8, k = i & 255;
        Wt_enc[n * 256 + k] = __float2bfloat16(We[k * 128 + n]);
    } else if (i < 65536) {
        int j = i - 32768; const int l = j >> 14; j &= 16383;
        const int n = j >> 7, k = j & 127;
        Wt_m0[l * 16384 + n * 128 + k] = __float2bfloat16(Wm0[l * 16384 + k * 128 + n]);
    } else if (i < 131072) {
        int j = i - 65536; const int l = j >> 15; j &= 32767;
        const int n = j >> 8, k = j & 255;
        Wt_m1[l * 32768 + n * 256 + k] = __float2bfloat16(Wm1[l * 32768 + k * 128 + n]);
    } else {
        const int j = i - 131072;
        const int n = j >> 7, k = j & 127;
        Wt_out[n * 128 + k] = (n < 40) ? __float2bfloat16(Wout[k * 40 + n])
                                       : __float2bfloat16(0.0f);
    }
}

// ---------------------------------------------------------------------------
// CSR build (atomic-free fill: hist captures per-edge rank)
// ---------------------------------------------------------------------------
__global__ __launch_bounds__(256) void zero_int_kernel(int* __restrict__ p, int n)
{
    const int i = blockIdx.x * 256 + threadIdx.x;
    if (i < n) p[i] = 0;
}

__global__ __launch_bounds__(256) void hist_kernel(
    const int* __restrict__ he_idx, const int* __restrict__ node_idx,
    int* __restrict__ he_cnt, int* __restrict__ node_cnt,
    int* __restrict__ he_rank, int* __restrict__ node_rank, int n)
{
    const int i = blockIdx.x * 256 + threadIdx.x;
    if (i < n) {
        he_rank[i] = atomicAdd(&he_cnt[he_idx[i]], 1);
        node_rank[i] = atomicAdd(&node_cnt[node_idx[i]], 1);
    }
}

__global__ __launch_bounds__(256) void scan1_kernel(
    int* __restrict__ data, int* __restrict__ bsums, int n)
{
    __shared__ int s[256];
    const int t = threadIdx.x;
    const int base = blockIdx.x * 1024 + t * 4;
    int4 v = make_int4(0, 0, 0, 0);
    if (base < n) v = *(const int4*)(data + base);
    s[t] = v.x + v.y + v.z + v.w;
    __syncthreads();
    for (int d = 1; d < 256; d <<= 1) {
        const int u = (t >= d) ? s[t - d] : 0;
        __syncthreads();
        s[t] += u;
        __syncthreads();
    }
    if (t == 255) bsums[blockIdx.x] = s[255];
    int e = t ? s[t - 1] : 0;
    if (base < n) {
        int4 o;
        o.x = e; e += v.x; o.y = e; e += v.y; o.z = e; e += v.z; o.w = e;
        *(int4*)(data + base) = o;
    }
}

__global__ __launch_bounds__(256) void scan2_kernel(int* __restrict__ bsums, int nb)
{
    __shared__ int s[256];
    const int t = threadIdx.x;
    const int v = (t < nb) ? bsums[t] : 0;
    s[t] = v;
    __syncthreads();
    for (int d = 1; d < 256; d <<= 1) {
        const int u = (t >= d) ? s[t - d] : 0;
        __syncthreads();
        s[t] += u;
        __syncthreads();
    }
    if (t < nb) bsums[t] = s[t] - v;
}

__global__ __launch_bounds__(256) void scan3_kernel(
    int* __restrict__ data, const int* __restrict__ bsums, int n)
{
    const int base = blockIdx.x * 1024 + threadIdx.x * 4;
    if (base >= n) return;
    const int adj = bsums[blockIdx.x] - ((base >= N_HE) ? N_INC : 0);
    int4 v = *(int4*)(data + base);
    v.x += adj; v.y += adj; v.z += adj; v.w += adj;
    *(int4*)(data + base) = v;
}

// fill packed edges at off[dest]+rank[e] — NO atomics
__global__ __launch_bounds__(256) void fill_kernel(
    const int* __restrict__ node_idx, const int* __restrict__ he_idx,
    const float* __restrict__ vals,
    const int* __restrict__ he_off, const int* __restrict__ node_off,
    const int* __restrict__ he_rank, const int* __restrict__ node_rank,
    int2* __restrict__ he_edge, int2* __restrict__ node_edge, int n)
{
    const int e = blockIdx.x * 256 + threadIdx.x;
    if (e >= n) return;
    const int hn = he_idx[e], nd = node_idx[e];
    const int vb = __float_as_int(vals[e]);
    he_edge[he_off[hn] + he_rank[e]] = make_int2(nd, vb);
    node_edge[node_off[nd] + node_rank[e]] = make_int2(hn, vb);
}

// ---------------------------------------------------------------------------
// Fused he-gather (4 edges/wave-iter, 16B/lane): agg = sum val*m0[src];
// writes m0_he AND x1_next = sigmoid(x1_cur + agg). Offsets EXCLUSIVE.
// ---------------------------------------------------------------------------
__global__ __launch_bounds__(256) void gather_he_kernel(
    const __hip_bfloat16* __restrict__ msrc,
    const __hip_bfloat16* __restrict__ x1cur,
    __hip_bfloat16* __restrict__ m0_he,
    __hip_bfloat16* __restrict__ x1next,
    const int* __restrict__ off, const int2* __restrict__ edges, int n_seg)
{
    const int wave = threadIdx.x >> 6;
    const int lane = threadIdx.x & 63;
    const int row = blockIdx.x * 4 + wave;
    if (row >= n_seg) return;
    const int start = off[row];
    const int end = (row + 1 < n_seg) ? off[row + 1] : N_INC;
    const int g = lane >> 4;
    const int l16 = lane & 15;
    float a0 = 0.f, a1 = 0.f, a2 = 0.f, a3 = 0.f;
    float a4 = 0.f, a5 = 0.f, a6 = 0.f, a7 = 0.f;
    const unsigned short* s16 = (const unsigned short*)msrc;
    for (int e = start; e < end; e += 4) {
        const int ee = e + g;
        const int2 ed = (ee < end) ? edges[ee] : make_int2(0, 0);
        const float v = __int_as_float(ed.y);        // 0 for padding slots
        const uint4 u = *(const uint4*)(s16 + (size_t)ed.x * 128 + l16 * 8);
        a0 += bf_lo(u.x) * v; a1 += bf_hi(u.x) * v;
        a2 += bf_lo(u.y) * v; a3 += bf_hi(u.y) * v;
        a4 += bf_lo(u.z) * v; a5 += bf_hi(u.z) * v;
        a6 += bf_lo(u.w) * v; a7 += bf_hi(u.w) * v;
    }
    a0 += __shfl_xor(a0, 16); a1 += __shfl_xor(a1, 16);
    a2 += __shfl_xor(a2, 16); a3 += __shfl_xor(a3, 16);
    a4 += __shfl_xor(a4, 16); a5 += __shfl_xor(a5, 16);
    a6 += __shfl_xor(a6, 16); a7 += __shfl_xor(a7, 16);
    a0 += __shfl_xor(a0, 32); a1 += __shfl_xor(a1, 32);
    a2 += __shfl_xor(a2, 32); a3 += __shfl_xor(a3, 32);
    a4 += __shfl_xor(a4, 32); a5 += __shfl_xor(a5, 32);
    a6 += __shfl_xor(a6, 32); a7 += __shfl_xor(a7, 32);
    if (g == 0) {
        const size_t o = (size_t)row * 128 + l16 * 8;
        uint4 mg;
        mg.x = bfpack(a0, a1); mg.y = bfpack(a2, a3);
        mg.z = bfpack(a4, a5); mg.w = bfpack(a6, a7);
        *(uint4*)((unsigned short*)m0_he + o) = mg;
        const uint4 xu = *(const uint4*)((const unsigned short*)x1cur + o);
        uint4 r;
        r.x = bfpack(sigmoidf_(bf_lo(xu.x) + a0), sigmoidf_(bf_hi(xu.x) + a1));
        r.y = bfpack(sigmoidf_(bf_lo(xu.y) + a2), sigmoidf_(bf_hi(xu.y) + a3));
        r.z = bfpack(sigmoidf_(bf_lo(xu.z) + a4), sigmoidf_(bf_hi(xu.z) + a5));
        r.w = bfpack(sigmoidf_(bf_lo(xu.w) + a6), sigmoidf_(bf_hi(xu.w) + a7));
        *(uint4*)((unsigned short*)x1next + o) = r;
    }
}

// ---------------------------------------------------------------------------
// Fused node-gather (4 edges/wave-iter, 16B/lane): x0 = sigmoid(x0 + agg).
// ---------------------------------------------------------------------------
__global__ __launch_bounds__(256) void gather_node_kernel(
    const __hip_bfloat16* __restrict__ msrc,
    __hip_bfloat16* __restrict__ x0,
    const int* __restrict__ off, const int2* __restrict__ edges, int n_seg)
{
    const int wave = threadIdx.x >> 6;
    const int lane = threadIdx.x & 63;
    const int row = blockIdx.x * 4 + wave;
    if (row >= n_seg) return;
    const int start = off[row];
    const int end = (row + 1 < n_seg) ? off[row + 1] : N_INC;
    const int g = lane >> 4;
    const int l16 = lane & 15;
    float a0 = 0.f, a1 = 0.f, a2 = 0.f, a3 = 0.f;
    float a4 = 0.f, a5 = 0.f, a6 = 0.f, a7 = 0.f;
    const unsigned short* s16 = (const unsigned short*)msrc;
    for (int e = start; e < end; e += 4) {
        const int ee = e + g;
        const int2 ed = (ee < end) ? edges[ee] : make_int2(0, 0);
        const float v = __int_as_float(ed.y);
        const uint4 u = *(const uint4*)(s16 + (size_t)ed.x * 128 + l16 * 8);
        a0 += bf_lo(u.x) * v; a1 += bf_hi(u.x) * v;
        a2 += bf_lo(u.y) * v; a3 += bf_hi(u.y) * v;
        a4 += bf_lo(u.z) * v; a5 += bf_hi(u.z) * v;
        a6 += bf_lo(u.w) * v; a7 += bf_hi(u.w) * v;
    }
    a0 += __shfl_xor(a0, 16); a1 += __shfl_xor(a1, 16);
    a2 += __shfl_xor(a2, 16); a3 += __shfl_xor(a3, 16);
    a4 += __shfl_xor(a4, 16); a5 += __shfl_xor(a5, 16);
    a6 += __shfl_xor(a6, 16); a7 += __shfl_xor(a7, 16);
    a0 += __shfl_xor(a0, 32); a1 += __shfl_xor(a1, 32);
    a2 += __shfl_xor(a2, 32); a3 += __shfl_xor(a3, 32);
    a4 += __shfl_xor(a4, 32); a5 += __shfl_xor(a5, 32);
    a6 += __shfl_xor(a6, 32); a7 += __shfl_xor(a7, 32);
    if (g == 0) {
        const size_t o = (size_t)row * 128 + l16 * 8;
        uint4* px = (uint4*)((unsigned short*)x0 + o);
        const uint4 xu = *px;
        uint4 r;
        r.x = bfpack(sigmoidf_(bf_lo(xu.x) + a0), sigmoidf_(bf_hi(xu.x) + a1));
        r.y = bfpack(sigmoidf_(bf_lo(xu.y) + a2), sigmoidf_(bf_hi(xu.y) + a3));
        r.z = bfpack(sigmoidf_(bf_lo(xu.z) + a4), sigmoidf_(bf_hi(xu.z) + a5));
        r.w = bfpack(sigmoidf_(bf_lo(xu.w) + a6), sigmoidf_(bf_hi(xu.w) + a7));
        *px = r;
    }
}

// ---------------------------------------------------------------------------
extern "C" void kernel_launch(void* const* d_in, const int* in_sizes, int n_in,
                              void* d_out, int out_size, void* d_ws, size_t ws_size,
                              hipStream_t stream)
{
    const float* x0_in   = (const float*)d_in[0];
    const float* x1_in   = (const float*)d_in[1];
    const int*   node_idx = (const int*)d_in[2];
    const int*   he_idx   = (const int*)d_in[3];
    const float* inc_vals = (const float*)d_in[4];
    const float* W_enc   = (const float*)d_in[5];
    const float* b_enc   = (const float*)d_in[6];
    const float* W_msg0  = (const float*)d_in[7];
    const float* b_msg0  = (const float*)d_in[8];
    const float* W_msg1  = (const float*)d_in[9];
    const float* b_msg1  = (const float*)d_in[10];
    const float* W_out   = (const float*)d_in[11];
    const float* b_out   = (const float*)d_in[12];
    float* out = (float*)d_out;

    __hip_bfloat16* x0h    = (__hip_bfloat16*)d_ws;         // 12,800,000
    __hip_bfloat16* x1a    = x0h + 12800000;                //  6,400,000
    __hip_bfloat16* x1b    = x1a + 6400000;                 //  6,400,000
    __hip_bfloat16* mbuf   = x1b + 6400000;                 // 12,800,000
    __hip_bfloat16* m0_he  = mbuf + 12800000;               //  6,400,000
    __hip_bfloat16* Wt_enc = m0_he + 6400000;               // 32768
    __hip_bfloat16* Wt_m0  = Wt_enc + 32768;                // 32768
    __hip_bfloat16* Wt_m1  = Wt_m0 + 32768;                 // 65536
    __hip_bfloat16* Wt_out = Wt_m1 + 65536;                 // 6144
    int*  he_off    = (int*)(Wt_out + 6144);
    int*  node_off  = he_off + N_HE;
    int*  bsums     = node_off + N_NODES;                   // 256
    int*  he_rank   = bsums + 256;                          // 600k
    int*  node_rank = he_rank + N_INC;                      // 600k
    int2* he_edge   = (int2*)(node_rank + N_INC);
    int2* node_edge = he_edge + N_INC;

    // scratch bf16 copies of encode inputs: reuse loop buffers (dead here).
    // x0bf needs 25.6M shorts: spans x1b+mbuf+m0_he exactly.
    __hip_bfloat16* x0bf = x1b;          // 25,600,000 shorts
    __hip_bfloat16* x1bf = x1b;          // 12,800,000 shorts (reused after)

    // ---- CSR build ----
    zero_int_kernel<<<(N_HE + N_NODES + 255) / 256, 256, 0, stream>>>(
        he_off, N_HE + N_NODES);
    hist_kernel<<<(N_INC + 255) / 256, 256, 0, stream>>>(
        he_idx, node_idx, he_off, node_off, he_rank, node_rank, N_INC);
    const int scan_n = N_HE + N_NODES;
    const int scan_blocks = (scan_n + 1023) / 1024;          // 147
    scan1_kernel<<<scan_blocks, 256, 0, stream>>>(he_off, bsums, scan_n);
    scan2_kernel<<<1, 256, 0, stream>>>(bsums, scan_blocks);
    scan3_kernel<<<scan_blocks, 256, 0, stream>>>(he_off, bsums, scan_n);
    fill_kernel<<<(N_INC + 255) / 256, 256, 0, stream>>>(
        node_idx, he_idx, inc_vals, he_off, node_off, he_rank, node_rank,
        he_edge, node_edge, N_INC);

    // ---- weight prep ----
    wprep_kernel<<<536, 256, 0, stream>>>(W_enc, W_msg0, W_msg1, W_out,
                                          Wt_enc, Wt_m0, Wt_m1, Wt_out);

    // ---- encode: cvt fp32->bf16, then staged bf16 gemm ----
    cvt_kernel<<<2048, 256, 0, stream>>>(x0_in, (unsigned short*)x0bf, 3200000);
    gemm_st<2, false><<<(N_NODES + 127) / 128, 256, 0, stream>>>(
        x0bf, nullptr, Wt_enc, b_enc, x0h, N_NODES, 0);
    cvt_kernel<<<2048, 256, 0, stream>>>(x1_in, (unsigned short*)x1bf, 1600000);
    gemm_st<2, false><<<(N_HE + 127) / 128, 256, 0, stream>>>(
        x1bf, nullptr, Wt_enc, b_enc, x1a, N_HE, 0);

    __hip_bfloat16* x1cur = x1a;
    __hip_bfloat16* x1nxt = x1b;
    for (int l = 0; l < 2; ++l) {
        gemm_st<1, false><<<(N_NODES + 127) / 128, 256, 0, stream>>>(
            x0h, nullptr, Wt_m0 + (size_t)l * 16384,
            b_msg0 + (size_t)l * 128, mbuf, N_NODES, 1);
        gather_he_kernel<<<(N_HE + 3) / 4, 256, 0, stream>>>(
            mbuf, x1cur, m0_he, x1nxt, he_off, he_edge, N_HE);
        gemm_st<2, true><<<(N_HE + 127) / 128, 256, 0, stream>>>(
            x1cur, m0_he, Wt_m1 + (size_t)l * 32768,
            b_msg1 + (size_t)l * 128, mbuf, N_HE, 1);
        gather_node_kernel<<<(N_NODES + 3) / 4, 256, 0, stream>>>(
            mbuf, x0h, node_off, node_edge, N_NODES);
        __hip_bfloat16* t = x1cur; x1cur = x1nxt; x1nxt = t;
    }

    out_gemm_mfma<<<(N_NODES + 63) / 64, 256, 0, stream>>>(
        x0h, Wt_out, b_out, out, N_NODES);
}

// Round 3
// 572.437 us; speedup vs baseline: 1.1316x; 1.1220x over previous
//
#include <hip/hip_runtime.h>
#include <hip/hip_bf16.h>
#include <math.h>

#define N_NODES 100000
#define N_HE    50000
#define N_INC   600000
#define D_IN    256
#define D_H     128
#define N_CLASSES 40

typedef __attribute__((ext_vector_type(8))) short short8;
typedef __attribute__((ext_vector_type(4))) float f32x4;

// fast sigmoid: v_exp-based, ~4 inst. Error ~1e-6 rel, invisible under bf16.
__device__ __forceinline__ float sigmoidf_(float x) {
    return __builtin_amdgcn_rcpf(1.0f + __expf(-x));
}

__device__ __forceinline__ short bfbits(float f) {
    __hip_bfloat16 h = __float2bfloat16(f);
    return *reinterpret_cast<short*>(&h);
}

__device__ __forceinline__ float bf_lo(unsigned u) { return __uint_as_float(u << 16); }
__device__ __forceinline__ float bf_hi(unsigned u) { return __uint_as_float(u & 0xffff0000u); }
__device__ __forceinline__ unsigned bfpack(float a, float b) {
    return (unsigned)(unsigned short)bfbits(a) | ((unsigned)(unsigned short)bfbits(b) << 16);
}

// async global->LDS, 16 B per lane; LDS dest is wave-uniform base + lane*16
__device__ __forceinline__ void gload_lds16(const void* g, void* l) {
    __builtin_amdgcn_global_load_lds(
        (const __attribute__((address_space(1))) unsigned int*)g,
        (__attribute__((address_space(3))) unsigned int*)l, 16, 0, 0);
}

// ---------------------------------------------------------------------------
// fp32 -> bf16 streaming convert (8 elems/thread/iter, grid-stride)
// ---------------------------------------------------------------------------
__global__ __launch_bounds__(256) void cvt_kernel(
    const float* __restrict__ in, unsigned short* __restrict__ out, int n8)
{
    const int stride = gridDim.x * 256;
    for (int i = blockIdx.x * 256 + threadIdx.x; i < n8; i += stride) {
        const float4 p = *(const float4*)(in + (size_t)i * 8);
        const float4 q = *(const float4*)(in + (size_t)i * 8 + 4);
        uint4 r;
        r.x = bfpack(p.x, p.y); r.y = bfpack(p.z, p.w);
        r.z = bfpack(q.x, q.y); r.w = bfpack(q.z, q.w);
        *(uint4*)(out + (size_t)i * 8) = r;
    }
}

// ---------------------------------------------------------------------------
// Staged MFMA GEMM: C(M x 128) = act( A @ W + bias ), bf16, fp32 acc.
// A tile (128 rows x 128 k) and B tile (128 n x 128 k) staged in LDS via
// global_load_lds (linear dest, XOR-swizzled source chunk ^= row&7; read
// applies the same XOR -> 2-way bank conflicts only).
// Block = 256 thr (4 waves 2x2), wave tile 64x64.  LDS 64 KB -> 2 blk/CU.
// ---------------------------------------------------------------------------
template<int KT, bool SPLIT>
__global__ __launch_bounds__(256) void gemm_st(
    const __hip_bfloat16* __restrict__ A1,
    const __hip_bfloat16* __restrict__ A2,
    const __hip_bfloat16* __restrict__ Wt,   // 128 x (KT*128) bf16, n-major
    const float* __restrict__ bias,
    __hip_bfloat16* __restrict__ C,          // M x 128 bf16
    int M, int act)
{
    __shared__ uint4 smemv[4096];            // 65536 B
    char* const sA = (char*)smemv;           // 32768 B: [128 rows][16 x 16B]
    char* const sB = (char*)smemv + 32768;   // 32768 B: [128 n   ][16 x 16B]

    const int tid = threadIdx.x;
    const int wave = tid >> 6, lane = tid & 63;
    const int quad = lane >> 4, nn = lane & 15;
    const int wr = wave >> 1, wc = wave & 1;
    const int row_base = blockIdx.x * 128;
    const int col_base = wc * 64;

    f32x4 acc[4][4] = {};

    for (int h = 0; h < KT; ++h) {
        const char* Asrc = (const char*)(SPLIT ? (h ? A2 : A1) : A1);
        const size_t astride = SPLIT ? 256 : (size_t)KT * 256;   // row bytes
        const size_t aoff = SPLIT ? 0 : (size_t)h * 256;
#pragma unroll
        for (int j = 0; j < 8; ++j) {
            const int sb = j * 4 + wave;          // slot-block 0..31
            const int s = sb * 64 + lane;         // slot 0..2047
            const int row = s >> 4, c = s & 15;
            int grow = row_base + row; if (grow >= M) grow = M - 1;
            gload_lds16(Asrc + (size_t)grow * astride + aoff + ((c ^ (row & 7)) * 16),
                        sA + sb * 1024);
        }
#pragma unroll
        for (int j = 0; j < 8; ++j) {
            const int sb = j * 4 + wave;
            const int s = sb * 64 + lane;
            const int n = s >> 4, c = s & 15;
            gload_lds16((const char*)Wt + (size_t)n * (KT * 256) + (size_t)h * 256
                            + ((c ^ (n & 7)) * 16),
                        sB + sb * 1024);
        }
        __syncthreads();   // compiler drains vmcnt before barrier

#pragma unroll
        for (int ks = 0; ks < 4; ++ks) {
            short8 a[4], b[4];
#pragma unroll
            for (int rt = 0; rt < 4; ++rt) {
                const int row = wr * 64 + rt * 16 + nn;
                a[rt] = *(const short8*)(sA + row * 256 + (((ks * 4 + quad) ^ (row & 7)) * 16));
            }
#pragma unroll
            for (int ct = 0; ct < 4; ++ct) {
                const int n = col_base + ct * 16 + nn;
                b[ct] = *(const short8*)(sB + n * 256 + (((ks * 4 + quad) ^ (n & 7)) * 16));
            }
#pragma unroll
            for (int ct = 0; ct < 4; ++ct)
#pragma unroll
                for (int rt = 0; rt < 4; ++rt)
                    acc[rt][ct] = __builtin_amdgcn_mfma_f32_16x16x32_bf16(
                        a[rt], b[ct], acc[rt][ct], 0, 0, 0);
        }
        __syncthreads();   // protects sA/sB overwrite (and sC reuse below)
    }

    float bs[4];
#pragma unroll
    for (int ct = 0; ct < 4; ++ct) bs[ct] = bias[col_base + ct * 16 + nn];

    // ---- stage C tile into LDS (bf16, stride 136 -> 2-way only) ----
    constexpr int KP = 136;
    unsigned short* sC = (unsigned short*)smemv;
#pragma unroll
    for (int rt = 0; rt < 4; ++rt) {
#pragma unroll
        for (int i = 0; i < 4; ++i) {
            const int R = wr * 64 + rt * 16 + quad * 4 + i;
#pragma unroll
            for (int ct = 0; ct < 4; ++ct) {
                float v = acc[rt][ct][i] + bs[ct];
                if (act) v = sigmoidf_(v);
                sC[R * KP + col_base + ct * 16 + nn] = (unsigned short)bfbits(v);
            }
        }
    }
    __syncthreads();

    // ---- cooperative coalesced store: thread t -> row t/2, half t&1 ----
    {
        const int row = tid >> 1, half = tid & 1;
        const int gr = row_base + row;
        if (gr < M) {
            const unsigned short* srcp = sC + row * KP + half * 64;
            uint4* dstp = (uint4*)(C + (size_t)gr * 128 + half * 64);
#pragma unroll
            for (int j = 0; j < 8; ++j) dstp[j] = *(const uint4*)(srcp + j * 8);
        }
    }
}

// ---------------------------------------------------------------------------
// MFMA output GEMM: out(M x 40) = X(M x 128 bf16) @ W + b, fp32 out.
// ---------------------------------------------------------------------------
__global__ __launch_bounds__(256) void out_gemm_mfma(
    const __hip_bfloat16* __restrict__ X,
    const __hip_bfloat16* __restrict__ Wt,   // 48 x 128 bf16 (n-major, padded)
    const float* __restrict__ b, float* __restrict__ out, int M)
{
    constexpr int KP = 136;
    __shared__ uint4 sXv[1024];              // 16384 B: [64 rows][16 x 16B]
    __shared__ __hip_bfloat16 sW[48 * KP];
    __shared__ float sB[48];
    __shared__ float sO[64 * 44];            // 11264 B

    char* const sX = (char*)sXv;
    const int tid = threadIdx.x;
    const int wave = tid >> 6, lane = tid & 63;

    // stage X: 1024 slots, 4 calls/wave
#pragma unroll
    for (int j = 0; j < 4; ++j) {
        const int sb = j * 4 + wave;          // 0..15
        const int s = sb * 64 + lane;         // 0..1023
        const int row = s >> 4, c = s & 15;
        int grow = blockIdx.x * 64 + row; if (grow >= M) grow = M - 1;
        gload_lds16((const char*)X + (size_t)grow * 256 + ((c ^ (row & 7)) * 16),
                    sX + sb * 1024);
    }
    for (int c = tid; c < 48 * 16; c += 256) {
        const int n = c >> 4, ko = (c & 15) * 8;
        *(uint4*)&sW[n * KP + ko] = *(const uint4*)&Wt[n * 128 + ko];
    }
    if (tid < 48) sB[tid] = (tid < 40) ? b[tid] : 0.0f;
    __syncthreads();

    const int quad = lane >> 4, nn = lane & 15;

    f32x4 acc[3] = {};
#pragma unroll
    for (int ks = 0; ks < 4; ++ks) {
        const int rowl = wave * 16 + nn;
        const short8 a = *(const short8*)(sX + rowl * 256 + (((ks * 4 + quad) ^ (rowl & 7)) * 16));
#pragma unroll
        for (int ct = 0; ct < 3; ++ct) {
            const short8 bf = *(const short8*)&sW[(ct * 16 + nn) * KP + ks * 32 + quad * 8];
            acc[ct] = __builtin_amdgcn_mfma_f32_16x16x32_bf16(a, bf, acc[ct], 0, 0, 0);
        }
    }

    // stage into LDS
#pragma unroll
    for (int ct = 0; ct < 3; ++ct) {
        const int c = ct * 16 + nn;
        if (c < 40) {
#pragma unroll
            for (int i = 0; i < 4; ++i) {
                const int rl = wave * 16 + quad * 4 + i;
                sO[rl * 44 + c] = acc[ct][i] + sB[c];
            }
        }
    }
    __syncthreads();

    // cooperative store: 64 rows x 10 float4
    for (int c = tid; c < 640; c += 256) {
        const int row = c / 10, ch = c % 10;
        const int gr = blockIdx.x * 64 + row;
        if (gr < M)
            *(float4*)(out + (size_t)gr * 40 + ch * 4) =
                *(const float4*)(sO + row * 44 + ch * 4);
    }
}

// ---------------------------------------------------------------------------
// Weight prep: fp32 -> bf16 transposed Wt[n][k] for enc/m0/m1/out.
// ---------------------------------------------------------------------------
__global__ __launch_bounds__(256) void wprep_kernel(
    const float* __restrict__ We, const float* __restrict__ Wm0,
    const float* __restrict__ Wm1, const float* __restrict__ Wout,
    __hip_bfloat16* __restrict__ Wt_enc, __hip_bfloat16* __restrict__ Wt_m0,
    __hip_bfloat16* __restrict__ Wt_m1, __hip_bfloat16* __restrict__ Wt_out)
{
    const int i = blockIdx.x * 256 + threadIdx.x;  // 0..137215
    if (i < 32768) {
        const int n = i >> 8, k = i & 255;
        Wt_enc[n * 256 + k] = __float2bfloat16(We[k * 128 + n]);
    } else if (i < 65536) {
        int j = i - 32768; const int l = j >> 14; j &= 16383;
        const int n = j >> 7, k = j & 127;
        Wt_m0[l * 16384 + n * 128 + k] = __float2bfloat16(Wm0[l * 16384 + k * 128 + n]);
    } else if (i < 131072) {
        int j = i - 65536; const int l = j >> 15; j &= 32767;
        const int n = j >> 8, k = j & 255;
        Wt_m1[l * 32768 + n * 256 + k] = __float2bfloat16(Wm1[l * 32768 + k * 128 + n]);
    } else {
        const int j = i - 131072;
        const int n = j >> 7, k = j & 127;
        Wt_out[n * 128 + k] = (n < 40) ? __float2bfloat16(Wout[k * 40 + n])
                                       : __float2bfloat16(0.0f);
    }
}

// ---------------------------------------------------------------------------
// CSR build (atomic-free fill: hist captures per-edge rank)
// ---------------------------------------------------------------------------
__global__ __launch_bounds__(256) void zero_int_kernel(int* __restrict__ p, int n)
{
    const int i = blockIdx.x * 256 + threadIdx.x;
    if (i < n) p[i] = 0;
}

__global__ __launch_bounds__(256) void hist_kernel(
    const int* __restrict__ he_idx, const int* __restrict__ node_idx,
    int* __restrict__ he_cnt, int* __restrict__ node_cnt,
    int* __restrict__ he_rank, int* __restrict__ node_rank, int n)
{
    const int i = blockIdx.x * 256 + threadIdx.x;
    if (i < n) {
        he_rank[i] = atomicAdd(&he_cnt[he_idx[i]], 1);
        node_rank[i] = atomicAdd(&node_cnt[node_idx[i]], 1);
    }
}

__global__ __launch_bounds__(256) void scan1_kernel(
    int* __restrict__ data, int* __restrict__ bsums, int n)
{
    __shared__ int s[256];
    const int t = threadIdx.x;
    const int base = blockIdx.x * 1024 + t * 4;
    int4 v = make_int4(0, 0, 0, 0);
    if (base < n) v = *(const int4*)(data + base);
    s[t] = v.x + v.y + v.z + v.w;
    __syncthreads();
    for (int d = 1; d < 256; d <<= 1) {
        const int u = (t >= d) ? s[t - d] : 0;
        __syncthreads();
        s[t] += u;
        __syncthreads();
    }
    if (t == 255) bsums[blockIdx.x] = s[255];
    int e = t ? s[t - 1] : 0;
    if (base < n) {
        int4 o;
        o.x = e; e += v.x; o.y = e; e += v.y; o.z = e; e += v.z; o.w = e;
        *(int4*)(data + base) = o;
    }
}

__global__ __launch_bounds__(256) void scan2_kernel(int* __restrict__ bsums, int nb)
{
    __shared__ int s[256];
    const int t = threadIdx.x;
    const int v = (t < nb) ? bsums[t] : 0;
    s[t] = v;
    __syncthreads();
    for (int d = 1; d < 256; d <<= 1) {
        const int u = (t >= d) ? s[t - d] : 0;
        __syncthreads();
        s[t] += u;
        __syncthreads();
    }
    if (t < nb) bsums[t] = s[t] - v;
}

__global__ __launch_bounds__(256) void scan3_kernel(
    int* __restrict__ data, const int* __restrict__ bsums, int n)
{
    const int base = blockIdx.x * 1024 + threadIdx.x * 4;
    if (base >= n) return;
    const int adj = bsums[blockIdx.x] - ((base >= N_HE) ? N_INC : 0);
    int4 v = *(int4*)(data + base);
    v.x += adj; v.y += adj; v.z += adj; v.w += adj;
    *(int4*)(data + base) = v;
}

// fill packed edges at off[dest]+rank[e] — NO atomics
__global__ __launch_bounds__(256) void fill_kernel(
    const int* __restrict__ node_idx, const int* __restrict__ he_idx,
    const float* __restrict__ vals,
    const int* __restrict__ he_off, const int* __restrict__ node_off,
    const int* __restrict__ he_rank, const int* __restrict__ node_rank,
    int2* __restrict__ he_edge, int2* __restrict__ node_edge, int n)
{
    const int e = blockIdx.x * 256 + threadIdx.x;
    if (e >= n) return;
    const int hn = he_idx[e], nd = node_idx[e];
    const int vb = __float_as_int(vals[e]);
    he_edge[he_off[hn] + he_rank[e]] = make_int2(nd, vb);
    node_edge[node_off[nd] + node_rank[e]] = make_int2(hn, vb);
}

// ---------------------------------------------------------------------------
// Split butterfly reduction helper: input a0..a7 (cols l16*8+i, partial over
// edge-slot groups), output s0,s1 = full sums for cols l16*8+2g, +1.
// 6 shfl + 6 add + selects (vs 16 shfl + 16 add + post-select).
// ---------------------------------------------------------------------------
__device__ __forceinline__ void reduce_groups(
    int lane, float a0, float a1, float a2, float a3,
    float a4, float a5, float a6, float a7, float& s0, float& s1)
{
    const bool hb = (lane & 32) != 0;    // bit1 of group g = lane>>4
    float t0 = hb ? a0 : a4;
    float t1 = hb ? a1 : a5;
    float t2 = hb ? a2 : a6;
    float t3 = hb ? a3 : a7;
    float r0 = __shfl_xor(t0, 32);
    float r1 = __shfl_xor(t1, 32);
    float r2 = __shfl_xor(t2, 32);
    float r3 = __shfl_xor(t3, 32);
    float e0 = (hb ? a4 : a0) + r0;
    float e1 = (hb ? a5 : a1) + r1;
    float e2 = (hb ? a6 : a2) + r2;
    float e3 = (hb ? a7 : a3) + r3;
    const bool lb = (lane & 16) != 0;    // bit0 of group
    float u0 = lb ? e0 : e2;
    float u1 = lb ? e1 : e3;
    float q0 = __shfl_xor(u0, 16);
    float q1 = __shfl_xor(u1, 16);
    s0 = (lb ? e2 : e0) + q0;
    s1 = (lb ? e3 : e1) + q1;
}

// ---------------------------------------------------------------------------
// Fused he-gather (4 edges/wave-iter, 16B/lane): agg = sum val*m0[src];
// writes m0_he AND x1_next = sigmoid(x1_cur + agg). Offsets EXCLUSIVE.
// Epilogue: all 64 lanes each finalize 2 cols (u32 stores, contiguous 256B).
// ---------------------------------------------------------------------------
__global__ __launch_bounds__(256) void gather_he_kernel(
    const __hip_bfloat16* __restrict__ msrc,
    const __hip_bfloat16* __restrict__ x1cur,
    __hip_bfloat16* __restrict__ m0_he,
    __hip_bfloat16* __restrict__ x1next,
    const int* __restrict__ off, const int2* __restrict__ edges, int n_seg)
{
    const int wave = threadIdx.x >> 6;
    const int lane = threadIdx.x & 63;
    const int row = blockIdx.x * 4 + wave;
    if (row >= n_seg) return;
    const int start = off[row];
    const int end = (row + 1 < n_seg) ? off[row + 1] : N_INC;
    const int g = lane >> 4;
    const int l16 = lane & 15;
    float a0 = 0.f, a1 = 0.f, a2 = 0.f, a3 = 0.f;
    float a4 = 0.f, a5 = 0.f, a6 = 0.f, a7 = 0.f;
    const unsigned short* s16 = (const unsigned short*)msrc;
    int e = start;
    for (; e + 4 <= end; e += 4) {                 // full quads: no bounds check
        const int2 ed = edges[e + g];
        const float v = __int_as_float(ed.y);
        const uint4 u = *(const uint4*)(s16 + (size_t)ed.x * 128 + l16 * 8);
        a0 += bf_lo(u.x) * v; a1 += bf_hi(u.x) * v;
        a2 += bf_lo(u.y) * v; a3 += bf_hi(u.y) * v;
        a4 += bf_lo(u.z) * v; a5 += bf_hi(u.z) * v;
        a6 += bf_lo(u.w) * v; a7 += bf_hi(u.w) * v;
    }
    if (e < end) {                                 // masked tail
        const int ee = e + g;
        const int2 ed = (ee < end) ? edges[ee] : make_int2(0, 0);
        const float v = __int_as_float(ed.y);
        const uint4 u = *(const uint4*)(s16 + (size_t)ed.x * 128 + l16 * 8);
        a0 += bf_lo(u.x) * v; a1 += bf_hi(u.x) * v;
        a2 += bf_lo(u.y) * v; a3 += bf_hi(u.y) * v;
        a4 += bf_lo(u.z) * v; a5 += bf_hi(u.z) * v;
        a6 += bf_lo(u.w) * v; a7 += bf_hi(u.w) * v;
    }
    float s0, s1;
    reduce_groups(lane, a0, a1, a2, a3, a4, a5, a6, a7, s0, s1);
    // lane owns cols l16*8+2g, +1  ->  u32 col index l16*4+g
    const size_t o32 = (size_t)row * 64 + l16 * 4 + g;
    ((unsigned*)m0_he)[o32] = bfpack(s0, s1);
    const unsigned xu = ((const unsigned*)x1cur)[o32];
    ((unsigned*)x1next)[o32] =
        bfpack(sigmoidf_(bf_lo(xu) + s0), sigmoidf_(bf_hi(xu) + s1));
}

// ---------------------------------------------------------------------------
// Fused node-gather (4 edges/wave-iter, 16B/lane): x0 = sigmoid(x0 + agg).
// ---------------------------------------------------------------------------
__global__ __launch_bounds__(256) void gather_node_kernel(
    const __hip_bfloat16* __restrict__ msrc,
    __hip_bfloat16* __restrict__ x0,
    const int* __restrict__ off, const int2* __restrict__ edges, int n_seg)
{
    const int wave = threadIdx.x >> 6;
    const int lane = threadIdx.x & 63;
    const int row = blockIdx.x * 4 + wave;
    if (row >= n_seg) return;
    const int start = off[row];
    const int end = (row + 1 < n_seg) ? off[row + 1] : N_INC;
    const int g = lane >> 4;
    const int l16 = lane & 15;
    float a0 = 0.f, a1 = 0.f, a2 = 0.f, a3 = 0.f;
    float a4 = 0.f, a5 = 0.f, a6 = 0.f, a7 = 0.f;
    const unsigned short* s16 = (const unsigned short*)msrc;
    int e = start;
    for (; e + 4 <= end; e += 4) {
        const int2 ed = edges[e + g];
        const float v = __int_as_float(ed.y);
        const uint4 u = *(const uint4*)(s16 + (size_t)ed.x * 128 + l16 * 8);
        a0 += bf_lo(u.x) * v; a1 += bf_hi(u.x) * v;
        a2 += bf_lo(u.y) * v; a3 += bf_hi(u.y) * v;
        a4 += bf_lo(u.z) * v; a5 += bf_hi(u.z) * v;
        a6 += bf_lo(u.w) * v; a7 += bf_hi(u.w) * v;
    }
    if (e < end) {
        const int ee = e + g;
        const int2 ed = (ee < end) ? edges[ee] : make_int2(0, 0);
        const float v = __int_as_float(ed.y);
        const uint4 u = *(const uint4*)(s16 + (size_t)ed.x * 128 + l16 * 8);
        a0 += bf_lo(u.x) * v; a1 += bf_hi(u.x) * v;
        a2 += bf_lo(u.y) * v; a3 += bf_hi(u.y) * v;
        a4 += bf_lo(u.z) * v; a5 += bf_hi(u.z) * v;
        a6 += bf_lo(u.w) * v; a7 += bf_hi(u.w) * v;
    }
    float s0, s1;
    reduce_groups(lane, a0, a1, a2, a3, a4, a5, a6, a7, s0, s1);
    const size_t o32 = (size_t)row * 64 + l16 * 4 + g;
    unsigned* px = (unsigned*)x0 + o32;
    const unsigned xu = *px;
    *px = bfpack(sigmoidf_(bf_lo(xu) + s0), sigmoidf_(bf_hi(xu) + s1));
}

// ---------------------------------------------------------------------------
extern "C" void kernel_launch(void* const* d_in, const int* in_sizes, int n_in,
                              void* d_out, int out_size, void* d_ws, size_t ws_size,
                              hipStream_t stream)
{
    const float* x0_in   = (const float*)d_in[0];
    const float* x1_in   = (const float*)d_in[1];
    const int*   node_idx = (const int*)d_in[2];
    const int*   he_idx   = (const int*)d_in[3];
    const float* inc_vals = (const float*)d_in[4];
    const float* W_enc   = (const float*)d_in[5];
    const float* b_enc   = (const float*)d_in[6];
    const float* W_msg0  = (const float*)d_in[7];
    const float* b_msg0  = (const float*)d_in[8];
    const float* W_msg1  = (const float*)d_in[9];
    const float* b_msg1  = (const float*)d_in[10];
    const float* W_out   = (const float*)d_in[11];
    const float* b_out   = (const float*)d_in[12];
    float* out = (float*)d_out;

    __hip_bfloat16* x0h    = (__hip_bfloat16*)d_ws;         // 12,800,000
    __hip_bfloat16* x1a    = x0h + 12800000;                //  6,400,000
    __hip_bfloat16* x1b    = x1a + 6400000;                 //  6,400,000
    __hip_bfloat16* mbuf   = x1b + 6400000;                 // 12,800,000
    __hip_bfloat16* m0_he  = mbuf + 12800000;               //  6,400,000
    __hip_bfloat16* Wt_enc = m0_he + 6400000;               // 32768
    __hip_bfloat16* Wt_m0  = Wt_enc + 32768;                // 32768
    __hip_bfloat16* Wt_m1  = Wt_m0 + 32768;                 // 65536
    __hip_bfloat16* Wt_out = Wt_m1 + 65536;                 // 6144
    int*  he_off    = (int*)(Wt_out + 6144);
    int*  node_off  = he_off + N_HE;
    int*  bsums     = node_off + N_NODES;                   // 256
    int*  he_rank   = bsums + 256;                          // 600k
    int*  node_rank = he_rank + N_INC;                      // 600k
    int2* he_edge   = (int2*)(node_rank + N_INC);
    int2* node_edge = he_edge + N_INC;

    // scratch bf16 copies of encode inputs: reuse loop buffers (dead here).
    __hip_bfloat16* x0bf = x1b;          // 25,600,000 shorts (x1b+mbuf+m0_he)
    __hip_bfloat16* x1bf = x1b;          // 12,800,000 shorts (reused after)

    // ---- CSR build ----
    zero_int_kernel<<<(N_HE + N_NODES + 255) / 256, 256, 0, stream>>>(
        he_off, N_HE + N_NODES);
    hist_kernel<<<(N_INC + 255) / 256, 256, 0, stream>>>(
        he_idx, node_idx, he_off, node_off, he_rank, node_rank, N_INC);
    const int scan_n = N_HE + N_NODES;
    const int scan_blocks = (scan_n + 1023) / 1024;          // 147
    scan1_kernel<<<scan_blocks, 256, 0, stream>>>(he_off, bsums, scan_n);
    scan2_kernel<<<1, 256, 0, stream>>>(bsums, scan_blocks);
    scan3_kernel<<<scan_blocks, 256, 0, stream>>>(he_off, bsums, scan_n);
    fill_kernel<<<(N_INC + 255) / 256, 256, 0, stream>>>(
        node_idx, he_idx, inc_vals, he_off, node_off, he_rank, node_rank,
        he_edge, node_edge, N_INC);

    // ---- weight prep ----
    wprep_kernel<<<536, 256, 0, stream>>>(W_enc, W_msg0, W_msg1, W_out,
                                          Wt_enc, Wt_m0, Wt_m1, Wt_out);

    // ---- encode: cvt fp32->bf16, then staged bf16 gemm ----
    cvt_kernel<<<2048, 256, 0, stream>>>(x0_in, (unsigned short*)x0bf, 3200000);
    gemm_st<2, false><<<(N_NODES + 127) / 128, 256, 0, stream>>>(
        x0bf, nullptr, Wt_enc, b_enc, x0h, N_NODES, 0);
    cvt_kernel<<<2048, 256, 0, stream>>>(x1_in, (unsigned short*)x1bf, 1600000);
    gemm_st<2, false><<<(N_HE + 127) / 128, 256, 0, stream>>>(
        x1bf, nullptr, Wt_enc, b_enc, x1a, N_HE, 0);

    __hip_bfloat16* x1cur = x1a;
    __hip_bfloat16* x1nxt = x1b;
    for (int l = 0; l < 2; ++l) {
        gemm_st<1, false><<<(N_NODES + 127) / 128, 256, 0, stream>>>(
            x0h, nullptr, Wt_m0 + (size_t)l * 16384,
            b_msg0 + (size_t)l * 128, mbuf, N_NODES, 1);
        gather_he_kernel<<<(N_HE + 3) / 4, 256, 0, stream>>>(
            mbuf, x1cur, m0_he, x1nxt, he_off, he_edge, N_HE);
        gemm_st<2, true><<<(N_HE + 127) / 128, 256, 0, stream>>>(
            x1cur, m0_he, Wt_m1 + (size_t)l * 32768,
            b_msg1 + (size_t)l * 128, mbuf, N_HE, 1);
        gather_node_kernel<<<(N_NODES + 3) / 4, 256, 0, stream>>>(
            mbuf, x0h, node_off, node_edge, N_NODES);
        __hip_bfloat16* t = x1cur; x1cur = x1nxt; x1nxt = t;
    }

    out_gemm_mfma<<<(N_NODES + 63) / 64, 256, 0, stream>>>(
        x0h, Wt_out, b_out, out, N_NODES);
}

// Round 5
// 547.295 us; speedup vs baseline: 1.1836x; 1.0459x over previous
//
#include <hip/hip_runtime.h>
#include <hip/hip_bf16.h>
#include <math.h>

#define N_NODES 100000
#define N_HE    50000
#define N_INC   600000
#define D_IN    256
#define D_H     128
#define N_CLASSES 40

typedef __attribute__((ext_vector_type(8))) short short8;
typedef __attribute__((ext_vector_type(4))) float f32x4;

// fast sigmoid: v_exp-based, ~4 inst. Error ~1e-6 rel, invisible under bf16.
__device__ __forceinline__ float sigmoidf_(float x) {
    return __builtin_amdgcn_rcpf(1.0f + __expf(-x));
}

__device__ __forceinline__ short bfbits(float f) {
    __hip_bfloat16 h = __float2bfloat16(f);
    return *reinterpret_cast<short*>(&h);
}

__device__ __forceinline__ float bf_lo(unsigned u) { return __uint_as_float(u << 16); }
__device__ __forceinline__ float bf_hi(unsigned u) { return __uint_as_float(u & 0xffff0000u); }
__device__ __forceinline__ unsigned bfpack(float a, float b) {
    return (unsigned)(unsigned short)bfbits(a) | ((unsigned)(unsigned short)bfbits(b) << 16);
}

// async global->LDS, 16 B per lane; LDS dest is wave-uniform base + lane*16
__device__ __forceinline__ void gload_lds16(const void* g, void* l) {
    __builtin_amdgcn_global_load_lds(
        (const __attribute__((address_space(1))) unsigned int*)g,
        (__attribute__((address_space(3))) unsigned int*)l, 16, 0, 0);
}

// ---------------------------------------------------------------------------
// Staged MFMA GEMM: C(M x 128) = act( A @ W + bias ), bf16, fp32 acc.
// A tile (128 rows x 128 k) and B tile (128 n x 128 k) staged in LDS via
// global_load_lds (linear dest, XOR-swizzled source chunk ^= row&7; read
// applies the same XOR -> 2-way bank conflicts only).
// Block = 256 thr (4 waves 2x2), wave tile 64x64.  LDS 64 KB -> 2 blk/CU.
// ---------------------------------------------------------------------------
template<int KT, bool SPLIT>
__global__ __launch_bounds__(256) void gemm_st(
    const __hip_bfloat16* __restrict__ A1,
    const __hip_bfloat16* __restrict__ A2,
    const __hip_bfloat16* __restrict__ Wt,   // 128 x (KT*128) bf16, n-major
    const float* __restrict__ bias,
    __hip_bfloat16* __restrict__ C,          // M x 128 bf16
    int M, int act)
{
    __shared__ uint4 smemv[4096];            // 65536 B
    char* const sA = (char*)smemv;           // 32768 B: [128 rows][16 x 16B]
    char* const sB = (char*)smemv + 32768;   // 32768 B: [128 n   ][16 x 16B]

    const int tid = threadIdx.x;
    const int wave = tid >> 6, lane = tid & 63;
    const int quad = lane >> 4, nn = lane & 15;
    const int wr = wave >> 1, wc = wave & 1;
    const int row_base = blockIdx.x * 128;
    const int col_base = wc * 64;

    f32x4 acc[4][4] = {};

    for (int h = 0; h < KT; ++h) {
        const char* Asrc = (const char*)(SPLIT ? (h ? A2 : A1) : A1);
        const size_t astride = SPLIT ? 256 : (size_t)KT * 256;   // row bytes
        const size_t aoff = SPLIT ? 0 : (size_t)h * 256;
#pragma unroll
        for (int j = 0; j < 8; ++j) {
            const int sb = j * 4 + wave;          // slot-block 0..31
            const int s = sb * 64 + lane;         // slot 0..2047
            const int row = s >> 4, c = s & 15;
            int grow = row_base + row; if (grow >= M) grow = M - 1;
            gload_lds16(Asrc + (size_t)grow * astride + aoff + ((c ^ (row & 7)) * 16),
                        sA + sb * 1024);
        }
#pragma unroll
        for (int j = 0; j < 8; ++j) {
            const int sb = j * 4 + wave;
            const int s = sb * 64 + lane;
            const int n = s >> 4, c = s & 15;
            gload_lds16((const char*)Wt + (size_t)n * (KT * 256) + (size_t)h * 256
                            + ((c ^ (n & 7)) * 16),
                        sB + sb * 1024);
        }
        __syncthreads();   // compiler drains vmcnt before barrier

#pragma unroll
        for (int ks = 0; ks < 4; ++ks) {
            short8 a[4], b[4];
#pragma unroll
            for (int rt = 0; rt < 4; ++rt) {
                const int row = wr * 64 + rt * 16 + nn;
                a[rt] = *(const short8*)(sA + row * 256 + (((ks * 4 + quad) ^ (row & 7)) * 16));
            }
#pragma unroll
            for (int ct = 0; ct < 4; ++ct) {
                const int n = col_base + ct * 16 + nn;
                b[ct] = *(const short8*)(sB + n * 256 + (((ks * 4 + quad) ^ (n & 7)) * 16));
            }
#pragma unroll
            for (int ct = 0; ct < 4; ++ct)
#pragma unroll
                for (int rt = 0; rt < 4; ++rt)
                    acc[rt][ct] = __builtin_amdgcn_mfma_f32_16x16x32_bf16(
                        a[rt], b[ct], acc[rt][ct], 0, 0, 0);
        }
        __syncthreads();   // protects sA/sB overwrite (and sC reuse below)
    }

    float bs[4];
#pragma unroll
    for (int ct = 0; ct < 4; ++ct) bs[ct] = bias[col_base + ct * 16 + nn];

    // ---- stage C tile into LDS (bf16, stride 136 -> 2-way only) ----
    constexpr int KP = 136;
    unsigned short* sC = (unsigned short*)smemv;
#pragma unroll
    for (int rt = 0; rt < 4; ++rt) {
#pragma unroll
        for (int i = 0; i < 4; ++i) {
            const int R = wr * 64 + rt * 16 + quad * 4 + i;
#pragma unroll
            for (int ct = 0; ct < 4; ++ct) {
                float v = acc[rt][ct][i] + bs[ct];
                if (act) v = sigmoidf_(v);
                sC[R * KP + col_base + ct * 16 + nn] = (unsigned short)bfbits(v);
            }
        }
    }
    __syncthreads();

    // ---- cooperative coalesced store: thread t -> row t/2, half t&1 ----
    {
        const int row = tid >> 1, half = tid & 1;
        const int gr = row_base + row;
        if (gr < M) {
            const unsigned short* srcp = sC + row * KP + half * 64;
            uint4* dstp = (uint4*)(C + (size_t)gr * 128 + half * 64);
#pragma unroll
            for (int j = 0; j < 8; ++j) dstp[j] = *(const uint4*)(srcp + j * 8);
        }
    }
}

// ---------------------------------------------------------------------------
// Fused fp32-encode GEMM: C(M x 128) = A_fp32(M x 256) @ W + bias, bf16 out.
// A loaded lane-linear coalesced (float4 x2), converted to bf16 in regs,
// ds_write_b128 into the same swizzled LDS layout (2-way alias only).
// W staged via global_load_lds.  Saves the cvt round-trip (51MB w + 51MB r).
// ---------------------------------------------------------------------------
__global__ __launch_bounds__(256) void gemm_enc(
    const float* __restrict__ A,             // M x 256 fp32
    const __hip_bfloat16* __restrict__ Wt,   // 128 x 256 bf16, n-major
    const float* __restrict__ bias,
    __hip_bfloat16* __restrict__ C,          // M x 128 bf16
    int M)
{
    __shared__ uint4 smemv[4096];            // 65536 B
    char* const sA = (char*)smemv;
    char* const sB = (char*)smemv + 32768;

    const int tid = threadIdx.x;
    const int wave = tid >> 6, lane = tid & 63;
    const int quad = lane >> 4, nn = lane & 15;
    const int wr = wave >> 1, wc = wave & 1;
    const int row_base = blockIdx.x * 128;
    const int col_base = wc * 64;

    f32x4 acc[4][4] = {};

    for (int h = 0; h < 2; ++h) {
        // ---- stage B (bf16 weights) via DMA
#pragma unroll
        for (int j = 0; j < 8; ++j) {
            const int sb = j * 4 + wave;
            const int s = sb * 64 + lane;
            const int n = s >> 4, c = s & 15;
            gload_lds16((const char*)Wt + (size_t)n * 512 + (size_t)h * 256
                            + ((c ^ (n & 7)) * 16),
                        sB + sb * 1024);
        }
        // ---- stage A: fp32 coalesced load -> bf16 convert -> swizzled LDS
#pragma unroll
        for (int j = 0; j < 8; ++j) {
            const int s = j * 256 + tid;          // slot 0..2047
            const int row = s >> 4, c = s & 15;   // 16 lanes cover 512B of a row
            int grow = row_base + row; if (grow >= M) grow = M - 1;
            const float* ap = A + (size_t)grow * 256 + h * 128 + c * 8;
            const float4 p = *(const float4*)ap;
            const float4 q = *(const float4*)(ap + 4);
            uint4 r;
            r.x = bfpack(p.x, p.y); r.y = bfpack(p.z, p.w);
            r.z = bfpack(q.x, q.y); r.w = bfpack(q.z, q.w);
            *(uint4*)(sA + row * 256 + ((c ^ (row & 7)) * 16)) = r;
        }
        __syncthreads();

#pragma unroll
        for (int ks = 0; ks < 4; ++ks) {
            short8 a[4], b[4];
#pragma unroll
            for (int rt = 0; rt < 4; ++rt) {
                const int row = wr * 64 + rt * 16 + nn;
                a[rt] = *(const short8*)(sA + row * 256 + (((ks * 4 + quad) ^ (row & 7)) * 16));
            }
#pragma unroll
            for (int ct = 0; ct < 4; ++ct) {
                const int n = col_base + ct * 16 + nn;
                b[ct] = *(const short8*)(sB + n * 256 + (((ks * 4 + quad) ^ (n & 7)) * 16));
            }
#pragma unroll
            for (int ct = 0; ct < 4; ++ct)
#pragma unroll
                for (int rt = 0; rt < 4; ++rt)
                    acc[rt][ct] = __builtin_amdgcn_mfma_f32_16x16x32_bf16(
                        a[rt], b[ct], acc[rt][ct], 0, 0, 0);
        }
        __syncthreads();
    }

    float bs[4];
#pragma unroll
    for (int ct = 0; ct < 4; ++ct) bs[ct] = bias[col_base + ct * 16 + nn];

    constexpr int KP = 136;
    unsigned short* sC = (unsigned short*)smemv;
#pragma unroll
    for (int rt = 0; rt < 4; ++rt) {
#pragma unroll
        for (int i = 0; i < 4; ++i) {
            const int R = wr * 64 + rt * 16 + quad * 4 + i;
#pragma unroll
            for (int ct = 0; ct < 4; ++ct) {
                const float v = acc[rt][ct][i] + bs[ct];
                sC[R * KP + col_base + ct * 16 + nn] = (unsigned short)bfbits(v);
            }
        }
    }
    __syncthreads();

    {
        const int row = tid >> 1, half = tid & 1;
        const int gr = row_base + row;
        if (gr < M) {
            const unsigned short* srcp = sC + row * KP + half * 64;
            uint4* dstp = (uint4*)(C + (size_t)gr * 128 + half * 64);
#pragma unroll
            for (int j = 0; j < 8; ++j) dstp[j] = *(const uint4*)(srcp + j * 8);
        }
    }
}

// ---------------------------------------------------------------------------
// MFMA output GEMM: out(M x 40) = X(M x 128 bf16) @ W + b, fp32 out.
// ---------------------------------------------------------------------------
__global__ __launch_bounds__(256) void out_gemm_mfma(
    const __hip_bfloat16* __restrict__ X,
    const __hip_bfloat16* __restrict__ Wt,   // 48 x 128 bf16 (n-major, padded)
    const float* __restrict__ b, float* __restrict__ out, int M)
{
    constexpr int KP = 136;
    __shared__ uint4 sXv[1024];              // 16384 B: [64 rows][16 x 16B]
    __shared__ __hip_bfloat16 sW[48 * KP];
    __shared__ float sB[48];
    __shared__ float sO[64 * 44];            // 11264 B

    char* const sX = (char*)sXv;
    const int tid = threadIdx.x;
    const int wave = tid >> 6, lane = tid & 63;

    // stage X: 1024 slots, 4 calls/wave
#pragma unroll
    for (int j = 0; j < 4; ++j) {
        const int sb = j * 4 + wave;          // 0..15
        const int s = sb * 64 + lane;         // 0..1023
        const int row = s >> 4, c = s & 15;
        int grow = blockIdx.x * 64 + row; if (grow >= M) grow = M - 1;
        gload_lds16((const char*)X + (size_t)grow * 256 + ((c ^ (row & 7)) * 16),
                    sX + sb * 1024);
    }
    for (int c = tid; c < 48 * 16; c += 256) {
        const int n = c >> 4, ko = (c & 15) * 8;
        *(uint4*)&sW[n * KP + ko] = *(const uint4*)&Wt[n * 128 + ko];
    }
    if (tid < 48) sB[tid] = (tid < 40) ? b[tid] : 0.0f;
    __syncthreads();

    const int quad = lane >> 4, nn = lane & 15;

    f32x4 acc[3] = {};
#pragma unroll
    for (int ks = 0; ks < 4; ++ks) {
        const int rowl = wave * 16 + nn;
        const short8 a = *(const short8*)(sX + rowl * 256 + (((ks * 4 + quad) ^ (rowl & 7)) * 16));
#pragma unroll
        for (int ct = 0; ct < 3; ++ct) {
            const short8 bf = *(const short8*)&sW[(ct * 16 + nn) * KP + ks * 32 + quad * 8];
            acc[ct] = __builtin_amdgcn_mfma_f32_16x16x32_bf16(a, bf, acc[ct], 0, 0, 0);
        }
    }

    // stage into LDS
#pragma unroll
    for (int ct = 0; ct < 3; ++ct) {
        const int c = ct * 16 + nn;
        if (c < 40) {
#pragma unroll
            for (int i = 0; i < 4; ++i) {
                const int rl = wave * 16 + quad * 4 + i;
                sO[rl * 44 + c] = acc[ct][i] + sB[c];
            }
        }
    }
    __syncthreads();

    // cooperative store: 64 rows x 10 float4
    for (int c = tid; c < 640; c += 256) {
        const int row = c / 10, ch = c % 10;
        const int gr = blockIdx.x * 64 + row;
        if (gr < M)
            *(float4*)(out + (size_t)gr * 40 + ch * 4) =
                *(const float4*)(sO + row * 44 + ch * 4);
    }
}

// ---------------------------------------------------------------------------
// Prep: weight transpose/convert (fp32 -> bf16 n-major) + zero CSR counts.
// ---------------------------------------------------------------------------
__global__ __launch_bounds__(256) void prep_kernel(
    const float* __restrict__ We, const float* __restrict__ Wm0,
    const float* __restrict__ Wm1, const float* __restrict__ Wout,
    __hip_bfloat16* __restrict__ Wt_enc, __hip_bfloat16* __restrict__ Wt_m0,
    __hip_bfloat16* __restrict__ Wt_m1, __hip_bfloat16* __restrict__ Wt_out,
    int* __restrict__ cnt_zero)
{
    const int i = blockIdx.x * 256 + threadIdx.x;
    if (i < 32768) {
        const int n = i >> 8, k = i & 255;
        Wt_enc[n * 256 + k] = __float2bfloat16(We[k * 128 + n]);
    } else if (i < 65536) {
        int j = i - 32768; const int l = j >> 14; j &= 16383;
        const int n = j >> 7, k = j & 127;
        Wt_m0[l * 16384 + n * 128 + k] = __float2bfloat16(Wm0[l * 16384 + k * 128 + n]);
    } else if (i < 131072) {
        int j = i - 65536; const int l = j >> 15; j &= 32767;
        const int n = j >> 8, k = j & 255;
        Wt_m1[l * 32768 + n * 256 + k] = __float2bfloat16(Wm1[l * 32768 + k * 128 + n]);
    } else if (i < 137216) {
        const int j = i - 131072;
        const int n = j >> 7, k = j & 127;
        Wt_out[n * 128 + k] = (n < 40) ? __float2bfloat16(Wout[k * 40 + n])
                                       : __float2bfloat16(0.0f);
    } else {
        const int z = i - 137216;
        if (z < N_HE + N_NODES) cnt_zero[z] = 0;
    }
}

// ---------------------------------------------------------------------------
// CSR build (atomic-free fill: hist captures per-edge rank)
// ---------------------------------------------------------------------------
__global__ __launch_bounds__(256) void hist_kernel(
    const int* __restrict__ he_idx, const int* __restrict__ node_idx,
    int* __restrict__ he_cnt, int* __restrict__ node_cnt,
    int* __restrict__ he_rank, int* __restrict__ node_rank, int n)
{
    const int i = blockIdx.x * 256 + threadIdx.x;
    if (i < n) {
        he_rank[i] = atomicAdd(&he_cnt[he_idx[i]], 1);
        node_rank[i] = atomicAdd(&node_cnt[node_idx[i]], 1);
    }
}

__global__ __launch_bounds__(256) void scan1_kernel(
    int* __restrict__ data, int* __restrict__ bsums, int n)
{
    __shared__ int s[256];
    const int t = threadIdx.x;
    const int base = blockIdx.x * 1024 + t * 4;
    int4 v = make_int4(0, 0, 0, 0);
    if (base < n) v = *(const int4*)(data + base);
    s[t] = v.x + v.y + v.z + v.w;
    __syncthreads();
    for (int d = 1; d < 256; d <<= 1) {
        const int u = (t >= d) ? s[t - d] : 0;
        __syncthreads();
        s[t] += u;
        __syncthreads();
    }
    if (t == 255) bsums[blockIdx.x] = s[255];
    int e = t ? s[t - 1] : 0;
    if (base < n) {
        int4 o;
        o.x = e; e += v.x; o.y = e; e += v.y; o.z = e; e += v.z; o.w = e;
        *(int4*)(data + base) = o;
    }
}

// scan2+scan3 fused: each block locally reduces bsums[0..bid-1], then adds.
__global__ __launch_bounds__(256) void scan23_kernel(
    int* __restrict__ data, const int* __restrict__ bsums, int n, int nb)
{
    __shared__ int s[256];
    const int t = threadIdx.x;
    const int v = (t < nb && t < (int)blockIdx.x) ? bsums[t] : 0;
    s[t] = v;
    __syncthreads();
    for (int d = 1; d < 256; d <<= 1) {
        const int u = (t >= d) ? s[t - d] : 0;
        __syncthreads();
        s[t] += u;
        __syncthreads();
    }
    const int total = s[255];                 // sum of bsums[0..bid-1]
    const int base = blockIdx.x * 1024 + t * 4;
    if (base >= n) return;
    const int adj = total - ((base >= N_HE) ? N_INC : 0);
    int4 vv = *(int4*)(data + base);
    vv.x += adj; vv.y += adj; vv.z += adj; vv.w += adj;
    *(int4*)(data + base) = vv;
}

// fill packed edges at off[dest]+rank[e] — NO atomics
__global__ __launch_bounds__(256) void fill_kernel(
    const int* __restrict__ node_idx, const int* __restrict__ he_idx,
    const float* __restrict__ vals,
    const int* __restrict__ he_off, const int* __restrict__ node_off,
    const int* __restrict__ he_rank, const int* __restrict__ node_rank,
    int2* __restrict__ he_edge, int2* __restrict__ node_edge, int n)
{
    const int e = blockIdx.x * 256 + threadIdx.x;
    if (e >= n) return;
    const int hn = he_idx[e], nd = node_idx[e];
    const int vb = __float_as_int(vals[e]);
    he_edge[he_off[hn] + he_rank[e]] = make_int2(nd, vb);
    node_edge[node_off[nd] + node_rank[e]] = make_int2(hn, vb);
}

// ---------------------------------------------------------------------------
// Split butterfly reduction helper: input a0..a7 (cols l16*8+i, partial over
// edge-slot groups), output s0,s1 = full sums for cols l16*8+2g, +1.
// ---------------------------------------------------------------------------
__device__ __forceinline__ void reduce_groups(
    int lane, float a0, float a1, float a2, float a3,
    float a4, float a5, float a6, float a7, float& s0, float& s1)
{
    const bool hb = (lane & 32) != 0;    // bit1 of group g = lane>>4
    float t0 = hb ? a0 : a4;
    float t1 = hb ? a1 : a5;
    float t2 = hb ? a2 : a6;
    float t3 = hb ? a3 : a7;
    float r0 = __shfl_xor(t0, 32);
    float r1 = __shfl_xor(t1, 32);
    float r2 = __shfl_xor(t2, 32);
    float r3 = __shfl_xor(t3, 32);
    float e0 = (hb ? a4 : a0) + r0;
    float e1 = (hb ? a5 : a1) + r1;
    float e2 = (hb ? a6 : a2) + r2;
    float e3 = (hb ? a7 : a3) + r3;
    const bool lb = (lane & 16) != 0;    // bit0 of group
    float u0 = lb ? e0 : e2;
    float u1 = lb ? e1 : e3;
    float q0 = __shfl_xor(u0, 16);
    float q1 = __shfl_xor(u1, 16);
    s0 = (lb ? e2 : e0) + q0;
    s1 = (lb ? e3 : e1) + q1;
}

// ---------------------------------------------------------------------------
// Fused he-gather (4 edges/wave-iter, 16B/lane): agg = sum val*m0[src];
// writes m0_he AND x1_next = sigmoid(x1_cur + agg). Offsets EXCLUSIVE.
// Epilogue: all 64 lanes each finalize 2 cols (u32 stores, contiguous 256B).
// ---------------------------------------------------------------------------
__global__ __launch_bounds__(256) void gather_he_kernel(
    const __hip_bfloat16* __restrict__ msrc,
    const __hip_bfloat16* __restrict__ x1cur,
    __hip_bfloat16* __restrict__ m0_he,
    __hip_bfloat16* __restrict__ x1next,
    const int* __restrict__ off, const int2* __restrict__ edges, int n_seg)
{
    const int wave = threadIdx.x >> 6;
    const int lane = threadIdx.x & 63;
    const int row = blockIdx.x * 4 + wave;
    if (row >= n_seg) return;
    const int start = off[row];
    const int end = (row + 1 < n_seg) ? off[row + 1] : N_INC;
    const int g = lane >> 4;
    const int l16 = lane & 15;
    float a0 = 0.f, a1 = 0.f, a2 = 0.f, a3 = 0.f;
    float a4 = 0.f, a5 = 0.f, a6 = 0.f, a7 = 0.f;
    const unsigned short* s16 = (const unsigned short*)msrc;
    int e = start;
    for (; e + 4 <= end; e += 4) {                 // full quads: no bounds check
        const int2 ed = edges[e + g];
        const float v = __int_as_float(ed.y);
        const uint4 u = *(const uint4*)(s16 + (size_t)ed.x * 128 + l16 * 8);
        a0 += bf_lo(u.x) * v; a1 += bf_hi(u.x) * v;
        a2 += bf_lo(u.y) * v; a3 += bf_hi(u.y) * v;
        a4 += bf_lo(u.z) * v; a5 += bf_hi(u.z) * v;
        a6 += bf_lo(u.w) * v; a7 += bf_hi(u.w) * v;
    }
    if (e < end) {                                 // masked tail
        const int ee = e + g;
        const int2 ed = (ee < end) ? edges[ee] : make_int2(0, 0);
        const float v = __int_as_float(ed.y);
        const uint4 u = *(const uint4*)(s16 + (size_t)ed.x * 128 + l16 * 8);
        a0 += bf_lo(u.x) * v; a1 += bf_hi(u.x) * v;
        a2 += bf_lo(u.y) * v; a3 += bf_hi(u.y) * v;
        a4 += bf_lo(u.z) * v; a5 += bf_hi(u.z) * v;
        a6 += bf_lo(u.w) * v; a7 += bf_hi(u.w) * v;
    }
    float s0, s1;
    reduce_groups(lane, a0, a1, a2, a3, a4, a5, a6, a7, s0, s1);
    // lane owns cols l16*8+2g, +1  ->  u32 col index l16*4+g
    const size_t o32 = (size_t)row * 64 + l16 * 4 + g;
    ((unsigned*)m0_he)[o32] = bfpack(s0, s1);
    const unsigned xu = ((const unsigned*)x1cur)[o32];
    ((unsigned*)x1next)[o32] =
        bfpack(sigmoidf_(bf_lo(xu) + s0), sigmoidf_(bf_hi(xu) + s1));
}

// ---------------------------------------------------------------------------
// Fused node-gather (4 edges/wave-iter, 16B/lane): x0 = sigmoid(x0 + agg).
// ---------------------------------------------------------------------------
__global__ __launch_bounds__(256) void gather_node_kernel(
    const __hip_bfloat16* __restrict__ msrc,
    __hip_bfloat16* __restrict__ x0,
    const int* __restrict__ off, const int2* __restrict__ edges, int n_seg)
{
    const int wave = threadIdx.x >> 6;
    const int lane = threadIdx.x & 63;
    const int row = blockIdx.x * 4 + wave;
    if (row >= n_seg) return;
    const int start = off[row];
    const int end = (row + 1 < n_seg) ? off[row + 1] : N_INC;
    const int g = lane >> 4;
    const int l16 = lane & 15;
    float a0 = 0.f, a1 = 0.f, a2 = 0.f, a3 = 0.f;
    float a4 = 0.f, a5 = 0.f, a6 = 0.f, a7 = 0.f;
    const unsigned short* s16 = (const unsigned short*)msrc;
    int e = start;
    for (; e + 4 <= end; e += 4) {
        const int2 ed = edges[e + g];
        const float v = __int_as_float(ed.y);
        const uint4 u = *(const uint4*)(s16 + (size_t)ed.x * 128 + l16 * 8);
        a0 += bf_lo(u.x) * v; a1 += bf_hi(u.x) * v;
        a2 += bf_lo(u.y) * v; a3 += bf_hi(u.y) * v;
        a4 += bf_lo(u.z) * v; a5 += bf_hi(u.z) * v;
        a6 += bf_lo(u.w) * v; a7 += bf_hi(u.w) * v;
    }
    if (e < end) {
        const int ee = e + g;
        const int2 ed = (ee < end) ? edges[ee] : make_int2(0, 0);
        const float v = __int_as_float(ed.y);
        const uint4 u = *(const uint4*)(s16 + (size_t)ed.x * 128 + l16 * 8);
        a0 += bf_lo(u.x) * v; a1 += bf_hi(u.x) * v;
        a2 += bf_lo(u.y) * v; a3 += bf_hi(u.y) * v;
        a4 += bf_lo(u.z) * v; a5 += bf_hi(u.z) * v;
        a6 += bf_lo(u.w) * v; a7 += bf_hi(u.w) * v;
    }
    float s0, s1;
    reduce_groups(lane, a0, a1, a2, a3, a4, a5, a6, a7, s0, s1);
    const size_t o32 = (size_t)row * 64 + l16 * 4 + g;
    unsigned* px = (unsigned*)x0 + o32;
    const unsigned xu = *px;
    *px = bfpack(sigmoidf_(bf_lo(xu) + s0), sigmoidf_(bf_hi(xu) + s1));
}

// ---------------------------------------------------------------------------
extern "C" void kernel_launch(void* const* d_in, const int* in_sizes, int n_in,
                              void* d_out, int out_size, void* d_ws, size_t ws_size,
                              hipStream_t stream)
{
    const float* x0_in   = (const float*)d_in[0];
    const float* x1_in   = (const float*)d_in[1];
    const int*   node_idx = (const int*)d_in[2];
    const int*   he_idx   = (const int*)d_in[3];
    const float* inc_vals = (const float*)d_in[4];
    const float* W_enc   = (const float*)d_in[5];
    const float* b_enc   = (const float*)d_in[6];
    const float* W_msg0  = (const float*)d_in[7];
    const float* b_msg0  = (const float*)d_in[8];
    const float* W_msg1  = (const float*)d_in[9];
    const float* b_msg1  = (const float*)d_in[10];
    const float* W_out   = (const float*)d_in[11];
    const float* b_out   = (const float*)d_in[12];
    float* out = (float*)d_out;

    __hip_bfloat16* x0h    = (__hip_bfloat16*)d_ws;         // 12,800,000
    __hip_bfloat16* x1a    = x0h + 12800000;                //  6,400,000
    __hip_bfloat16* x1b    = x1a + 6400000;                 //  6,400,000
    __hip_bfloat16* mbuf   = x1b + 6400000;                 // 12,800,000
    __hip_bfloat16* m0_he  = mbuf + 12800000;               //  6,400,000
    __hip_bfloat16* Wt_enc = m0_he + 6400000;               // 32768
    __hip_bfloat16* Wt_m0  = Wt_enc + 32768;                // 32768
    __hip_bfloat16* Wt_m1  = Wt_m0 + 32768;                 // 65536
    __hip_bfloat16* Wt_out = Wt_m1 + 65536;                 // 6144
    int*  he_off    = (int*)(Wt_out + 6144);
    int*  node_off  = he_off + N_HE;
    int*  bsums     = node_off + N_NODES;                   // 256
    int*  he_rank   = bsums + 256;                          // 600k
    int*  node_rank = he_rank + N_INC;                      // 600k
    int2* he_edge   = (int2*)(node_rank + N_INC);
    int2* node_edge = he_edge + N_INC;

    // ---- prep (weight transpose + zero CSR counts) ----
    prep_kernel<<<(137216 + N_HE + N_NODES + 255) / 256, 256, 0, stream>>>(
        W_enc, W_msg0, W_msg1, W_out, Wt_enc, Wt_m0, Wt_m1, Wt_out, he_off);

    // ---- CSR build ----
    hist_kernel<<<(N_INC + 255) / 256, 256, 0, stream>>>(
        he_idx, node_idx, he_off, node_off, he_rank, node_rank, N_INC);
    const int scan_n = N_HE + N_NODES;
    const int scan_blocks = (scan_n + 1023) / 1024;          // 147
    scan1_kernel<<<scan_blocks, 256, 0, stream>>>(he_off, bsums, scan_n);
    scan23_kernel<<<scan_blocks, 256, 0, stream>>>(he_off, bsums, scan_n, scan_blocks);
    fill_kernel<<<(N_INC + 255) / 256, 256, 0, stream>>>(
        node_idx, he_idx, inc_vals, he_off, node_off, he_rank, node_rank,
        he_edge, node_edge, N_INC);

    // ---- encode: fused fp32 gemm (no cvt round-trip) ----
    gemm_enc<<<(N_NODES + 127) / 128, 256, 0, stream>>>(
        x0_in, Wt_enc, b_enc, x0h, N_NODES);
    gemm_enc<<<(N_HE + 127) / 128, 256, 0, stream>>>(
        x1_in, Wt_enc, b_enc, x1a, N_HE);

    __hip_bfloat16* x1cur = x1a;
    __hip_bfloat16* x1nxt = x1b;
    for (int l = 0; l < 2; ++l) {
        gemm_st<1, false><<<(N_NODES + 127) / 128, 256, 0, stream>>>(
            x0h, nullptr, Wt_m0 + (size_t)l * 16384,
            b_msg0 + (size_t)l * 128, mbuf, N_NODES, 1);
        gather_he_kernel<<<(N_HE + 3) / 4, 256, 0, stream>>>(
            mbuf, x1cur, m0_he, x1nxt, he_off, he_edge, N_HE);
        gemm_st<2, true><<<(N_HE + 127) / 128, 256, 0, stream>>>(
            x1cur, m0_he, Wt_m1 + (size_t)l * 32768,
            b_msg1 + (size_t)l * 128, mbuf, N_HE, 1);
        gather_node_kernel<<<(N_NODES + 3) / 4, 256, 0, stream>>>(
            mbuf, x0h, node_off, node_edge, N_NODES);
        __hip_bfloat16* t = x1cur; x1cur = x1nxt; x1nxt = t;
    }

    out_gemm_mfma<<<(N_NODES + 63) / 64, 256, 0, stream>>>(
        x0h, Wt_out, b_out, out, N_NODES);
}

// Round 6
// 515.821 us; speedup vs baseline: 1.2558x; 1.0610x over previous
//
#include <hip/hip_runtime.h>
#include <hip/hip_bf16.h>
#include <math.h>

#define N_NODES 100000
#define N_HE    50000
#define N_INC   600000
#define D_IN    256
#define D_H     128
#define N_CLASSES 40

typedef __attribute__((ext_vector_type(8))) short short8;
typedef __attribute__((ext_vector_type(4))) float f32x4;

// fast sigmoid: v_exp-based, ~4 inst. Error ~1e-6 rel, invisible under bf16.
__device__ __forceinline__ float sigmoidf_(float x) {
    return __builtin_amdgcn_rcpf(1.0f + __expf(-x));
}

__device__ __forceinline__ short bfbits(float f) {
    __hip_bfloat16 h = __float2bfloat16(f);
    return *reinterpret_cast<short*>(&h);
}

__device__ __forceinline__ float bf_lo(unsigned u) { return __uint_as_float(u << 16); }
__device__ __forceinline__ float bf_hi(unsigned u) { return __uint_as_float(u & 0xffff0000u); }
__device__ __forceinline__ unsigned bfpack(float a, float b) {
    return (unsigned)(unsigned short)bfbits(a) | ((unsigned)(unsigned short)bfbits(b) << 16);
}

// async global->LDS, 16 B per lane; LDS dest is wave-uniform base + lane*16
__device__ __forceinline__ void gload_lds16(const void* g, void* l) {
    __builtin_amdgcn_global_load_lds(
        (const __attribute__((address_space(1))) unsigned int*)g,
        (__attribute__((address_space(3))) unsigned int*)l, 16, 0, 0);
}

// ---------------------------------------------------------------------------
// Staged MFMA GEMM: C(M x 128) = act( A @ W + bias ), bf16, fp32 acc.
// A tile (128 rows x 128 k) and B tile (128 n x 128 k) staged in LDS via
// global_load_lds (linear dest, XOR-swizzled source chunk ^= row&7; read
// applies the same XOR -> 2-way bank conflicts only).
// Block = 256 thr (4 waves 2x2), wave tile 64x64.  LDS 64 KB -> 2 blk/CU.
// ---------------------------------------------------------------------------
template<int KT, bool SPLIT>
__global__ __launch_bounds__(256) void gemm_st(
    const __hip_bfloat16* __restrict__ A1,
    const __hip_bfloat16* __restrict__ A2,
    const __hip_bfloat16* __restrict__ Wt,   // 128 x (KT*128) bf16, n-major
    const float* __restrict__ bias,
    __hip_bfloat16* __restrict__ C,          // M x 128 bf16
    int M, int act)
{
    __shared__ uint4 smemv[4096];            // 65536 B
    char* const sA = (char*)smemv;           // 32768 B: [128 rows][16 x 16B]
    char* const sB = (char*)smemv + 32768;   // 32768 B: [128 n   ][16 x 16B]

    const int tid = threadIdx.x;
    const int wave = tid >> 6, lane = tid & 63;
    const int quad = lane >> 4, nn = lane & 15;
    const int wr = wave >> 1, wc = wave & 1;
    const int row_base = blockIdx.x * 128;
    const int col_base = wc * 64;

    f32x4 acc[4][4] = {};

    for (int h = 0; h < KT; ++h) {
        const char* Asrc = (const char*)(SPLIT ? (h ? A2 : A1) : A1);
        const size_t astride = SPLIT ? 256 : (size_t)KT * 256;   // row bytes
        const size_t aoff = SPLIT ? 0 : (size_t)h * 256;
#pragma unroll
        for (int j = 0; j < 8; ++j) {
            const int sb = j * 4 + wave;          // slot-block 0..31
            const int s = sb * 64 + lane;         // slot 0..2047
            const int row = s >> 4, c = s & 15;
            int grow = row_base + row; if (grow >= M) grow = M - 1;
            gload_lds16(Asrc + (size_t)grow * astride + aoff + ((c ^ (row & 7)) * 16),
                        sA + sb * 1024);
        }
#pragma unroll
        for (int j = 0; j < 8; ++j) {
            const int sb = j * 4 + wave;
            const int s = sb * 64 + lane;
            const int n = s >> 4, c = s & 15;
            gload_lds16((const char*)Wt + (size_t)n * (KT * 256) + (size_t)h * 256
                            + ((c ^ (n & 7)) * 16),
                        sB + sb * 1024);
        }
        __syncthreads();   // compiler drains vmcnt before barrier

#pragma unroll
        for (int ks = 0; ks < 4; ++ks) {
            short8 a[4], b[4];
#pragma unroll
            for (int rt = 0; rt < 4; ++rt) {
                const int row = wr * 64 + rt * 16 + nn;
                a[rt] = *(const short8*)(sA + row * 256 + (((ks * 4 + quad) ^ (row & 7)) * 16));
            }
#pragma unroll
            for (int ct = 0; ct < 4; ++ct) {
                const int n = col_base + ct * 16 + nn;
                b[ct] = *(const short8*)(sB + n * 256 + (((ks * 4 + quad) ^ (n & 7)) * 16));
            }
#pragma unroll
            for (int ct = 0; ct < 4; ++ct)
#pragma unroll
                for (int rt = 0; rt < 4; ++rt)
                    acc[rt][ct] = __builtin_amdgcn_mfma_f32_16x16x32_bf16(
                        a[rt], b[ct], acc[rt][ct], 0, 0, 0);
        }
        __syncthreads();   // protects sA/sB overwrite (and sC reuse below)
    }

    float bs[4];
#pragma unroll
    for (int ct = 0; ct < 4; ++ct) bs[ct] = bias[col_base + ct * 16 + nn];

    // ---- stage C tile into LDS (bf16, stride 136 -> 2-way only) ----
    constexpr int KP = 136;
    unsigned short* sC = (unsigned short*)smemv;
#pragma unroll
    for (int rt = 0; rt < 4; ++rt) {
#pragma unroll
        for (int i = 0; i < 4; ++i) {
            const int R = wr * 64 + rt * 16 + quad * 4 + i;
#pragma unroll
            for (int ct = 0; ct < 4; ++ct) {
                float v = acc[rt][ct][i] + bs[ct];
                if (act) v = sigmoidf_(v);
                sC[R * KP + col_base + ct * 16 + nn] = (unsigned short)bfbits(v);
            }
        }
    }
    __syncthreads();

    // ---- cooperative coalesced store: thread t -> row t/2, half t&1 ----
    {
        const int row = tid >> 1, half = tid & 1;
        const int gr = row_base + row;
        if (gr < M) {
            const unsigned short* srcp = sC + row * KP + half * 64;
            uint4* dstp = (uint4*)(C + (size_t)gr * 128 + half * 64);
#pragma unroll
            for (int j = 0; j < 8; ++j) dstp[j] = *(const uint4*)(srcp + j * 8);
        }
    }
}

// ---------------------------------------------------------------------------
// Fused fp32-encode GEMM, BOTH inputs in one dispatch (block-range select):
// C(M x 128) = A_fp32(M x 256) @ W + bias, bf16 out.
// A loaded lane-linear coalesced (float4 x2), converted to bf16 in regs,
// ds_write_b128 into the swizzled LDS layout (2-way alias only).
// ---------------------------------------------------------------------------
__global__ __launch_bounds__(256) void gemm_enc2(
    const float* __restrict__ A0,            // N_NODES x 256 fp32
    const float* __restrict__ A1src,         // N_HE x 256 fp32
    const __hip_bfloat16* __restrict__ Wt,   // 128 x 256 bf16, n-major
    const float* __restrict__ bias,
    __hip_bfloat16* __restrict__ C0,
    __hip_bfloat16* __restrict__ C1,
    int NB0)                                 // blocks covering A0
{
    __shared__ uint4 smemv[4096];            // 65536 B
    char* const sA = (char*)smemv;
    char* const sB = (char*)smemv + 32768;

    const int tid = threadIdx.x;
    const int wave = tid >> 6, lane = tid & 63;
    const int quad = lane >> 4, nn = lane & 15;
    const int wr = wave >> 1, wc = wave & 1;

    const int b = blockIdx.x;
    const bool first = (b < NB0);
    const float* const A = first ? A0 : A1src;
    __hip_bfloat16* const C = first ? C0 : C1;
    const int M = first ? N_NODES : N_HE;
    const int row_base = (first ? b : b - NB0) * 128;
    const int col_base = wc * 64;

    f32x4 acc[4][4] = {};

    for (int h = 0; h < 2; ++h) {
        // ---- stage B (bf16 weights) via DMA
#pragma unroll
        for (int j = 0; j < 8; ++j) {
            const int sb = j * 4 + wave;
            const int s = sb * 64 + lane;
            const int n = s >> 4, c = s & 15;
            gload_lds16((const char*)Wt + (size_t)n * 512 + (size_t)h * 256
                            + ((c ^ (n & 7)) * 16),
                        sB + sb * 1024);
        }
        // ---- stage A: fp32 coalesced load -> bf16 convert -> swizzled LDS
#pragma unroll
        for (int j = 0; j < 8; ++j) {
            const int s = j * 256 + tid;          // slot 0..2047
            const int row = s >> 4, c = s & 15;   // 16 lanes cover 512B of a row
            int grow = row_base + row; if (grow >= M) grow = M - 1;
            const float* ap = A + (size_t)grow * 256 + h * 128 + c * 8;
            const float4 p = *(const float4*)ap;
            const float4 q = *(const float4*)(ap + 4);
            uint4 r;
            r.x = bfpack(p.x, p.y); r.y = bfpack(p.z, p.w);
            r.z = bfpack(q.x, q.y); r.w = bfpack(q.z, q.w);
            *(uint4*)(sA + row * 256 + ((c ^ (row & 7)) * 16)) = r;
        }
        __syncthreads();

#pragma unroll
        for (int ks = 0; ks < 4; ++ks) {
            short8 a[4], b2[4];
#pragma unroll
            for (int rt = 0; rt < 4; ++rt) {
                const int row = wr * 64 + rt * 16 + nn;
                a[rt] = *(const short8*)(sA + row * 256 + (((ks * 4 + quad) ^ (row & 7)) * 16));
            }
#pragma unroll
            for (int ct = 0; ct < 4; ++ct) {
                const int n = col_base + ct * 16 + nn;
                b2[ct] = *(const short8*)(sB + n * 256 + (((ks * 4 + quad) ^ (n & 7)) * 16));
            }
#pragma unroll
            for (int ct = 0; ct < 4; ++ct)
#pragma unroll
                for (int rt = 0; rt < 4; ++rt)
                    acc[rt][ct] = __builtin_amdgcn_mfma_f32_16x16x32_bf16(
                        a[rt], b2[ct], acc[rt][ct], 0, 0, 0);
        }
        __syncthreads();
    }

    float bs[4];
#pragma unroll
    for (int ct = 0; ct < 4; ++ct) bs[ct] = bias[col_base + ct * 16 + nn];

    constexpr int KP = 136;
    unsigned short* sC = (unsigned short*)smemv;
#pragma unroll
    for (int rt = 0; rt < 4; ++rt) {
#pragma unroll
        for (int i = 0; i < 4; ++i) {
            const int R = wr * 64 + rt * 16 + quad * 4 + i;
#pragma unroll
            for (int ct = 0; ct < 4; ++ct) {
                const float v = acc[rt][ct][i] + bs[ct];
                sC[R * KP + col_base + ct * 16 + nn] = (unsigned short)bfbits(v);
            }
        }
    }
    __syncthreads();

    {
        const int row = tid >> 1, half = tid & 1;
        const int gr = row_base + row;
        if (gr < M) {
            const unsigned short* srcp = sC + row * KP + half * 64;
            uint4* dstp = (uint4*)(C + (size_t)gr * 128 + half * 64);
#pragma unroll
            for (int j = 0; j < 8; ++j) dstp[j] = *(const uint4*)(srcp + j * 8);
        }
    }
}

// ---------------------------------------------------------------------------
// MFMA output GEMM: out(M x 40) = X(M x 128 bf16) @ W + b, fp32 out.
// ---------------------------------------------------------------------------
__global__ __launch_bounds__(256) void out_gemm_mfma(
    const __hip_bfloat16* __restrict__ X,
    const __hip_bfloat16* __restrict__ Wt,   // 48 x 128 bf16 (n-major, padded)
    const float* __restrict__ b, float* __restrict__ out, int M)
{
    constexpr int KP = 136;
    __shared__ uint4 sXv[1024];              // 16384 B: [64 rows][16 x 16B]
    __shared__ __hip_bfloat16 sW[48 * KP];
    __shared__ float sB[48];
    __shared__ float sO[64 * 44];            // 11264 B

    char* const sX = (char*)sXv;
    const int tid = threadIdx.x;
    const int wave = tid >> 6, lane = tid & 63;

    // stage X: 1024 slots, 4 calls/wave
#pragma unroll
    for (int j = 0; j < 4; ++j) {
        const int sb = j * 4 + wave;          // 0..15
        const int s = sb * 64 + lane;         // 0..1023
        const int row = s >> 4, c = s & 15;
        int grow = blockIdx.x * 64 + row; if (grow >= M) grow = M - 1;
        gload_lds16((const char*)X + (size_t)grow * 256 + ((c ^ (row & 7)) * 16),
                    sX + sb * 1024);
    }
    for (int c = tid; c < 48 * 16; c += 256) {
        const int n = c >> 4, ko = (c & 15) * 8;
        *(uint4*)&sW[n * KP + ko] = *(const uint4*)&Wt[n * 128 + ko];
    }
    if (tid < 48) sB[tid] = (tid < 40) ? b[tid] : 0.0f;
    __syncthreads();

    const int quad = lane >> 4, nn = lane & 15;

    f32x4 acc[3] = {};
#pragma unroll
    for (int ks = 0; ks < 4; ++ks) {
        const int rowl = wave * 16 + nn;
        const short8 a = *(const short8*)(sX + rowl * 256 + (((ks * 4 + quad) ^ (rowl & 7)) * 16));
#pragma unroll
        for (int ct = 0; ct < 3; ++ct) {
            const short8 bf = *(const short8*)&sW[(ct * 16 + nn) * KP + ks * 32 + quad * 8];
            acc[ct] = __builtin_amdgcn_mfma_f32_16x16x32_bf16(a, bf, acc[ct], 0, 0, 0);
        }
    }

    // stage into LDS
#pragma unroll
    for (int ct = 0; ct < 3; ++ct) {
        const int c = ct * 16 + nn;
        if (c < 40) {
#pragma unroll
            for (int i = 0; i < 4; ++i) {
                const int rl = wave * 16 + quad * 4 + i;
                sO[rl * 44 + c] = acc[ct][i] + sB[c];
            }
        }
    }
    __syncthreads();

    // cooperative store: 64 rows x 10 float4
    for (int c = tid; c < 640; c += 256) {
        const int row = c / 10, ch = c % 10;
        const int gr = blockIdx.x * 64 + row;
        if (gr < M)
            *(float4*)(out + (size_t)gr * 40 + ch * 4) =
                *(const float4*)(sO + row * 44 + ch * 4);
    }
}

// ---------------------------------------------------------------------------
// Prep: weight transpose/convert (fp32 -> bf16 n-major) + zero CSR counts.
// ---------------------------------------------------------------------------
__global__ __launch_bounds__(256) void prep_kernel(
    const float* __restrict__ We, const float* __restrict__ Wm0,
    const float* __restrict__ Wm1, const float* __restrict__ Wout,
    __hip_bfloat16* __restrict__ Wt_enc, __hip_bfloat16* __restrict__ Wt_m0,
    __hip_bfloat16* __restrict__ Wt_m1, __hip_bfloat16* __restrict__ Wt_out,
    int* __restrict__ cnt_zero)
{
    const int i = blockIdx.x * 256 + threadIdx.x;
    if (i < 32768) {
        const int n = i >> 8, k = i & 255;
        Wt_enc[n * 256 + k] = __float2bfloat16(We[k * 128 + n]);
    } else if (i < 65536) {
        int j = i - 32768; const int l = j >> 14; j &= 16383;
        const int n = j >> 7, k = j & 127;
        Wt_m0[l * 16384 + n * 128 + k] = __float2bfloat16(Wm0[l * 16384 + k * 128 + n]);
    } else if (i < 131072) {
        int j = i - 65536; const int l = j >> 15; j &= 32767;
        const int n = j >> 8, k = j & 255;
        Wt_m1[l * 32768 + n * 256 + k] = __float2bfloat16(Wm1[l * 32768 + k * 128 + n]);
    } else if (i < 137216) {
        const int j = i - 131072;
        const int n = j >> 7, k = j & 127;
        Wt_out[n * 128 + k] = (n < 40) ? __float2bfloat16(Wout[k * 40 + n])
                                       : __float2bfloat16(0.0f);
    } else {
        const int z = i - 137216;
        if (z < N_HE + N_NODES) cnt_zero[z] = 0;
    }
}

// ---------------------------------------------------------------------------
// CSR build (atomic-free fill: hist captures per-edge rank)
// ---------------------------------------------------------------------------
__global__ __launch_bounds__(256) void hist_kernel(
    const int* __restrict__ he_idx, const int* __restrict__ node_idx,
    int* __restrict__ he_cnt, int* __restrict__ node_cnt,
    int* __restrict__ he_rank, int* __restrict__ node_rank, int n)
{
    const int i = blockIdx.x * 256 + threadIdx.x;
    if (i < n) {
        he_rank[i] = atomicAdd(&he_cnt[he_idx[i]], 1);
        node_rank[i] = atomicAdd(&node_cnt[node_idx[i]], 1);
    }
}

__global__ __launch_bounds__(256) void scan1_kernel(
    int* __restrict__ data, int* __restrict__ bsums, int n)
{
    __shared__ int s[256];
    const int t = threadIdx.x;
    const int base = blockIdx.x * 1024 + t * 4;
    int4 v = make_int4(0, 0, 0, 0);
    if (base < n) v = *(const int4*)(data + base);
    s[t] = v.x + v.y + v.z + v.w;
    __syncthreads();
    for (int d = 1; d < 256; d <<= 1) {
        const int u = (t >= d) ? s[t - d] : 0;
        __syncthreads();
        s[t] += u;
        __syncthreads();
    }
    if (t == 255) bsums[blockIdx.x] = s[255];
    int e = t ? s[t - 1] : 0;
    if (base < n) {
        int4 o;
        o.x = e; e += v.x; o.y = e; e += v.y; o.z = e; e += v.z; o.w = e;
        *(int4*)(data + base) = o;
    }
}

// scan2+scan3 fused: each block locally reduces bsums[0..bid-1], then adds.
__global__ __launch_bounds__(256) void scan23_kernel(
    int* __restrict__ data, const int* __restrict__ bsums, int n, int nb)
{
    __shared__ int s[256];
    const int t = threadIdx.x;
    const int v = (t < nb && t < (int)blockIdx.x) ? bsums[t] : 0;
    s[t] = v;
    __syncthreads();
    for (int d = 1; d < 256; d <<= 1) {
        const int u = (t >= d) ? s[t - d] : 0;
        __syncthreads();
        s[t] += u;
        __syncthreads();
    }
    const int total = s[255];                 // sum of bsums[0..bid-1]
    const int base = blockIdx.x * 1024 + t * 4;
    if (base >= n) return;
    const int adj = total - ((base >= N_HE) ? N_INC : 0);
    int4 vv = *(int4*)(data + base);
    vv.x += adj; vv.y += adj; vv.z += adj; vv.w += adj;
    *(int4*)(data + base) = vv;
}

// fill packed edges at off[dest]+rank[e] — NO atomics
__global__ __launch_bounds__(256) void fill_kernel(
    const int* __restrict__ node_idx, const int* __restrict__ he_idx,
    const float* __restrict__ vals,
    const int* __restrict__ he_off, const int* __restrict__ node_off,
    const int* __restrict__ he_rank, const int* __restrict__ node_rank,
    int2* __restrict__ he_edge, int2* __restrict__ node_edge, int n)
{
    const int e = blockIdx.x * 256 + threadIdx.x;
    if (e >= n) return;
    const int hn = he_idx[e], nd = node_idx[e];
    const int vb = __float_as_int(vals[e]);
    he_edge[he_off[hn] + he_rank[e]] = make_int2(nd, vb);
    node_edge[node_off[nd] + node_rank[e]] = make_int2(hn, vb);
}

// ---------------------------------------------------------------------------
// Split butterfly reduction helper: input a0..a7 (cols l16*8+i, partial over
// edge-slot groups), output s0,s1 = full sums for cols l16*8+2g, +1.
// ---------------------------------------------------------------------------
__device__ __forceinline__ void reduce_groups(
    int lane, float a0, float a1, float a2, float a3,
    float a4, float a5, float a6, float a7, float& s0, float& s1)
{
    const bool hb = (lane & 32) != 0;    // bit1 of group g = lane>>4
    float t0 = hb ? a0 : a4;
    float t1 = hb ? a1 : a5;
    float t2 = hb ? a2 : a6;
    float t3 = hb ? a3 : a7;
    float r0 = __shfl_xor(t0, 32);
    float r1 = __shfl_xor(t1, 32);
    float r2 = __shfl_xor(t2, 32);
    float r3 = __shfl_xor(t3, 32);
    float e0 = (hb ? a4 : a0) + r0;
    float e1 = (hb ? a5 : a1) + r1;
    float e2 = (hb ? a6 : a2) + r2;
    float e3 = (hb ? a7 : a3) + r3;
    const bool lb = (lane & 16) != 0;    // bit0 of group
    float u0 = lb ? e0 : e2;
    float u1 = lb ? e1 : e3;
    float q0 = __shfl_xor(u0, 16);
    float q1 = __shfl_xor(u1, 16);
    s0 = (lb ? e2 : e0) + q0;
    s1 = (lb ? e3 : e1) + q1;
}

// ---------------------------------------------------------------------------
// Fused he-gather (4 edges/wave-iter, 16B/lane, edge prefetch + hoisted
// x1cur read): agg = sum val*m0[src]; writes m0_he AND x1_next.
// ---------------------------------------------------------------------------
__global__ __launch_bounds__(256) void gather_he_kernel(
    const __hip_bfloat16* __restrict__ msrc,
    const __hip_bfloat16* __restrict__ x1cur,
    __hip_bfloat16* __restrict__ m0_he,
    __hip_bfloat16* __restrict__ x1next,
    const int* __restrict__ off, const int2* __restrict__ edges, int n_seg)
{
    const int wave = threadIdx.x >> 6;
    const int lane = threadIdx.x & 63;
    const int row = blockIdx.x * 4 + wave;
    if (row >= n_seg) return;
    const int start = off[row];
    const int end = (row + 1 < n_seg) ? off[row + 1] : N_INC;
    const int g = lane >> 4;
    const int l16 = lane & 15;
    // hoist the epilogue operand load: hides under the gather loop
    const size_t o32 = (size_t)row * 64 + l16 * 4 + g;
    const unsigned xu = ((const unsigned*)x1cur)[o32];
    float a0 = 0.f, a1 = 0.f, a2 = 0.f, a3 = 0.f;
    float a4 = 0.f, a5 = 0.f, a6 = 0.f, a7 = 0.f;
    const unsigned short* s16 = (const unsigned short*)msrc;
    // software pipeline: edge record prefetched one quad ahead
    int e = start;
    int2 ed = (start + g < end) ? edges[start + g] : make_int2(0, 0);
    for (; e + 4 <= end; e += 4) {
        const int2 cur = ed;
        const int ee = e + 4 + g;
        ed = (ee < end) ? edges[ee] : make_int2(0, 0);   // covers tail too
        const float v = __int_as_float(cur.y);
        const uint4 u = *(const uint4*)(s16 + (size_t)cur.x * 128 + l16 * 8);
        a0 += bf_lo(u.x) * v; a1 += bf_hi(u.x) * v;
        a2 += bf_lo(u.y) * v; a3 += bf_hi(u.y) * v;
        a4 += bf_lo(u.z) * v; a5 += bf_hi(u.z) * v;
        a6 += bf_lo(u.w) * v; a7 += bf_hi(u.w) * v;
    }
    if (e < end) {                                       // masked tail (prefetched)
        const float v = __int_as_float(ed.y);
        const uint4 u = *(const uint4*)(s16 + (size_t)ed.x * 128 + l16 * 8);
        a0 += bf_lo(u.x) * v; a1 += bf_hi(u.x) * v;
        a2 += bf_lo(u.y) * v; a3 += bf_hi(u.y) * v;
        a4 += bf_lo(u.z) * v; a5 += bf_hi(u.z) * v;
        a6 += bf_lo(u.w) * v; a7 += bf_hi(u.w) * v;
    }
    float s0, s1;
    reduce_groups(lane, a0, a1, a2, a3, a4, a5, a6, a7, s0, s1);
    ((unsigned*)m0_he)[o32] = bfpack(s0, s1);
    ((unsigned*)x1next)[o32] =
        bfpack(sigmoidf_(bf_lo(xu) + s0), sigmoidf_(bf_hi(xu) + s1));
}

// ---------------------------------------------------------------------------
// Fused node-gather (4 edges/wave-iter, prefetch + hoisted x0 read):
// x0 = sigmoid(x0 + agg) in place.
// ---------------------------------------------------------------------------
__global__ __launch_bounds__(256) void gather_node_kernel(
    const __hip_bfloat16* __restrict__ msrc,
    __hip_bfloat16* __restrict__ x0,
    const int* __restrict__ off, const int2* __restrict__ edges, int n_seg)
{
    const int wave = threadIdx.x >> 6;
    const int lane = threadIdx.x & 63;
    const int row = blockIdx.x * 4 + wave;
    if (row >= n_seg) return;
    const int start = off[row];
    const int end = (row + 1 < n_seg) ? off[row + 1] : N_INC;
    const int g = lane >> 4;
    const int l16 = lane & 15;
    const size_t o32 = (size_t)row * 64 + l16 * 4 + g;
    unsigned* const px = (unsigned*)x0 + o32;
    const unsigned xu = *px;                             // hoisted RMW read
    float a0 = 0.f, a1 = 0.f, a2 = 0.f, a3 = 0.f;
    float a4 = 0.f, a5 = 0.f, a6 = 0.f, a7 = 0.f;
    const unsigned short* s16 = (const unsigned short*)msrc;
    int e = start;
    int2 ed = (start + g < end) ? edges[start + g] : make_int2(0, 0);
    for (; e + 4 <= end; e += 4) {
        const int2 cur = ed;
        const int ee = e + 4 + g;
        ed = (ee < end) ? edges[ee] : make_int2(0, 0);
        const float v = __int_as_float(cur.y);
        const uint4 u = *(const uint4*)(s16 + (size_t)cur.x * 128 + l16 * 8);
        a0 += bf_lo(u.x) * v; a1 += bf_hi(u.x) * v;
        a2 += bf_lo(u.y) * v; a3 += bf_hi(u.y) * v;
        a4 += bf_lo(u.z) * v; a5 += bf_hi(u.z) * v;
        a6 += bf_lo(u.w) * v; a7 += bf_hi(u.w) * v;
    }
    if (e < end) {
        const float v = __int_as_float(ed.y);
        const uint4 u = *(const uint4*)(s16 + (size_t)ed.x * 128 + l16 * 8);
        a0 += bf_lo(u.x) * v; a1 += bf_hi(u.x) * v;
        a2 += bf_lo(u.y) * v; a3 += bf_hi(u.y) * v;
        a4 += bf_lo(u.z) * v; a5 += bf_hi(u.z) * v;
        a6 += bf_lo(u.w) * v; a7 += bf_hi(u.w) * v;
    }
    float s0, s1;
    reduce_groups(lane, a0, a1, a2, a3, a4, a5, a6, a7, s0, s1);
    *px = bfpack(sigmoidf_(bf_lo(xu) + s0), sigmoidf_(bf_hi(xu) + s1));
}

// ---------------------------------------------------------------------------
extern "C" void kernel_launch(void* const* d_in, const int* in_sizes, int n_in,
                              void* d_out, int out_size, void* d_ws, size_t ws_size,
                              hipStream_t stream)
{
    const float* x0_in   = (const float*)d_in[0];
    const float* x1_in   = (const float*)d_in[1];
    const int*   node_idx = (const int*)d_in[2];
    const int*   he_idx   = (const int*)d_in[3];
    const float* inc_vals = (const float*)d_in[4];
    const float* W_enc   = (const float*)d_in[5];
    const float* b_enc   = (const float*)d_in[6];
    const float* W_msg0  = (const float*)d_in[7];
    const float* b_msg0  = (const float*)d_in[8];
    const float* W_msg1  = (const float*)d_in[9];
    const float* b_msg1  = (const float*)d_in[10];
    const float* W_out   = (const float*)d_in[11];
    const float* b_out   = (const float*)d_in[12];
    float* out = (float*)d_out;

    __hip_bfloat16* x0h    = (__hip_bfloat16*)d_ws;         // 12,800,000
    __hip_bfloat16* x1a    = x0h + 12800000;                //  6,400,000
    __hip_bfloat16* x1b    = x1a + 6400000;                 //  6,400,000
    __hip_bfloat16* mbuf   = x1b + 6400000;                 // 12,800,000
    __hip_bfloat16* m0_he  = mbuf + 12800000;               //  6,400,000
    __hip_bfloat16* Wt_enc = m0_he + 6400000;               // 32768
    __hip_bfloat16* Wt_m0  = Wt_enc + 32768;                // 32768
    __hip_bfloat16* Wt_m1  = Wt_m0 + 32768;                 // 65536
    __hip_bfloat16* Wt_out = Wt_m1 + 65536;                 // 6144
    int*  he_off    = (int*)(Wt_out + 6144);
    int*  node_off  = he_off + N_HE;
    int*  bsums     = node_off + N_NODES;                   // 256
    int*  he_rank   = bsums + 256;                          // 600k
    int*  node_rank = he_rank + N_INC;                      // 600k
    int2* he_edge   = (int2*)(node_rank + N_INC);
    int2* node_edge = he_edge + N_INC;

    // ---- prep (weight transpose + zero CSR counts) ----
    prep_kernel<<<(137216 + N_HE + N_NODES + 255) / 256, 256, 0, stream>>>(
        W_enc, W_msg0, W_msg1, W_out, Wt_enc, Wt_m0, Wt_m1, Wt_out, he_off);

    // ---- CSR build ----
    hist_kernel<<<(N_INC + 255) / 256, 256, 0, stream>>>(
        he_idx, node_idx, he_off, node_off, he_rank, node_rank, N_INC);
    const int scan_n = N_HE + N_NODES;
    const int scan_blocks = (scan_n + 1023) / 1024;          // 147
    scan1_kernel<<<scan_blocks, 256, 0, stream>>>(he_off, bsums, scan_n);
    scan23_kernel<<<scan_blocks, 256, 0, stream>>>(he_off, bsums, scan_n, scan_blocks);
    fill_kernel<<<(N_INC + 255) / 256, 256, 0, stream>>>(
        node_idx, he_idx, inc_vals, he_off, node_off, he_rank, node_rank,
        he_edge, node_edge, N_INC);

    // ---- encode: one dispatch for both inputs ----
    const int NB0 = (N_NODES + 127) / 128;                   // 782
    const int NB1 = (N_HE + 127) / 128;                      // 391
    gemm_enc2<<<NB0 + NB1, 256, 0, stream>>>(
        x0_in, x1_in, Wt_enc, b_enc, x0h, x1a, NB0);

    __hip_bfloat16* x1cur = x1a;
    __hip_bfloat16* x1nxt = x1b;
    for (int l = 0; l < 2; ++l) {
        gemm_st<1, false><<<(N_NODES + 127) / 128, 256, 0, stream>>>(
            x0h, nullptr, Wt_m0 + (size_t)l * 16384,
            b_msg0 + (size_t)l * 128, mbuf, N_NODES, 1);
        gather_he_kernel<<<(N_HE + 3) / 4, 256, 0, stream>>>(
            mbuf, x1cur, m0_he, x1nxt, he_off, he_edge, N_HE);
        gemm_st<2, true><<<(N_HE + 127) / 128, 256, 0, stream>>>(
            x1cur, m0_he, Wt_m1 + (size_t)l * 32768,
            b_msg1 + (size_t)l * 128, mbuf, N_HE, 1);
        gather_node_kernel<<<(N_NODES + 3) / 4, 256, 0, stream>>>(
            mbuf, x0h, node_off, node_edge, N_NODES);
        __hip_bfloat16* t = x1cur; x1cur = x1nxt; x1nxt = t;
    }

    out_gemm_mfma<<<(N_NODES + 63) / 64, 256, 0, stream>>>(
        x0h, Wt_out, b_out, out, N_NODES);
}

// Round 7
// 515.419 us; speedup vs baseline: 1.2568x; 1.0008x over previous
//
#include <hip/hip_runtime.h>
#include <hip/hip_bf16.h>
#include <math.h>

#define N_NODES 100000
#define N_HE    50000
#define N_INC   600000
#define D_IN    256
#define D_H     128
#define N_CLASSES 40

typedef __attribute__((ext_vector_type(8))) short short8;
typedef __attribute__((ext_vector_type(4))) float f32x4;

// fast sigmoid: v_exp-based, ~4 inst. Error ~1e-6 rel, invisible under bf16.
__device__ __forceinline__ float sigmoidf_(float x) {
    return __builtin_amdgcn_rcpf(1.0f + __expf(-x));
}

__device__ __forceinline__ short bfbits(float f) {
    __hip_bfloat16 h = __float2bfloat16(f);
    return *reinterpret_cast<short*>(&h);
}

__device__ __forceinline__ float bf_lo(unsigned u) { return __uint_as_float(u << 16); }
__device__ __forceinline__ float bf_hi(unsigned u) { return __uint_as_float(u & 0xffff0000u); }
__device__ __forceinline__ unsigned bfpack(float a, float b) {
    return (unsigned)(unsigned short)bfbits(a) | ((unsigned)(unsigned short)bfbits(b) << 16);
}

// async global->LDS, 16 B per lane; LDS dest is wave-uniform base + lane*16
__device__ __forceinline__ void gload_lds16(const void* g, void* l) {
    __builtin_amdgcn_global_load_lds(
        (const __attribute__((address_space(1))) unsigned int*)g,
        (__attribute__((address_space(3))) unsigned int*)l, 16, 0, 0);
}

// ---------------------------------------------------------------------------
// Staged MFMA GEMM: C(M x 128) = act( A @ W + bias ), bf16, fp32 acc.
// BM=64 geometry: LDS = 16KB sA + 32KB sB = 48KB -> 3 blocks/CU (12 waves),
// vs old BM=128/64KB/2 blocks (latency-bound at 17% occupancy).
// A/B staged via global_load_lds (linear dest, XOR-swizzled source
// chunk ^= row&7; read applies the same XOR).
// Block = 256 thr (4 waves 2x2), wave tile 32x64.
// ---------------------------------------------------------------------------
template<int KT, bool SPLIT>
__global__ __launch_bounds__(256) void gemm_st(
    const __hip_bfloat16* __restrict__ A1,
    const __hip_bfloat16* __restrict__ A2,
    const __hip_bfloat16* __restrict__ Wt,   // 128 x (KT*128) bf16, n-major
    const float* __restrict__ bias,
    __hip_bfloat16* __restrict__ C,          // M x 128 bf16
    int M, int act)
{
    __shared__ uint4 smemv[3072];            // 49152 B
    char* const sA = (char*)smemv;           // 16384 B: [64 rows][16 x 16B]
    char* const sB = (char*)smemv + 16384;   // 32768 B: [128 n  ][16 x 16B]

    const int tid = threadIdx.x;
    const int wave = tid >> 6, lane = tid & 63;
    const int quad = lane >> 4, nn = lane & 15;
    const int wr = wave >> 1, wc = wave & 1;
    const int row_base = blockIdx.x * 64;
    const int col_base = wc * 64;

    f32x4 acc[2][4] = {};

    for (int h = 0; h < KT; ++h) {
        const char* Asrc = (const char*)(SPLIT ? (h ? A2 : A1) : A1);
        const size_t astride = SPLIT ? 256 : (size_t)KT * 256;   // row bytes
        const size_t aoff = SPLIT ? 0 : (size_t)h * 256;
        // ---- stage A: 1024 slots of 16 B (4 DMA calls/wave)
#pragma unroll
        for (int j = 0; j < 4; ++j) {
            const int sb = j * 4 + wave;          // slot-block 0..15
            const int s = sb * 64 + lane;         // slot 0..1023
            const int row = s >> 4, c = s & 15;
            int grow = row_base + row; if (grow >= M) grow = M - 1;
            gload_lds16(Asrc + (size_t)grow * astride + aoff + ((c ^ (row & 7)) * 16),
                        sA + sb * 1024);
        }
        // ---- stage B: 2048 slots (8 DMA calls/wave)
#pragma unroll
        for (int j = 0; j < 8; ++j) {
            const int sb = j * 4 + wave;          // 0..31
            const int s = sb * 64 + lane;
            const int n = s >> 4, c = s & 15;
            gload_lds16((const char*)Wt + (size_t)n * (KT * 256) + (size_t)h * 256
                            + ((c ^ (n & 7)) * 16),
                        sB + sb * 1024);
        }
        __syncthreads();   // compiler drains vmcnt before barrier

#pragma unroll
        for (int ks = 0; ks < 4; ++ks) {
            short8 a[2], b[4];
#pragma unroll
            for (int rt = 0; rt < 2; ++rt) {
                const int row = wr * 32 + rt * 16 + nn;
                a[rt] = *(const short8*)(sA + row * 256 + (((ks * 4 + quad) ^ (row & 7)) * 16));
            }
#pragma unroll
            for (int ct = 0; ct < 4; ++ct) {
                const int n = col_base + ct * 16 + nn;
                b[ct] = *(const short8*)(sB + n * 256 + (((ks * 4 + quad) ^ (n & 7)) * 16));
            }
#pragma unroll
            for (int ct = 0; ct < 4; ++ct)
#pragma unroll
                for (int rt = 0; rt < 2; ++rt)
                    acc[rt][ct] = __builtin_amdgcn_mfma_f32_16x16x32_bf16(
                        a[rt], b[ct], acc[rt][ct], 0, 0, 0);
        }
        __syncthreads();   // protects sA/sB overwrite (and sC reuse below)
    }

    float bs[4];
#pragma unroll
    for (int ct = 0; ct < 4; ++ct) bs[ct] = bias[col_base + ct * 16 + nn];

    // ---- stage C tile into LDS (bf16, stride 136 -> 2-way only) ----
    constexpr int KP = 136;
    unsigned short* sC = (unsigned short*)smemv;
#pragma unroll
    for (int rt = 0; rt < 2; ++rt) {
#pragma unroll
        for (int i = 0; i < 4; ++i) {
            const int R = wr * 32 + rt * 16 + quad * 4 + i;
#pragma unroll
            for (int ct = 0; ct < 4; ++ct) {
                float v = acc[rt][ct][i] + bs[ct];
                if (act) v = sigmoidf_(v);
                sC[R * KP + col_base + ct * 16 + nn] = (unsigned short)bfbits(v);
            }
        }
    }
    __syncthreads();

    // ---- cooperative coalesced store: thread t -> row t/4, quarter t&3 ----
    {
        const int row = tid >> 2, q = tid & 3;
        const int gr = row_base + row;
        if (gr < M) {
            const unsigned short* srcp = sC + row * KP + q * 32;
            uint4* dstp = (uint4*)(C + (size_t)gr * 128 + q * 32);
#pragma unroll
            for (int j = 0; j < 4; ++j) dstp[j] = *(const uint4*)(srcp + j * 8);
        }
    }
}

// ---------------------------------------------------------------------------
// Fused fp32-encode GEMM, BOTH inputs in one dispatch (block-range select):
// C(M x 128) = A_fp32(M x 256) @ W + bias, bf16 out.  BM=64 / 48KB LDS.
// A fp32 loads are issued FIRST (before B DMA): vmcnt is FIFO, so waiting
// on A results must not drain the B global_load_lds queue.
// ---------------------------------------------------------------------------
__global__ __launch_bounds__(256) void gemm_enc2(
    const float* __restrict__ A0,            // N_NODES x 256 fp32
    const float* __restrict__ A1src,         // N_HE x 256 fp32
    const __hip_bfloat16* __restrict__ Wt,   // 128 x 256 bf16, n-major
    const float* __restrict__ bias,
    __hip_bfloat16* __restrict__ C0,
    __hip_bfloat16* __restrict__ C1,
    int NB0)                                 // blocks covering A0
{
    __shared__ uint4 smemv[3072];            // 49152 B
    char* const sA = (char*)smemv;           // 16384 B
    char* const sB = (char*)smemv + 16384;   // 32768 B

    const int tid = threadIdx.x;
    const int wave = tid >> 6, lane = tid & 63;
    const int quad = lane >> 4, nn = lane & 15;
    const int wr = wave >> 1, wc = wave & 1;

    const int b = blockIdx.x;
    const bool first = (b < NB0);
    const float* const A = first ? A0 : A1src;
    __hip_bfloat16* const C = first ? C0 : C1;
    const int M = first ? N_NODES : N_HE;
    const int row_base = (first ? b : b - NB0) * 64;
    const int col_base = wc * 64;

    f32x4 acc[2][4] = {};

    for (int h = 0; h < 2; ++h) {
        // ---- issue A fp32 loads FIRST (1024 slots, 4/thread, 32B each)
        float4 pv[4], qv[4];
#pragma unroll
        for (int j = 0; j < 4; ++j) {
            const int s = j * 256 + tid;          // slot 0..1023
            const int row = s >> 4, c = s & 15;
            int grow = row_base + row; if (grow >= M) grow = M - 1;
            const float* ap = A + (size_t)grow * 256 + h * 128 + c * 8;
            pv[j] = *(const float4*)ap;
            qv[j] = *(const float4*)(ap + 4);
        }
        // ---- stage B (bf16 weights) via DMA (async, drains at barrier)
#pragma unroll
        for (int j = 0; j < 8; ++j) {
            const int sb = j * 4 + wave;
            const int s = sb * 64 + lane;
            const int n = s >> 4, c = s & 15;
            gload_lds16((const char*)Wt + (size_t)n * 512 + (size_t)h * 256
                            + ((c ^ (n & 7)) * 16),
                        sB + sb * 1024);
        }
        // ---- convert + swizzled LDS write (waits only on A loads)
#pragma unroll
        for (int j = 0; j < 4; ++j) {
            const int s = j * 256 + tid;
            const int row = s >> 4, c = s & 15;
            uint4 r;
            r.x = bfpack(pv[j].x, pv[j].y); r.y = bfpack(pv[j].z, pv[j].w);
            r.z = bfpack(qv[j].x, qv[j].y); r.w = bfpack(qv[j].z, qv[j].w);
            *(uint4*)(sA + row * 256 + ((c ^ (row & 7)) * 16)) = r;
        }
        __syncthreads();

#pragma unroll
        for (int ks = 0; ks < 4; ++ks) {
            short8 a[2], b2[4];
#pragma unroll
            for (int rt = 0; rt < 2; ++rt) {
                const int row = wr * 32 + rt * 16 + nn;
                a[rt] = *(const short8*)(sA + row * 256 + (((ks * 4 + quad) ^ (row & 7)) * 16));
            }
#pragma unroll
            for (int ct = 0; ct < 4; ++ct) {
                const int n = col_base + ct * 16 + nn;
                b2[ct] = *(const short8*)(sB + n * 256 + (((ks * 4 + quad) ^ (n & 7)) * 16));
            }
#pragma unroll
            for (int ct = 0; ct < 4; ++ct)
#pragma unroll
                for (int rt = 0; rt < 2; ++rt)
                    acc[rt][ct] = __builtin_amdgcn_mfma_f32_16x16x32_bf16(
                        a[rt], b2[ct], acc[rt][ct], 0, 0, 0);
        }
        __syncthreads();
    }

    float bs[4];
#pragma unroll
    for (int ct = 0; ct < 4; ++ct) bs[ct] = bias[col_base + ct * 16 + nn];

    constexpr int KP = 136;
    unsigned short* sC = (unsigned short*)smemv;
#pragma unroll
    for (int rt = 0; rt < 2; ++rt) {
#pragma unroll
        for (int i = 0; i < 4; ++i) {
            const int R = wr * 32 + rt * 16 + quad * 4 + i;
#pragma unroll
            for (int ct = 0; ct < 4; ++ct) {
                const float v = acc[rt][ct][i] + bs[ct];
                sC[R * KP + col_base + ct * 16 + nn] = (unsigned short)bfbits(v);
            }
        }
    }
    __syncthreads();

    {
        const int row = tid >> 2, q = tid & 3;
        const int gr = row_base + row;
        if (gr < M) {
            const unsigned short* srcp = sC + row * KP + q * 32;
            uint4* dstp = (uint4*)(C + (size_t)gr * 128 + q * 32);
#pragma unroll
            for (int j = 0; j < 4; ++j) dstp[j] = *(const uint4*)(srcp + j * 8);
        }
    }
}

// ---------------------------------------------------------------------------
// MFMA output GEMM: out(M x 40) = X(M x 128 bf16) @ W + b, fp32 out.
// ---------------------------------------------------------------------------
__global__ __launch_bounds__(256) void out_gemm_mfma(
    const __hip_bfloat16* __restrict__ X,
    const __hip_bfloat16* __restrict__ Wt,   // 48 x 128 bf16 (n-major, padded)
    const float* __restrict__ b, float* __restrict__ out, int M)
{
    constexpr int KP = 136;
    __shared__ uint4 sXv[1024];              // 16384 B: [64 rows][16 x 16B]
    __shared__ __hip_bfloat16 sW[48 * KP];
    __shared__ float sB[48];
    __shared__ float sO[64 * 44];            // 11264 B

    char* const sX = (char*)sXv;
    const int tid = threadIdx.x;
    const int wave = tid >> 6, lane = tid & 63;

    // stage X: 1024 slots, 4 calls/wave
#pragma unroll
    for (int j = 0; j < 4; ++j) {
        const int sb = j * 4 + wave;          // 0..15
        const int s = sb * 64 + lane;         // 0..1023
        const int row = s >> 4, c = s & 15;
        int grow = blockIdx.x * 64 + row; if (grow >= M) grow = M - 1;
        gload_lds16((const char*)X + (size_t)grow * 256 + ((c ^ (row & 7)) * 16),
                    sX + sb * 1024);
    }
    for (int c = tid; c < 48 * 16; c += 256) {
        const int n = c >> 4, ko = (c & 15) * 8;
        *(uint4*)&sW[n * KP + ko] = *(const uint4*)&Wt[n * 128 + ko];
    }
    if (tid < 48) sB[tid] = (tid < 40) ? b[tid] : 0.0f;
    __syncthreads();

    const int quad = lane >> 4, nn = lane & 15;

    f32x4 acc[3] = {};
#pragma unroll
    for (int ks = 0; ks < 4; ++ks) {
        const int rowl = wave * 16 + nn;
        const short8 a = *(const short8*)(sX + rowl * 256 + (((ks * 4 + quad) ^ (rowl & 7)) * 16));
#pragma unroll
        for (int ct = 0; ct < 3; ++ct) {
            const short8 bf = *(const short8*)&sW[(ct * 16 + nn) * KP + ks * 32 + quad * 8];
            acc[ct] = __builtin_amdgcn_mfma_f32_16x16x32_bf16(a, bf, acc[ct], 0, 0, 0);
        }
    }

    // stage into LDS
#pragma unroll
    for (int ct = 0; ct < 3; ++ct) {
        const int c = ct * 16 + nn;
        if (c < 40) {
#pragma unroll
            for (int i = 0; i < 4; ++i) {
                const int rl = wave * 16 + quad * 4 + i;
                sO[rl * 44 + c] = acc[ct][i] + sB[c];
            }
        }
    }
    __syncthreads();

    // cooperative store: 64 rows x 10 float4
    for (int c = tid; c < 640; c += 256) {
        const int row = c / 10, ch = c % 10;
        const int gr = blockIdx.x * 64 + row;
        if (gr < M)
            *(float4*)(out + (size_t)gr * 40 + ch * 4) =
                *(const float4*)(sO + row * 44 + ch * 4);
    }
}

// ---------------------------------------------------------------------------
// Prep: weight transpose/convert (fp32 -> bf16 n-major) + zero CSR counts.
// ---------------------------------------------------------------------------
__global__ __launch_bounds__(256) void prep_kernel(
    const float* __restrict__ We, const float* __restrict__ Wm0,
    const float* __restrict__ Wm1, const float* __restrict__ Wout,
    __hip_bfloat16* __restrict__ Wt_enc, __hip_bfloat16* __restrict__ Wt_m0,
    __hip_bfloat16* __restrict__ Wt_m1, __hip_bfloat16* __restrict__ Wt_out,
    int* __restrict__ cnt_zero)
{
    const int i = blockIdx.x * 256 + threadIdx.x;
    if (i < 32768) {
        const int n = i >> 8, k = i & 255;
        Wt_enc[n * 256 + k] = __float2bfloat16(We[k * 128 + n]);
    } else if (i < 65536) {
        int j = i - 32768; const int l = j >> 14; j &= 16383;
        const int n = j >> 7, k = j & 127;
        Wt_m0[l * 16384 + n * 128 + k] = __float2bfloat16(Wm0[l * 16384 + k * 128 + n]);
    } else if (i < 131072) {
        int j = i - 65536; const int l = j >> 15; j &= 32767;
        const int n = j >> 8, k = j & 255;
        Wt_m1[l * 32768 + n * 256 + k] = __float2bfloat16(Wm1[l * 32768 + k * 128 + n]);
    } else if (i < 137216) {
        const int j = i - 131072;
        const int n = j >> 7, k = j & 127;
        Wt_out[n * 128 + k] = (n < 40) ? __float2bfloat16(Wout[k * 40 + n])
                                       : __float2bfloat16(0.0f);
    } else {
        const int z = i - 137216;
        if (z < N_HE + N_NODES) cnt_zero[z] = 0;
    }
}

// ---------------------------------------------------------------------------
// CSR build (atomic-free fill: hist captures per-edge rank)
// ---------------------------------------------------------------------------
__global__ __launch_bounds__(256) void hist_kernel(
    const int* __restrict__ he_idx, const int* __restrict__ node_idx,
    int* __restrict__ he_cnt, int* __restrict__ node_cnt,
    int* __restrict__ he_rank, int* __restrict__ node_rank, int n)
{
    const int i = blockIdx.x * 256 + threadIdx.x;
    if (i < n) {
        he_rank[i] = atomicAdd(&he_cnt[he_idx[i]], 1);
        node_rank[i] = atomicAdd(&node_cnt[node_idx[i]], 1);
    }
}

__global__ __launch_bounds__(256) void scan1_kernel(
    int* __restrict__ data, int* __restrict__ bsums, int n)
{
    __shared__ int s[256];
    const int t = threadIdx.x;
    const int base = blockIdx.x * 1024 + t * 4;
    int4 v = make_int4(0, 0, 0, 0);
    if (base < n) v = *(const int4*)(data + base);
    s[t] = v.x + v.y + v.z + v.w;
    __syncthreads();
    for (int d = 1; d < 256; d <<= 1) {
        const int u = (t >= d) ? s[t - d] : 0;
        __syncthreads();
        s[t] += u;
        __syncthreads();
    }
    if (t == 255) bsums[blockIdx.x] = s[255];
    int e = t ? s[t - 1] : 0;
    if (base < n) {
        int4 o;
        o.x = e; e += v.x; o.y = e; e += v.y; o.z = e; e += v.z; o.w = e;
        *(int4*)(data + base) = o;
    }
}

// scan2+scan3 fused: each block locally reduces bsums[0..bid-1], then adds.
__global__ __launch_bounds__(256) void scan23_kernel(
    int* __restrict__ data, const int* __restrict__ bsums, int n, int nb)
{
    __shared__ int s[256];
    const int t = threadIdx.x;
    const int v = (t < nb && t < (int)blockIdx.x) ? bsums[t] : 0;
    s[t] = v;
    __syncthreads();
    for (int d = 1; d < 256; d <<= 1) {
        const int u = (t >= d) ? s[t - d] : 0;
        __syncthreads();
        s[t] += u;
        __syncthreads();
    }
    const int total = s[255];                 // sum of bsums[0..bid-1]
    const int base = blockIdx.x * 1024 + t * 4;
    if (base >= n) return;
    const int adj = total - ((base >= N_HE) ? N_INC : 0);
    int4 vv = *(int4*)(data + base);
    vv.x += adj; vv.y += adj; vv.z += adj; vv.w += adj;
    *(int4*)(data + base) = vv;
}

// fill packed edges at off[dest]+rank[e] — NO atomics
__global__ __launch_bounds__(256) void fill_kernel(
    const int* __restrict__ node_idx, const int* __restrict__ he_idx,
    const float* __restrict__ vals,
    const int* __restrict__ he_off, const int* __restrict__ node_off,
    const int* __restrict__ he_rank, const int* __restrict__ node_rank,
    int2* __restrict__ he_edge, int2* __restrict__ node_edge, int n)
{
    const int e = blockIdx.x * 256 + threadIdx.x;
    if (e >= n) return;
    const int hn = he_idx[e], nd = node_idx[e];
    const int vb = __float_as_int(vals[e]);
    he_edge[he_off[hn] + he_rank[e]] = make_int2(nd, vb);
    node_edge[node_off[nd] + node_rank[e]] = make_int2(hn, vb);
}

// ---------------------------------------------------------------------------
// Split butterfly reduction helper: input a0..a7 (cols l16*8+i, partial over
// edge-slot groups), output s0,s1 = full sums for cols l16*8+2g, +1.
// ---------------------------------------------------------------------------
__device__ __forceinline__ void reduce_groups(
    int lane, float a0, float a1, float a2, float a3,
    float a4, float a5, float a6, float a7, float& s0, float& s1)
{
    const bool hb = (lane & 32) != 0;    // bit1 of group g = lane>>4
    float t0 = hb ? a0 : a4;
    float t1 = hb ? a1 : a5;
    float t2 = hb ? a2 : a6;
    float t3 = hb ? a3 : a7;
    float r0 = __shfl_xor(t0, 32);
    float r1 = __shfl_xor(t1, 32);
    float r2 = __shfl_xor(t2, 32);
    float r3 = __shfl_xor(t3, 32);
    float e0 = (hb ? a4 : a0) + r0;
    float e1 = (hb ? a5 : a1) + r1;
    float e2 = (hb ? a6 : a2) + r2;
    float e3 = (hb ? a7 : a3) + r3;
    const bool lb = (lane & 16) != 0;    // bit0 of group
    float u0 = lb ? e0 : e2;
    float u1 = lb ? e1 : e3;
    float q0 = __shfl_xor(u0, 16);
    float q1 = __shfl_xor(u1, 16);
    s0 = (lb ? e2 : e0) + q0;
    s1 = (lb ? e3 : e1) + q1;
}

// ---------------------------------------------------------------------------
// Fused he-gather (4 edges/wave-iter, 16B/lane, edge prefetch + hoisted
// x1cur read): agg = sum val*m0[src]; writes m0_he AND x1_next.
// ---------------------------------------------------------------------------
__global__ __launch_bounds__(256) void gather_he_kernel(
    const __hip_bfloat16* __restrict__ msrc,
    const __hip_bfloat16* __restrict__ x1cur,
    __hip_bfloat16* __restrict__ m0_he,
    __hip_bfloat16* __restrict__ x1next,
    const int* __restrict__ off, const int2* __restrict__ edges, int n_seg)
{
    const int wave = threadIdx.x >> 6;
    const int lane = threadIdx.x & 63;
    const int row = blockIdx.x * 4 + wave;
    if (row >= n_seg) return;
    const int start = off[row];
    const int end = (row + 1 < n_seg) ? off[row + 1] : N_INC;
    const int g = lane >> 4;
    const int l16 = lane & 15;
    // hoist the epilogue operand load: hides under the gather loop
    const size_t o32 = (size_t)row * 64 + l16 * 4 + g;
    const unsigned xu = ((const unsigned*)x1cur)[o32];
    float a0 = 0.f, a1 = 0.f, a2 = 0.f, a3 = 0.f;
    float a4 = 0.f, a5 = 0.f, a6 = 0.f, a7 = 0.f;
    const unsigned short* s16 = (const unsigned short*)msrc;
    // software pipeline: edge record prefetched one quad ahead
    int e = start;
    int2 ed = (start + g < end) ? edges[start + g] : make_int2(0, 0);
    for (; e + 4 <= end; e += 4) {
        const int2 cur = ed;
        const int ee = e + 4 + g;
        ed = (ee < end) ? edges[ee] : make_int2(0, 0);   // covers tail too
        const float v = __int_as_float(cur.y);
        const uint4 u = *(const uint4*)(s16 + (size_t)cur.x * 128 + l16 * 8);
        a0 += bf_lo(u.x) * v; a1 += bf_hi(u.x) * v;
        a2 += bf_lo(u.y) * v; a3 += bf_hi(u.y) * v;
        a4 += bf_lo(u.z) * v; a5 += bf_hi(u.z) * v;
        a6 += bf_lo(u.w) * v; a7 += bf_hi(u.w) * v;
    }
    if (e < end) {                                       // masked tail (prefetched)
        const float v = __int_as_float(ed.y);
        const uint4 u = *(const uint4*)(s16 + (size_t)ed.x * 128 + l16 * 8);
        a0 += bf_lo(u.x) * v; a1 += bf_hi(u.x) * v;
        a2 += bf_lo(u.y) * v; a3 += bf_hi(u.y) * v;
        a4 += bf_lo(u.z) * v; a5 += bf_hi(u.z) * v;
        a6 += bf_lo(u.w) * v; a7 += bf_hi(u.w) * v;
    }
    float s0, s1;
    reduce_groups(lane, a0, a1, a2, a3, a4, a5, a6, a7, s0, s1);
    ((unsigned*)m0_he)[o32] = bfpack(s0, s1);
    ((unsigned*)x1next)[o32] =
        bfpack(sigmoidf_(bf_lo(xu) + s0), sigmoidf_(bf_hi(xu) + s1));
}

// ---------------------------------------------------------------------------
// Fused node-gather (4 edges/wave-iter, prefetch + hoisted x0 read):
// x0 = sigmoid(x0 + agg) in place.
// ---------------------------------------------------------------------------
__global__ __launch_bounds__(256) void gather_node_kernel(
    const __hip_bfloat16* __restrict__ msrc,
    __hip_bfloat16* __restrict__ x0,
    const int* __restrict__ off, const int2* __restrict__ edges, int n_seg)
{
    const int wave = threadIdx.x >> 6;
    const int lane = threadIdx.x & 63;
    const int row = blockIdx.x * 4 + wave;
    if (row >= n_seg) return;
    const int start = off[row];
    const int end = (row + 1 < n_seg) ? off[row + 1] : N_INC;
    const int g = lane >> 4;
    const int l16 = lane & 15;
    const size_t o32 = (size_t)row * 64 + l16 * 4 + g;
    unsigned* const px = (unsigned*)x0 + o32;
    const unsigned xu = *px;                             // hoisted RMW read
    float a0 = 0.f, a1 = 0.f, a2 = 0.f, a3 = 0.f;
    float a4 = 0.f, a5 = 0.f, a6 = 0.f, a7 = 0.f;
    const unsigned short* s16 = (const unsigned short*)msrc;
    int e = start;
    int2 ed = (start + g < end) ? edges[start + g] : make_int2(0, 0);
    for (; e + 4 <= end; e += 4) {
        const int2 cur = ed;
        const int ee = e + 4 + g;
        ed = (ee < end) ? edges[ee] : make_int2(0, 0);
        const float v = __int_as_float(cur.y);
        const uint4 u = *(const uint4*)(s16 + (size_t)cur.x * 128 + l16 * 8);
        a0 += bf_lo(u.x) * v; a1 += bf_hi(u.x) * v;
        a2 += bf_lo(u.y) * v; a3 += bf_hi(u.y) * v;
        a4 += bf_lo(u.z) * v; a5 += bf_hi(u.z) * v;
        a6 += bf_lo(u.w) * v; a7 += bf_hi(u.w) * v;
    }
    if (e < end) {
        const float v = __int_as_float(ed.y);
        const uint4 u = *(const uint4*)(s16 + (size_t)ed.x * 128 + l16 * 8);
        a0 += bf_lo(u.x) * v; a1 += bf_hi(u.x) * v;
        a2 += bf_lo(u.y) * v; a3 += bf_hi(u.y) * v;
        a4 += bf_lo(u.z) * v; a5 += bf_hi(u.z) * v;
        a6 += bf_lo(u.w) * v; a7 += bf_hi(u.w) * v;
    }
    float s0, s1;
    reduce_groups(lane, a0, a1, a2, a3, a4, a5, a6, a7, s0, s1);
    *px = bfpack(sigmoidf_(bf_lo(xu) + s0), sigmoidf_(bf_hi(xu) + s1));
}

// ---------------------------------------------------------------------------
extern "C" void kernel_launch(void* const* d_in, const int* in_sizes, int n_in,
                              void* d_out, int out_size, void* d_ws, size_t ws_size,
                              hipStream_t stream)
{
    const float* x0_in   = (const float*)d_in[0];
    const float* x1_in   = (const float*)d_in[1];
    const int*   node_idx = (const int*)d_in[2];
    const int*   he_idx   = (const int*)d_in[3];
    const float* inc_vals = (const float*)d_in[4];
    const float* W_enc   = (const float*)d_in[5];
    const float* b_enc   = (const float*)d_in[6];
    const float* W_msg0  = (const float*)d_in[7];
    const float* b_msg0  = (const float*)d_in[8];
    const float* W_msg1  = (const float*)d_in[9];
    const float* b_msg1  = (const float*)d_in[10];
    const float* W_out   = (const float*)d_in[11];
    const float* b_out   = (const float*)d_in[12];
    float* out = (float*)d_out;

    __hip_bfloat16* x0h    = (__hip_bfloat16*)d_ws;         // 12,800,000
    __hip_bfloat16* x1a    = x0h + 12800000;                //  6,400,000
    __hip_bfloat16* x1b    = x1a + 6400000;                 //  6,400,000
    __hip_bfloat16* mbuf   = x1b + 6400000;                 // 12,800,000
    __hip_bfloat16* m0_he  = mbuf + 12800000;               //  6,400,000
    __hip_bfloat16* Wt_enc = m0_he + 6400000;               // 32768
    __hip_bfloat16* Wt_m0  = Wt_enc + 32768;                // 32768
    __hip_bfloat16* Wt_m1  = Wt_m0 + 32768;                 // 65536
    __hip_bfloat16* Wt_out = Wt_m1 + 65536;                 // 6144
    int*  he_off    = (int*)(Wt_out + 6144);
    int*  node_off  = he_off + N_HE;
    int*  bsums     = node_off + N_NODES;                   // 256
    int*  he_rank   = bsums + 256;                          // 600k
    int*  node_rank = he_rank + N_INC;                      // 600k
    int2* he_edge   = (int2*)(node_rank + N_INC);
    int2* node_edge = he_edge + N_INC;

    // ---- prep (weight transpose + zero CSR counts) ----
    prep_kernel<<<(137216 + N_HE + N_NODES + 255) / 256, 256, 0, stream>>>(
        W_enc, W_msg0, W_msg1, W_out, Wt_enc, Wt_m0, Wt_m1, Wt_out, he_off);

    // ---- CSR build ----
    hist_kernel<<<(N_INC + 255) / 256, 256, 0, stream>>>(
        he_idx, node_idx, he_off, node_off, he_rank, node_rank, N_INC);
    const int scan_n = N_HE + N_NODES;
    const int scan_blocks = (scan_n + 1023) / 1024;          // 147
    scan1_kernel<<<scan_blocks, 256, 0, stream>>>(he_off, bsums, scan_n);
    scan23_kernel<<<scan_blocks, 256, 0, stream>>>(he_off, bsums, scan_n, scan_blocks);
    fill_kernel<<<(N_INC + 255) / 256, 256, 0, stream>>>(
        node_idx, he_idx, inc_vals, he_off, node_off, he_rank, node_rank,
        he_edge, node_edge, N_INC);

    // ---- encode: one dispatch for both inputs ----
    const int NB0 = (N_NODES + 63) / 64;                     // 1563
    const int NB1 = (N_HE + 63) / 64;                        // 782
    gemm_enc2<<<NB0 + NB1, 256, 0, stream>>>(
        x0_in, x1_in, Wt_enc, b_enc, x0h, x1a, NB0);

    __hip_bfloat16* x1cur = x1a;
    __hip_bfloat16* x1nxt = x1b;
    for (int l = 0; l < 2; ++l) {
        gemm_st<1, false><<<(N_NODES + 63) / 64, 256, 0, stream>>>(
            x0h, nullptr, Wt_m0 + (size_t)l * 16384,
            b_msg0 + (size_t)l * 128, mbuf, N_NODES, 1);
        gather_he_kernel<<<(N_HE + 3) / 4, 256, 0, stream>>>(
            mbuf, x1cur, m0_he, x1nxt, he_off, he_edge, N_HE);
        gemm_st<2, true><<<(N_HE + 63) / 64, 256, 0, stream>>>(
            x1cur, m0_he, Wt_m1 + (size_t)l * 32768,
            b_msg1 + (size_t)l * 128, mbuf, N_HE, 1);
        gather_node_kernel<<<(N_NODES + 3) / 4, 256, 0, stream>>>(
            mbuf, x0h, node_off, node_edge, N_NODES);
        __hip_bfloat16* t = x1cur; x1cur = x1nxt; x1nxt = t;
    }

    out_gemm_mfma<<<(N_NODES + 63) / 64, 256, 0, stream>>>(
        x0h, Wt_out, b_out, out, N_NODES);
}

// Round 8
// 511.939 us; speedup vs baseline: 1.2653x; 1.0068x over previous
//
#include <hip/hip_runtime.h>
#include <hip/hip_bf16.h>
#include <math.h>

#define N_NODES 100000
#define N_HE    50000
#define N_INC   600000
#define D_IN    256
#define D_H     128
#define N_CLASSES 40

typedef __attribute__((ext_vector_type(8))) short short8;
typedef __attribute__((ext_vector_type(4))) float f32x4;

// fast sigmoid: v_exp-based, ~4 inst. Error ~1e-6 rel, invisible under bf16.
__device__ __forceinline__ float sigmoidf_(float x) {
    return __builtin_amdgcn_rcpf(1.0f + __expf(-x));
}

__device__ __forceinline__ short bfbits(float f) {
    __hip_bfloat16 h = __float2bfloat16(f);
    return *reinterpret_cast<short*>(&h);
}

__device__ __forceinline__ float bf_lo(unsigned u) { return __uint_as_float(u << 16); }
__device__ __forceinline__ float bf_hi(unsigned u) { return __uint_as_float(u & 0xffff0000u); }
__device__ __forceinline__ unsigned bfpack(float a, float b) {
    return (unsigned)(unsigned short)bfbits(a) | ((unsigned)(unsigned short)bfbits(b) << 16);
}

// async global->LDS, 16 B per lane; LDS dest is wave-uniform base + lane*16
__device__ __forceinline__ void gload_lds16(const void* g, void* l) {
    __builtin_amdgcn_global_load_lds(
        (const __attribute__((address_space(1))) unsigned int*)g,
        (__attribute__((address_space(3))) unsigned int*)l, 16, 0, 0);
}

// ---------------------------------------------------------------------------
// Staged MFMA GEMM: C(M x 128) = act( A @ W + bias ), bf16, fp32 acc.
// BM=64 geometry: LDS = 16KB sA + 32KB sB = 48KB -> 3 blocks/CU.
// A/B staged via global_load_lds (linear dest, XOR-swizzled source
// chunk ^= row&7; read applies the same XOR).
// Block = 256 thr (4 waves 2x2), wave tile 32x64.
// ---------------------------------------------------------------------------
template<int KT, bool SPLIT>
__global__ __launch_bounds__(256) void gemm_st(
    const __hip_bfloat16* __restrict__ A1,
    const __hip_bfloat16* __restrict__ A2,
    const __hip_bfloat16* __restrict__ Wt,   // 128 x (KT*128) bf16, n-major
    const float* __restrict__ bias,
    __hip_bfloat16* __restrict__ C,          // M x 128 bf16
    int M, int act)
{
    __shared__ uint4 smemv[3072];            // 49152 B
    char* const sA = (char*)smemv;           // 16384 B: [64 rows][16 x 16B]
    char* const sB = (char*)smemv + 16384;   // 32768 B: [128 n  ][16 x 16B]

    const int tid = threadIdx.x;
    const int wave = tid >> 6, lane = tid & 63;
    const int quad = lane >> 4, nn = lane & 15;
    const int wr = wave >> 1, wc = wave & 1;
    const int row_base = blockIdx.x * 64;
    const int col_base = wc * 64;

    f32x4 acc[2][4] = {};

    for (int h = 0; h < KT; ++h) {
        const char* Asrc = (const char*)(SPLIT ? (h ? A2 : A1) : A1);
        const size_t astride = SPLIT ? 256 : (size_t)KT * 256;   // row bytes
        const size_t aoff = SPLIT ? 0 : (size_t)h * 256;
        // ---- stage A: 1024 slots of 16 B (4 DMA calls/wave)
#pragma unroll
        for (int j = 0; j < 4; ++j) {
            const int sb = j * 4 + wave;          // slot-block 0..15
            const int s = sb * 64 + lane;         // slot 0..1023
            const int row = s >> 4, c = s & 15;
            int grow = row_base + row; if (grow >= M) grow = M - 1;
            gload_lds16(Asrc + (size_t)grow * astride + aoff + ((c ^ (row & 7)) * 16),
                        sA + sb * 1024);
        }
        // ---- stage B: 2048 slots (8 DMA calls/wave)
#pragma unroll
        for (int j = 0; j < 8; ++j) {
            const int sb = j * 4 + wave;          // 0..31
            const int s = sb * 64 + lane;
            const int n = s >> 4, c = s & 15;
            gload_lds16((const char*)Wt + (size_t)n * (KT * 256) + (size_t)h * 256
                            + ((c ^ (n & 7)) * 16),
                        sB + sb * 1024);
        }
        __syncthreads();   // compiler drains vmcnt before barrier

#pragma unroll
        for (int ks = 0; ks < 4; ++ks) {
            short8 a[2], b[4];
#pragma unroll
            for (int rt = 0; rt < 2; ++rt) {
                const int row = wr * 32 + rt * 16 + nn;
                a[rt] = *(const short8*)(sA + row * 256 + (((ks * 4 + quad) ^ (row & 7)) * 16));
            }
#pragma unroll
            for (int ct = 0; ct < 4; ++ct) {
                const int n = col_base + ct * 16 + nn;
                b[ct] = *(const short8*)(sB + n * 256 + (((ks * 4 + quad) ^ (n & 7)) * 16));
            }
#pragma unroll
            for (int ct = 0; ct < 4; ++ct)
#pragma unroll
                for (int rt = 0; rt < 2; ++rt)
                    acc[rt][ct] = __builtin_amdgcn_mfma_f32_16x16x32_bf16(
                        a[rt], b[ct], acc[rt][ct], 0, 0, 0);
        }
        __syncthreads();   // protects sA/sB overwrite (and sC reuse below)
    }

    float bs[4];
#pragma unroll
    for (int ct = 0; ct < 4; ++ct) bs[ct] = bias[col_base + ct * 16 + nn];

    // ---- stage C tile into LDS (bf16, stride 136 -> 2-way only) ----
    constexpr int KP = 136;
    unsigned short* sC = (unsigned short*)smemv;
#pragma unroll
    for (int rt = 0; rt < 2; ++rt) {
#pragma unroll
        for (int i = 0; i < 4; ++i) {
            const int R = wr * 32 + rt * 16 + quad * 4 + i;
#pragma unroll
            for (int ct = 0; ct < 4; ++ct) {
                float v = acc[rt][ct][i] + bs[ct];
                if (act) v = sigmoidf_(v);
                sC[R * KP + col_base + ct * 16 + nn] = (unsigned short)bfbits(v);
            }
        }
    }
    __syncthreads();

    // ---- cooperative coalesced store: thread t -> row t/4, quarter t&3 ----
    {
        const int row = tid >> 2, q = tid & 3;
        const int gr = row_base + row;
        if (gr < M) {
            const unsigned short* srcp = sC + row * KP + q * 32;
            uint4* dstp = (uint4*)(C + (size_t)gr * 128 + q * 32);
#pragma unroll
            for (int j = 0; j < 4; ++j) dstp[j] = *(const uint4*)(srcp + j * 8);
        }
    }
}

// ---------------------------------------------------------------------------
// Fused fp32-encode GEMM, BOTH inputs in one dispatch (block-range select):
// C(M x 128) = A_fp32(M x 256) @ W + bias, bf16 out.  BM=64 / 48KB LDS.
// 2-deep A pipeline in named registers (p0/q0, p1/q1): prologue issues
// phase-0 loads; phase-0 issues B DMA then phase-1 loads BEFORE converting,
// so the phase-0 barrier drain absorbs phase-1's HBM latency.
// __launch_bounds__(256,3): 3 blocks/CU (LDS limit) with VGPR cap ~170 so
// regalloc can keep both A tiles (64 VGPRs) in flight (68-VGPR build
// serialized the loads -> 72us at 27% occupancy, R7).
// ---------------------------------------------------------------------------
__global__ __launch_bounds__(256, 3) void gemm_enc2(
    const float* __restrict__ A0,            // N_NODES x 256 fp32
    const float* __restrict__ A1src,         // N_HE x 256 fp32
    const __hip_bfloat16* __restrict__ Wt,   // 128 x 256 bf16, n-major
    const float* __restrict__ bias,
    __hip_bfloat16* __restrict__ C0,
    __hip_bfloat16* __restrict__ C1,
    int NB0)                                 // blocks covering A0
{
    __shared__ uint4 smemv[3072];            // 49152 B
    char* const sA = (char*)smemv;           // 16384 B
    char* const sB = (char*)smemv + 16384;   // 32768 B

    const int tid = threadIdx.x;
    const int wave = tid >> 6, lane = tid & 63;
    const int quad = lane >> 4, nn = lane & 15;
    const int wr = wave >> 1, wc = wave & 1;

    const int b = blockIdx.x;
    const bool first = (b < NB0);
    const float* const A = first ? A0 : A1src;
    __hip_bfloat16* const C = first ? C0 : C1;
    const int M = first ? N_NODES : N_HE;
    const int row_base = (first ? b : b - NB0) * 64;
    const int col_base = wc * 64;

    // per-thread A slot geometry (same both phases; k-offset differs)
    int arow[4], acol[4];
#pragma unroll
    for (int j = 0; j < 4; ++j) {
        const int s = j * 256 + tid;          // slot 0..1023
        int grow = row_base + (s >> 4); if (grow >= M) grow = M - 1;
        arow[j] = grow; acol[j] = (s & 15) * 8;
    }

    f32x4 acc[2][4] = {};
    float4 p0[4], q0[4], p1[4], q1[4];

    // ---- prologue: issue phase-0 A loads
#pragma unroll
    for (int j = 0; j < 4; ++j) {
        const float* ap = A + (size_t)arow[j] * 256 + acol[j];
        p0[j] = *(const float4*)ap;
        q0[j] = *(const float4*)(ap + 4);
    }

    // ================= phase 0 =================
#pragma unroll
    for (int j = 0; j < 8; ++j) {            // B DMA (k 0..127)
        const int sb = j * 4 + wave;
        const int s = sb * 64 + lane;
        const int n = s >> 4, c = s & 15;
        gload_lds16((const char*)Wt + (size_t)n * 512 + ((c ^ (n & 7)) * 16),
                    sB + sb * 1024);
    }
#pragma unroll
    for (int j = 0; j < 4; ++j) {            // issue phase-1 A loads NOW
        const float* ap = A + (size_t)arow[j] * 256 + 128 + acol[j];
        p1[j] = *(const float4*)ap;
        q1[j] = *(const float4*)(ap + 4);
    }
#pragma unroll
    for (int j = 0; j < 4; ++j) {            // cvt + swizzled LDS write (p0)
        const int s = j * 256 + tid;
        const int row = s >> 4, c = s & 15;
        uint4 r;
        r.x = bfpack(p0[j].x, p0[j].y); r.y = bfpack(p0[j].z, p0[j].w);
        r.z = bfpack(q0[j].x, q0[j].y); r.w = bfpack(q0[j].z, q0[j].w);
        *(uint4*)(sA + row * 256 + ((c ^ (row & 7)) * 16)) = r;
    }
    __syncthreads();                         // drains B DMA + A1 loads too

#pragma unroll
    for (int ks = 0; ks < 4; ++ks) {
        short8 a[2], b2[4];
#pragma unroll
        for (int rt = 0; rt < 2; ++rt) {
            const int row = wr * 32 + rt * 16 + nn;
            a[rt] = *(const short8*)(sA + row * 256 + (((ks * 4 + quad) ^ (row & 7)) * 16));
        }
#pragma unroll
        for (int ct = 0; ct < 4; ++ct) {
            const int n = col_base + ct * 16 + nn;
            b2[ct] = *(const short8*)(sB + n * 256 + (((ks * 4 + quad) ^ (n & 7)) * 16));
        }
#pragma unroll
        for (int ct = 0; ct < 4; ++ct)
#pragma unroll
            for (int rt = 0; rt < 2; ++rt)
                acc[rt][ct] = __builtin_amdgcn_mfma_f32_16x16x32_bf16(
                    a[rt], b2[ct], acc[rt][ct], 0, 0, 0);
    }
    __syncthreads();

    // ================= phase 1 =================
#pragma unroll
    for (int j = 0; j < 8; ++j) {            // B DMA (k 128..255)
        const int sb = j * 4 + wave;
        const int s = sb * 64 + lane;
        const int n = s >> 4, c = s & 15;
        gload_lds16((const char*)Wt + (size_t)n * 512 + 256 + ((c ^ (n & 7)) * 16),
                    sB + sb * 1024);
    }
#pragma unroll
    for (int j = 0; j < 4; ++j) {            // cvt + write (p1, already landed)
        const int s = j * 256 + tid;
        const int row = s >> 4, c = s & 15;
        uint4 r;
        r.x = bfpack(p1[j].x, p1[j].y); r.y = bfpack(p1[j].z, p1[j].w);
        r.z = bfpack(q1[j].x, q1[j].y); r.w = bfpack(q1[j].z, q1[j].w);
        *(uint4*)(sA + row * 256 + ((c ^ (row & 7)) * 16)) = r;
    }
    __syncthreads();

#pragma unroll
    for (int ks = 0; ks < 4; ++ks) {
        short8 a[2], b2[4];
#pragma unroll
        for (int rt = 0; rt < 2; ++rt) {
            const int row = wr * 32 + rt * 16 + nn;
            a[rt] = *(const short8*)(sA + row * 256 + (((ks * 4 + quad) ^ (row & 7)) * 16));
        }
#pragma unroll
        for (int ct = 0; ct < 4; ++ct) {
            const int n = col_base + ct * 16 + nn;
            b2[ct] = *(const short8*)(sB + n * 256 + (((ks * 4 + quad) ^ (n & 7)) * 16));
        }
#pragma unroll
        for (int ct = 0; ct < 4; ++ct)
#pragma unroll
            for (int rt = 0; rt < 2; ++rt)
                acc[rt][ct] = __builtin_amdgcn_mfma_f32_16x16x32_bf16(
                    a[rt], b2[ct], acc[rt][ct], 0, 0, 0);
    }
    __syncthreads();

    // ================= epilogue =================
    float bs[4];
#pragma unroll
    for (int ct = 0; ct < 4; ++ct) bs[ct] = bias[col_base + ct * 16 + nn];

    constexpr int KP = 136;
    unsigned short* sC = (unsigned short*)smemv;
#pragma unroll
    for (int rt = 0; rt < 2; ++rt) {
#pragma unroll
        for (int i = 0; i < 4; ++i) {
            const int R = wr * 32 + rt * 16 + quad * 4 + i;
#pragma unroll
            for (int ct = 0; ct < 4; ++ct) {
                const float v = acc[rt][ct][i] + bs[ct];
                sC[R * KP + col_base + ct * 16 + nn] = (unsigned short)bfbits(v);
            }
        }
    }
    __syncthreads();

    {
        const int row = tid >> 2, q = tid & 3;
        const int gr = row_base + row;
        if (gr < M) {
            const unsigned short* srcp = sC + row * KP + q * 32;
            uint4* dstp = (uint4*)(C + (size_t)gr * 128 + q * 32);
#pragma unroll
            for (int j = 0; j < 4; ++j) dstp[j] = *(const uint4*)(srcp + j * 8);
        }
    }
}

// ---------------------------------------------------------------------------
// MFMA output GEMM: out(M x 40) = X(M x 128 bf16) @ W + b, fp32 out.
// ---------------------------------------------------------------------------
__global__ __launch_bounds__(256) void out_gemm_mfma(
    const __hip_bfloat16* __restrict__ X,
    const __hip_bfloat16* __restrict__ Wt,   // 48 x 128 bf16 (n-major, padded)
    const float* __restrict__ b, float* __restrict__ out, int M)
{
    constexpr int KP = 136;
    __shared__ uint4 sXv[1024];              // 16384 B: [64 rows][16 x 16B]
    __shared__ __hip_bfloat16 sW[48 * KP];
    __shared__ float sB[48];
    __shared__ float sO[64 * 44];            // 11264 B

    char* const sX = (char*)sXv;
    const int tid = threadIdx.x;
    const int wave = tid >> 6, lane = tid & 63;

    // stage X: 1024 slots, 4 calls/wave
#pragma unroll
    for (int j = 0; j < 4; ++j) {
        const int sb = j * 4 + wave;          // 0..15
        const int s = sb * 64 + lane;         // 0..1023
        const int row = s >> 4, c = s & 15;
        int grow = blockIdx.x * 64 + row; if (grow >= M) grow = M - 1;
        gload_lds16((const char*)X + (size_t)grow * 256 + ((c ^ (row & 7)) * 16),
                    sX + sb * 1024);
    }
    for (int c = tid; c < 48 * 16; c += 256) {
        const int n = c >> 4, ko = (c & 15) * 8;
        *(uint4*)&sW[n * KP + ko] = *(const uint4*)&Wt[n * 128 + ko];
    }
    if (tid < 48) sB[tid] = (tid < 40) ? b[tid] : 0.0f;
    __syncthreads();

    const int quad = lane >> 4, nn = lane & 15;

    f32x4 acc[3] = {};
#pragma unroll
    for (int ks = 0; ks < 4; ++ks) {
        const int rowl = wave * 16 + nn;
        const short8 a = *(const short8*)(sX + rowl * 256 + (((ks * 4 + quad) ^ (rowl & 7)) * 16));
#pragma unroll
        for (int ct = 0; ct < 3; ++ct) {
            const short8 bf = *(const short8*)&sW[(ct * 16 + nn) * KP + ks * 32 + quad * 8];
            acc[ct] = __builtin_amdgcn_mfma_f32_16x16x32_bf16(a, bf, acc[ct], 0, 0, 0);
        }
    }

    // stage into LDS
#pragma unroll
    for (int ct = 0; ct < 3; ++ct) {
        const int c = ct * 16 + nn;
        if (c < 40) {
#pragma unroll
            for (int i = 0; i < 4; ++i) {
                const int rl = wave * 16 + quad * 4 + i;
                sO[rl * 44 + c] = acc[ct][i] + sB[c];
            }
        }
    }
    __syncthreads();

    // cooperative store: 64 rows x 10 float4
    for (int c = tid; c < 640; c += 256) {
        const int row = c / 10, ch = c % 10;
        const int gr = blockIdx.x * 64 + row;
        if (gr < M)
            *(float4*)(out + (size_t)gr * 40 + ch * 4) =
                *(const float4*)(sO + row * 44 + ch * 4);
    }
}

// ---------------------------------------------------------------------------
// Prep: weight transpose/convert (fp32 -> bf16 n-major) + zero CSR counts.
// ---------------------------------------------------------------------------
__global__ __launch_bounds__(256) void prep_kernel(
    const float* __restrict__ We, const float* __restrict__ Wm0,
    const float* __restrict__ Wm1, const float* __restrict__ Wout,
    __hip_bfloat16* __restrict__ Wt_enc, __hip_bfloat16* __restrict__ Wt_m0,
    __hip_bfloat16* __restrict__ Wt_m1, __hip_bfloat16* __restrict__ Wt_out,
    int* __restrict__ cnt_zero)
{
    const int i = blockIdx.x * 256 + threadIdx.x;
    if (i < 32768) {
        const int n = i >> 8, k = i & 255;
        Wt_enc[n * 256 + k] = __float2bfloat16(We[k * 128 + n]);
    } else if (i < 65536) {
        int j = i - 32768; const int l = j >> 14; j &= 16383;
        const int n = j >> 7, k = j & 127;
        Wt_m0[l * 16384 + n * 128 + k] = __float2bfloat16(Wm0[l * 16384 + k * 128 + n]);
    } else if (i < 131072) {
        int j = i - 65536; const int l = j >> 15; j &= 32767;
        const int n = j >> 8, k = j & 255;
        Wt_m1[l * 32768 + n * 256 + k] = __float2bfloat16(Wm1[l * 32768 + k * 128 + n]);
    } else if (i < 137216) {
        const int j = i - 131072;
        const int n = j >> 7, k = j & 127;
        Wt_out[n * 128 + k] = (n < 40) ? __float2bfloat16(Wout[k * 40 + n])
                                       : __float2bfloat16(0.0f);
    } else {
        const int z = i - 137216;
        if (z < N_HE + N_NODES) cnt_zero[z] = 0;
    }
}

// ---------------------------------------------------------------------------
// CSR build (atomic-free fill: hist captures per-edge rank)
// ---------------------------------------------------------------------------
__global__ __launch_bounds__(256) void hist_kernel(
    const int* __restrict__ he_idx, const int* __restrict__ node_idx,
    int* __restrict__ he_cnt, int* __restrict__ node_cnt,
    int* __restrict__ he_rank, int* __restrict__ node_rank, int n)
{
    const int i = blockIdx.x * 256 + threadIdx.x;
    if (i < n) {
        he_rank[i] = atomicAdd(&he_cnt[he_idx[i]], 1);
        node_rank[i] = atomicAdd(&node_cnt[node_idx[i]], 1);
    }
}

__global__ __launch_bounds__(256) void scan1_kernel(
    int* __restrict__ data, int* __restrict__ bsums, int n)
{
    __shared__ int s[256];
    const int t = threadIdx.x;
    const int base = blockIdx.x * 1024 + t * 4;
    int4 v = make_int4(0, 0, 0, 0);
    if (base < n) v = *(const int4*)(data + base);
    s[t] = v.x + v.y + v.z + v.w;
    __syncthreads();
    for (int d = 1; d < 256; d <<= 1) {
        const int u = (t >= d) ? s[t - d] : 0;
        __syncthreads();
        s[t] += u;
        __syncthreads();
    }
    if (t == 255) bsums[blockIdx.x] = s[255];
    int e = t ? s[t - 1] : 0;
    if (base < n) {
        int4 o;
        o.x = e; e += v.x; o.y = e; e += v.y; o.z = e; e += v.z; o.w = e;
        *(int4*)(data + base) = o;
    }
}

// scan2+scan3 fused: each block locally reduces bsums[0..bid-1], then adds.
__global__ __launch_bounds__(256) void scan23_kernel(
    int* __restrict__ data, const int* __restrict__ bsums, int n, int nb)
{
    __shared__ int s[256];
    const int t = threadIdx.x;
    const int v = (t < nb && t < (int)blockIdx.x) ? bsums[t] : 0;
    s[t] = v;
    __syncthreads();
    for (int d = 1; d < 256; d <<= 1) {
        const int u = (t >= d) ? s[t - d] : 0;
        __syncthreads();
        s[t] += u;
        __syncthreads();
    }
    const int total = s[255];                 // sum of bsums[0..bid-1]
    const int base = blockIdx.x * 1024 + t * 4;
    if (base >= n) return;
    const int adj = total - ((base >= N_HE) ? N_INC : 0);
    int4 vv = *(int4*)(data + base);
    vv.x += adj; vv.y += adj; vv.z += adj; vv.w += adj;
    *(int4*)(data + base) = vv;
}

// fill packed edges at off[dest]+rank[e] — NO atomics
__global__ __launch_bounds__(256) void fill_kernel(
    const int* __restrict__ node_idx, const int* __restrict__ he_idx,
    const float* __restrict__ vals,
    const int* __restrict__ he_off, const int* __restrict__ node_off,
    const int* __restrict__ he_rank, const int* __restrict__ node_rank,
    int2* __restrict__ he_edge, int2* __restrict__ node_edge, int n)
{
    const int e = blockIdx.x * 256 + threadIdx.x;
    if (e >= n) return;
    const int hn = he_idx[e], nd = node_idx[e];
    const int vb = __float_as_int(vals[e]);
    he_edge[he_off[hn] + he_rank[e]] = make_int2(nd, vb);
    node_edge[node_off[nd] + node_rank[e]] = make_int2(hn, vb);
}

// ---------------------------------------------------------------------------
// Split butterfly reduction helper: input a0..a7 (cols l16*8+i, partial over
// edge-slot groups), output s0,s1 = full sums for cols l16*8+2g, +1.
// ---------------------------------------------------------------------------
__device__ __forceinline__ void reduce_groups(
    int lane, float a0, float a1, float a2, float a3,
    float a4, float a5, float a6, float a7, float& s0, float& s1)
{
    const bool hb = (lane & 32) != 0;    // bit1 of group g = lane>>4
    float t0 = hb ? a0 : a4;
    float t1 = hb ? a1 : a5;
    float t2 = hb ? a2 : a6;
    float t3 = hb ? a3 : a7;
    float r0 = __shfl_xor(t0, 32);
    float r1 = __shfl_xor(t1, 32);
    float r2 = __shfl_xor(t2, 32);
    float r3 = __shfl_xor(t3, 32);
    float e0 = (hb ? a4 : a0) + r0;
    float e1 = (hb ? a5 : a1) + r1;
    float e2 = (hb ? a6 : a2) + r2;
    float e3 = (hb ? a7 : a3) + r3;
    const bool lb = (lane & 16) != 0;    // bit0 of group
    float u0 = lb ? e0 : e2;
    float u1 = lb ? e1 : e3;
    float q0 = __shfl_xor(u0, 16);
    float q1 = __shfl_xor(u1, 16);
    s0 = (lb ? e2 : e0) + q0;
    s1 = (lb ? e3 : e1) + q1;
}

// ---------------------------------------------------------------------------
// Fused he-gather (4 edges/wave-iter, 16B/lane, edge prefetch + hoisted
// x1cur read): agg = sum val*m0[src]; writes m0_he AND x1_next.
// ---------------------------------------------------------------------------
__global__ __launch_bounds__(256) void gather_he_kernel(
    const __hip_bfloat16* __restrict__ msrc,
    const __hip_bfloat16* __restrict__ x1cur,
    __hip_bfloat16* __restrict__ m0_he,
    __hip_bfloat16* __restrict__ x1next,
    const int* __restrict__ off, const int2* __restrict__ edges, int n_seg)
{
    const int wave = threadIdx.x >> 6;
    const int lane = threadIdx.x & 63;
    const int row = blockIdx.x * 4 + wave;
    if (row >= n_seg) return;
    const int start = off[row];
    const int end = (row + 1 < n_seg) ? off[row + 1] : N_INC;
    const int g = lane >> 4;
    const int l16 = lane & 15;
    // hoist the epilogue operand load: hides under the gather loop
    const size_t o32 = (size_t)row * 64 + l16 * 4 + g;
    const unsigned xu = ((const unsigned*)x1cur)[o32];
    float a0 = 0.f, a1 = 0.f, a2 = 0.f, a3 = 0.f;
    float a4 = 0.f, a5 = 0.f, a6 = 0.f, a7 = 0.f;
    const unsigned short* s16 = (const unsigned short*)msrc;
    // software pipeline: edge record prefetched one quad ahead
    int e = start;
    int2 ed = (start + g < end) ? edges[start + g] : make_int2(0, 0);
    for (; e + 4 <= end; e += 4) {
        const int2 cur = ed;
        const int ee = e + 4 + g;
        ed = (ee < end) ? edges[ee] : make_int2(0, 0);   // covers tail too
        const float v = __int_as_float(cur.y);
        const uint4 u = *(const uint4*)(s16 + (size_t)cur.x * 128 + l16 * 8);
        a0 += bf_lo(u.x) * v; a1 += bf_hi(u.x) * v;
        a2 += bf_lo(u.y) * v; a3 += bf_hi(u.y) * v;
        a4 += bf_lo(u.z) * v; a5 += bf_hi(u.z) * v;
        a6 += bf_lo(u.w) * v; a7 += bf_hi(u.w) * v;
    }
    if (e < end) {                                       // masked tail (prefetched)
        const float v = __int_as_float(ed.y);
        const uint4 u = *(const uint4*)(s16 + (size_t)ed.x * 128 + l16 * 8);
        a0 += bf_lo(u.x) * v; a1 += bf_hi(u.x) * v;
        a2 += bf_lo(u.y) * v; a3 += bf_hi(u.y) * v;
        a4 += bf_lo(u.z) * v; a5 += bf_hi(u.z) * v;
        a6 += bf_lo(u.w) * v; a7 += bf_hi(u.w) * v;
    }
    float s0, s1;
    reduce_groups(lane, a0, a1, a2, a3, a4, a5, a6, a7, s0, s1);
    ((unsigned*)m0_he)[o32] = bfpack(s0, s1);
    ((unsigned*)x1next)[o32] =
        bfpack(sigmoidf_(bf_lo(xu) + s0), sigmoidf_(bf_hi(xu) + s1));
}

// ---------------------------------------------------------------------------
// Fused node-gather (4 edges/wave-iter, prefetch + hoisted x0 read):
// x0 = sigmoid(x0 + agg) in place.
// ---------------------------------------------------------------------------
__global__ __launch_bounds__(256) void gather_node_kernel(
    const __hip_bfloat16* __restrict__ msrc,
    __hip_bfloat16* __restrict__ x0,
    const int* __restrict__ off, const int2* __restrict__ edges, int n_seg)
{
    const int wave = threadIdx.x >> 6;
    const int lane = threadIdx.x & 63;
    const int row = blockIdx.x * 4 + wave;
    if (row >= n_seg) return;
    const int start = off[row];
    const int end = (row + 1 < n_seg) ? off[row + 1] : N_INC;
    const int g = lane >> 4;
    const int l16 = lane & 15;
    const size_t o32 = (size_t)row * 64 + l16 * 4 + g;
    unsigned* const px = (unsigned*)x0 + o32;
    const unsigned xu = *px;                             // hoisted RMW read
    float a0 = 0.f, a1 = 0.f, a2 = 0.f, a3 = 0.f;
    float a4 = 0.f, a5 = 0.f, a6 = 0.f, a7 = 0.f;
    const unsigned short* s16 = (const unsigned short*)msrc;
    int e = start;
    int2 ed = (start + g < end) ? edges[start + g] : make_int2(0, 0);
    for (; e + 4 <= end; e += 4) {
        const int2 cur = ed;
        const int ee = e + 4 + g;
        ed = (ee < end) ? edges[ee] : make_int2(0, 0);
        const float v = __int_as_float(cur.y);
        const uint4 u = *(const uint4*)(s16 + (size_t)cur.x * 128 + l16 * 8);
        a0 += bf_lo(u.x) * v; a1 += bf_hi(u.x) * v;
        a2 += bf_lo(u.y) * v; a3 += bf_hi(u.y) * v;
        a4 += bf_lo(u.z) * v; a5 += bf_hi(u.z) * v;
        a6 += bf_lo(u.w) * v; a7 += bf_hi(u.w) * v;
    }
    if (e < end) {
        const float v = __int_as_float(ed.y);
        const uint4 u = *(const uint4*)(s16 + (size_t)ed.x * 128 + l16 * 8);
        a0 += bf_lo(u.x) * v; a1 += bf_hi(u.x) * v;
        a2 += bf_lo(u.y) * v; a3 += bf_hi(u.y) * v;
        a4 += bf_lo(u.z) * v; a5 += bf_hi(u.z) * v;
        a6 += bf_lo(u.w) * v; a7 += bf_hi(u.w) * v;
    }
    float s0, s1;
    reduce_groups(lane, a0, a1, a2, a3, a4, a5, a6, a7, s0, s1);
    *px = bfpack(sigmoidf_(bf_lo(xu) + s0), sigmoidf_(bf_hi(xu) + s1));
}

// ---------------------------------------------------------------------------
extern "C" void kernel_launch(void* const* d_in, const int* in_sizes, int n_in,
                              void* d_out, int out_size, void* d_ws, size_t ws_size,
                              hipStream_t stream)
{
    const float* x0_in   = (const float*)d_in[0];
    const float* x1_in   = (const float*)d_in[1];
    const int*   node_idx = (const int*)d_in[2];
    const int*   he_idx   = (const int*)d_in[3];
    const float* inc_vals = (const float*)d_in[4];
    const float* W_enc   = (const float*)d_in[5];
    const float* b_enc   = (const float*)d_in[6];
    const float* W_msg0  = (const float*)d_in[7];
    const float* b_msg0  = (const float*)d_in[8];
    const float* W_msg1  = (const float*)d_in[9];
    const float* b_msg1  = (const float*)d_in[10];
    const float* W_out   = (const float*)d_in[11];
    const float* b_out   = (const float*)d_in[12];
    float* out = (float*)d_out;

    __hip_bfloat16* x0h    = (__hip_bfloat16*)d_ws;         // 12,800,000
    __hip_bfloat16* x1a    = x0h + 12800000;                //  6,400,000
    __hip_bfloat16* x1b    = x1a + 6400000;                 //  6,400,000
    __hip_bfloat16* mbuf   = x1b + 6400000;                 // 12,800,000
    __hip_bfloat16* m0_he  = mbuf + 12800000;               //  6,400,000
    __hip_bfloat16* Wt_enc = m0_he + 6400000;               // 32768
    __hip_bfloat16* Wt_m0  = Wt_enc + 32768;                // 32768
    __hip_bfloat16* Wt_m1  = Wt_m0 + 32768;                 // 65536
    __hip_bfloat16* Wt_out = Wt_m1 + 65536;                 // 6144
    int*  he_off    = (int*)(Wt_out + 6144);
    int*  node_off  = he_off + N_HE;
    int*  bsums     = node_off + N_NODES;                   // 256
    int*  he_rank   = bsums + 256;                          // 600k
    int*  node_rank = he_rank + N_INC;                      // 600k
    int2* he_edge   = (int2*)(node_rank + N_INC);
    int2* node_edge = he_edge + N_INC;

    // ---- prep (weight transpose + zero CSR counts) ----
    prep_kernel<<<(137216 + N_HE + N_NODES + 255) / 256, 256, 0, stream>>>(
        W_enc, W_msg0, W_msg1, W_out, Wt_enc, Wt_m0, Wt_m1, Wt_out, he_off);

    // ---- CSR build ----
    hist_kernel<<<(N_INC + 255) / 256, 256, 0, stream>>>(
        he_idx, node_idx, he_off, node_off, he_rank, node_rank, N_INC);
    const int scan_n = N_HE + N_NODES;
    const int scan_blocks = (scan_n + 1023) / 1024;          // 147
    scan1_kernel<<<scan_blocks, 256, 0, stream>>>(he_off, bsums, scan_n);
    scan23_kernel<<<scan_blocks, 256, 0, stream>>>(he_off, bsums, scan_n, scan_blocks);
    fill_kernel<<<(N_INC + 255) / 256, 256, 0, stream>>>(
        node_idx, he_idx, inc_vals, he_off, node_off, he_rank, node_rank,
        he_edge, node_edge, N_INC);

    // ---- encode: one dispatch for both inputs ----
    const int NB0 = (N_NODES + 63) / 64;                     // 1563
    const int NB1 = (N_HE + 63) / 64;                        // 782
    gemm_enc2<<<NB0 + NB1, 256, 0, stream>>>(
        x0_in, x1_in, Wt_enc, b_enc, x0h, x1a, NB0);

    __hip_bfloat16* x1cur = x1a;
    __hip_bfloat16* x1nxt = x1b;
    for (int l = 0; l < 2; ++l) {
        gemm_st<1, false><<<(N_NODES + 63) / 64, 256, 0, stream>>>(
            x0h, nullptr, Wt_m0 + (size_t)l * 16384,
            b_msg0 + (size_t)l * 128, mbuf, N_NODES, 1);
        gather_he_kernel<<<(N_HE + 3) / 4, 256, 0, stream>>>(
            mbuf, x1cur, m0_he, x1nxt, he_off, he_edge, N_HE);
        gemm_st<2, true><<<(N_HE + 63) / 64, 256, 0, stream>>>(
            x1cur, m0_he, Wt_m1 + (size_t)l * 32768,
            b_msg1 + (size_t)l * 128, mbuf, N_HE, 1);
        gather_node_kernel<<<(N_NODES + 3) / 4, 256, 0, stream>>>(
            mbuf, x0h, node_off, node_edge, N_NODES);
        __hip_bfloat16* t = x1cur; x1cur = x1nxt; x1nxt = t;
    }

    out_gemm_mfma<<<(N_NODES + 63) / 64, 256, 0, stream>>>(
        x0h, Wt_out, b_out, out, N_NODES);
}